// Round 23
// baseline (1181.984 us; speedup 1.0000x reference)
//
#include <hip/hip_runtime.h>
#include <hip/hip_bf16.h>

#define N_NODES 50000
#define N_EDGES 800000
#define N_GRAPH 500
#define ND 64
#define ED 32
#define HD 128
#define WPB 4   // waves per block (256 threads)
#define NBU ((N_NODES + 31) / 32)   // 1563 one-wave node blocks

typedef __attribute__((ext_vector_type(8))) short bf16x8;
typedef __attribute__((ext_vector_type(4))) float f32x4;

__device__ __forceinline__ float sp(float x) {
    return fmaxf(x, 0.f) + log1pf(expf(-fabsf(x)));
}

// fast softplus for the bf16 path (v_exp_f32/v_log_f32 based)
__device__ __forceinline__ float spf(float x) {
    return fmaxf(x, 0.f) + __logf(1.f + __expf(-fabsf(x)));
}

__device__ __forceinline__ unsigned short f2bf(float v) {
    __hip_bfloat16 b = __float2bfloat16(v);
    return *(unsigned short*)&b;
}

__device__ __forceinline__ unsigned int pkbf(float a, float b) {
    return (unsigned int)f2bf(a) | ((unsigned int)f2bf(b) << 16);
}

__device__ __forceinline__ float lo_bf(unsigned int u) { return __uint_as_float(u << 16); }
__device__ __forceinline__ float hi_bf(unsigned int u) { return __uint_as_float(u & 0xffff0000u); }

// load 8 fp32 and round to bf16x8 (same RNE as k_bn_apply/f2bf)
__device__ __forceinline__ bf16x8 ld8_f32_bf(const float* p) {
    f32x4 v0 = *(const f32x4*)p;
    f32x4 v1 = *(const f32x4*)(p + 4);
    bf16x8 r;
    r[0] = (short)f2bf(v0[0]); r[1] = (short)f2bf(v0[1]);
    r[2] = (short)f2bf(v0[2]); r[3] = (short)f2bf(v0[3]);
    r[4] = (short)f2bf(v1[0]); r[5] = (short)f2bf(v1[1]);
    r[6] = (short)f2bf(v1[2]); r[7] = (short)f2bf(v1[3]);
    return r;
}

// ---------------- node projection: partial BN stats per block -----------
__global__ __launch_bounds__(256) void k_node_proj(
    const float* __restrict__ x, const float* __restrict__ Wnp,
    const float* __restrict__ bnp, float* __restrict__ t,
    float* __restrict__ partN) {
    __shared__ float red0[4][64], red1[4][64];
    int lane = threadIdx.x & 63;
    int wid = threadIdx.x >> 6;
    int wave = (blockIdx.x * blockDim.x + threadIdx.x) >> 6;
    int nw = (gridDim.x * blockDim.x) >> 6;
    float w[13];
#pragma unroll
    for (int k = 0; k < 13; ++k) w[k] = Wnp[k * ND + lane];
    float bb = bnp[lane];
    float s0 = 0.f, s1 = 0.f;
    for (int i = wave; i < N_NODES; i += nw) {
        float acc = bb;
#pragma unroll
        for (int k = 0; k < 13; ++k) acc += x[i * 13 + k] * w[k];
        float v = sp(acc);
        t[i * ND + lane] = v;
        s0 += v; s1 += v * v;
    }
    red0[wid][lane] = s0;
    red1[wid][lane] = s1;
    __syncthreads();
    int tid = threadIdx.x;
    if (tid < 64)
        partN[blockIdx.x * 128 + tid] =
            red0[0][tid] + red0[1][tid] + red0[2][tid] + red0[3][tid];
    else if (tid < 128) {
        int c = tid - 64;
        partN[blockIdx.x * 128 + tid] =
            red1[0][c] + red1[1][c] + red1[2][c] + red1[3][c];
    }
}

// ---- two-stage BN stats: sum R partial rows, emit scale/shift ----------
__global__ void k_stats_reduce(const float* __restrict__ part, int R,
                               const float* __restrict__ g,
                               const float* __restrict__ b,
                               float* __restrict__ ss) {
    __shared__ float r0[4][64], r1[4][64];
    int q = threadIdx.x >> 6, c = threadIdx.x & 63;
    float S0 = 0.f, S1 = 0.f;
    for (int r = q; r < R; r += 4) {
        S0 += part[(size_t)r * 128 + c];
        S1 += part[(size_t)r * 128 + 64 + c];
    }
    r0[q][c] = S0; r1[q][c] = S1;
    __syncthreads();
    if (threadIdx.x < 64) {
        float s0 = r0[0][c] + r0[1][c] + r0[2][c] + r0[3][c];
        float s1 = r1[0][c] + r1[1][c] + r1[2][c] + r1[3][c];
        float inv_n = 1.f / (float)N_NODES;
        float mu = s0 * inv_n;
        float var = s1 * inv_n - mu * mu;
        float rs = rsqrtf(var + 1e-5f);
        float sc = rs * g[c];
        ss[c] = sc;
        ss[64 + c] = b[c] - mu * sc;
    }
}

__global__ __launch_bounds__(256) void k_bn_apply(
    const float* __restrict__ t, const float* __restrict__ ss,
    float* __restrict__ h, unsigned short* __restrict__ hb) {
    int idx = blockIdx.x * blockDim.x + threadIdx.x;
    int tot = N_NODES * ND;
    int stride = gridDim.x * blockDim.x;
    for (; idx < tot; idx += stride) {
        int c = idx & (ND - 1);
        float v = t[idx] * ss[c] + ss[ND + c];
        h[idx] = v;
        hb[idx] = f2bf(v);
    }
}

// ---------------- counting sort of edges by dst -------------------------
__global__ __launch_bounds__(256) void k_hist(const int* __restrict__ ei,
                                              int* __restrict__ hist) {
    int e = blockIdx.x * 256 + threadIdx.x;
    if (e < N_EDGES) atomicAdd(&hist[ei[N_EDGES + e]], 1);
}

__global__ __launch_bounds__(1024) void k_scan1(const int* __restrict__ hist,
                                                int* __restrict__ chunksum) {
    __shared__ int s[1024];
    int t = threadIdx.x;
    int i = blockIdx.x * 1024 + t;
    s[t] = (i < N_NODES) ? hist[i] : 0;
    __syncthreads();
    for (int off = 512; off; off >>= 1) {
        if (t < off) s[t] += s[t + off];
        __syncthreads();
    }
    if (t == 0) chunksum[blockIdx.x] = s[0];
}

__global__ void k_scan2(int* __restrict__ chunksum, int n) {
    if (threadIdx.x == 0) {
        int acc = 0;
        for (int i = 0; i < n; ++i) { int v = chunksum[i]; chunksum[i] = acc; acc += v; }
    }
}

__global__ __launch_bounds__(1024) void k_scan3(const int* __restrict__ hist,
                                                const int* __restrict__ chunksum,
                                                int* __restrict__ cursor,
                                                int* __restrict__ rowptr) {
    __shared__ int s[1024];
    int t = threadIdx.x;
    int i = blockIdx.x * 1024 + t;
    int v = (i < N_NODES) ? hist[i] : 0;
    s[t] = v;
    __syncthreads();
    for (int off = 1; off < 1024; off <<= 1) {
        int u = (t >= off) ? s[t - off] : 0;
        __syncthreads();
        s[t] += u;
        __syncthreads();
    }
    if (i < N_NODES) {
        int ex = chunksum[blockIdx.x] + s[t] - v;  // exclusive
        cursor[i] = ex;
        rowptr[i] = ex;
    }
}

__global__ __launch_bounds__(256) void k_scatter(const int* __restrict__ ei,
                                                 int* __restrict__ cursor,
                                                 int* __restrict__ sD,
                                                 int* __restrict__ sS,
                                                 int* __restrict__ sE) {
    int e = blockIdx.x * 256 + threadIdx.x;
    if (e >= N_EDGES) return;
    int d = ei[N_EDGES + e];
    int pos = atomicAdd(&cursor[d], 1);
    sD[pos] = d;
    sS[pos] = ei[e];
    sE[pos] = e;
}

// edge projection into sorted order (layer-invariant, once per call)
__global__ __launch_bounds__(256) void k_eproj_sorted(
    const float* __restrict__ ea, const int* __restrict__ sE,
    const float* __restrict__ Wep, const float* __restrict__ bep,
    unsigned short* __restrict__ e_bf) {
    long idx = (long)blockIdx.x * blockDim.x + threadIdx.x;
    long tot = (long)N_EDGES * 32;
    if (idx >= tot) return;
    int p = (int)(idx >> 5), col = (int)(idx & 31);
    int e = sE[p];
    float v = spf(ea[2 * e] * Wep[col] + ea[2 * e + 1] * Wep[32 + col] + bep[col]);
    e_bf[idx] = f2bf(v);
}

// ---- fused weight pack: all 3 layers x {We1,We2,Wn1,Wn2} in ONE launch --
__global__ __launch_bounds__(256) void k_pack_all(
    const float* __restrict__ We1, const float* __restrict__ We2,
    const float* __restrict__ Wn1, const float* __restrict__ Wn2,
    unsigned short* __restrict__ pA1, unsigned short* __restrict__ pA2,
    unsigned short* __restrict__ pWn1, unsigned short* __restrict__ pWn2) {
    int tid = blockIdx.x * 256 + threadIdx.x;
    const int PER_L = (40 + 32 + 48 + 16) * 64;  // 8704
    if (tid >= 3 * PER_L) return;
    int layer = tid / PER_L;
    int r = tid % PER_L;
    const float* W;
    unsigned short* out;
    int ncols, lt;
    if (r < 40 * 64) {
        lt = r; W = We1 + (size_t)layer * 160 * 128; out = pA1 + (size_t)layer * 40 * 64 * 8;
        ncols = 128;
    } else if (r < 72 * 64) {
        lt = r - 40 * 64; W = We2 + (size_t)layer * 128 * 128; out = pA2 + (size_t)layer * 32 * 64 * 8;
        ncols = 128;
    } else if (r < 120 * 64) {
        lt = r - 72 * 64; W = Wn1 + (size_t)layer * 192 * 128; out = pWn1 + (size_t)layer * 48 * 64 * 8;
        ncols = 128;
    } else {
        lt = r - 120 * 64; W = Wn2 + (size_t)layer * 128 * 64; out = pWn2 + (size_t)layer * 16 * 64 * 8;
        ncols = 64;
    }
    int nfrag = ncols >> 4;
    int l = lt & 63; int fr = lt >> 6; int nf = fr % nfrag; int ks = fr / nfrag;
    int n = 16 * nf + (l & 15);
    int k0 = 32 * ks + 8 * (l >> 4);
#pragma unroll
    for (int rr = 0; rr < 8; ++rr)
        out[lt * 8 + rr] = f2bf(W[(k0 + rr) * ncols + n]);
}

// ---------------- MFMA edge conv on dst-sorted edges --------------------
// Fully register-bounded for 4 blocks/CU:
//  - GEMM1 in QUARTERS (2 nf): <=10 A-loads + 16 AGPR acc per region.
//  - GEMM2 per m-fragment in two nf-halves (16 A-loads, acc2[4]); half 0's
//    packed output deferred in 8 uints (can't write LDS while half 1 still
//    reads those columns), half 1 writes both.
template <bool EPRE>
__global__ __launch_bounds__(256, 4) void k_edge_mfma_s(
    const unsigned short* __restrict__ h_bf, const unsigned short* __restrict__ e_bf,
    const float* __restrict__ ea, const int* __restrict__ sE,
    const float* __restrict__ Wep, const float* __restrict__ bep,
    const int* __restrict__ sD, const int* __restrict__ sS,
    const int* __restrict__ rowptr, const int* __restrict__ hist,
    const unsigned short* __restrict__ pA1, const float* __restrict__ be1,
    const unsigned short* __restrict__ pA2, const float* __restrict__ be2,
    float* __restrict__ aggr) {
    __shared__ unsigned short P[WPB][32][136];   // per-wave P; reused as 128-row stage
    __shared__ int dstB[128];
    __shared__ unsigned short eL[EPRE ? 64 : 128 * 32];

    int lane = threadIdx.x & 63;
    int w = threadIdx.x >> 6;
    int m = lane & 15, g = lane >> 4;
    int tile0 = blockIdx.x * 128;
    int wbase = tile0 + 32 * w;

    int eD0 = sD[wbase + m];
    int eD1 = sD[wbase + 16 + m];
    int eS0 = sS[wbase + m];
    int eS1 = sS[wbase + 16 + m];

    if constexpr (!EPRE) {
        int col = threadIdx.x & 31;
        int r0 = threadIdx.x >> 5;
        float w0 = Wep[col], w1 = Wep[32 + col], bb = bep[col];
#pragma unroll
        for (int i = 0; i < 16; ++i) {
            int em = r0 + 8 * i;
            int e = sE[tile0 + em];
            eL[em * 32 + col] = f2bf(spf(ea[2 * e] * w0 + ea[2 * e + 1] * w1 + bb));
        }
        __syncthreads();
    }

    // ---- GEMM1 (K=160) in four nf-quarters: acc = 16 AGPR per region ----
#pragma unroll
    for (int qt = 0; qt < 4; ++qt) {
        f32x4 acc[2][2];
#pragma unroll
        for (int mf = 0; mf < 2; ++mf)
#pragma unroll
            for (int n2 = 0; n2 < 2; ++n2) acc[mf][n2] = (f32x4){0.f, 0.f, 0.f, 0.f};
#pragma unroll
        for (int ks = 0; ks < 5; ++ks) {
            bf16x8 b0, b1;
            if (ks < 2) {
                b0 = *(const bf16x8*)(h_bf + (size_t)eD0 * 64 + ks * 32 + 8 * g);
                b1 = *(const bf16x8*)(h_bf + (size_t)eD1 * 64 + ks * 32 + 8 * g);
            } else if (ks < 4) {
                b0 = *(const bf16x8*)(h_bf + (size_t)eS0 * 64 + (ks - 2) * 32 + 8 * g);
                b1 = *(const bf16x8*)(h_bf + (size_t)eS1 * 64 + (ks - 2) * 32 + 8 * g);
            } else {
                if constexpr (EPRE) {
                    b0 = *(const bf16x8*)(e_bf + (size_t)(wbase + m) * 32 + 8 * g);
                    b1 = *(const bf16x8*)(e_bf + (size_t)(wbase + 16 + m) * 32 + 8 * g);
                } else {
                    b0 = *(const bf16x8*)&eL[(32 * w + m) * 32 + 8 * g];
                    b1 = *(const bf16x8*)&eL[(32 * w + 16 + m) * 32 + 8 * g];
                }
            }
#pragma unroll
            for (int n2 = 0; n2 < 2; ++n2) {
                int nf = qt * 2 + n2;
                bf16x8 a = *(const bf16x8*)(pA1 + ((ks * 8 + nf) * 64 + lane) * 8);
                acc[0][n2] = __builtin_amdgcn_mfma_f32_16x16x32_bf16(a, b0, acc[0][n2], 0, 0, 0);
                acc[1][n2] = __builtin_amdgcn_mfma_f32_16x16x32_bf16(a, b1, acc[1][n2], 0, 0, 0);
            }
        }
        // epilogue 1 (this quarter): bias + fast softplus -> P (bf16) in LDS
#pragma unroll
        for (int n2 = 0; n2 < 2; ++n2) {
            int nf = qt * 2 + n2;
            f32x4 bb = *(const f32x4*)(be1 + 16 * nf + 4 * g);
#pragma unroll
            for (int mf = 0; mf < 2; ++mf) {
                f32x4 c = acc[mf][n2];
                unsigned int u01 = pkbf(spf(c[0] + bb[0]), spf(c[1] + bb[1]));
                unsigned int u23 = pkbf(spf(c[2] + bb[2]), spf(c[3] + bb[3]));
                unsigned int* dst = (unsigned int*)&P[w][m + 16 * mf][16 * nf + 4 * g];
                dst[0] = u01; dst[1] = u23;
            }
        }
    }

    // ---- GEMM2 (K=128) per m-fragment, two nf-halves; 8-reg deferral ----
    unsigned short (*Pf)[136] = (unsigned short(*)[136]) & P[0][0][0];
#pragma unroll
    for (int mf = 0; mf < 2; ++mf) {
        unsigned int defer[8];
#pragma unroll
        for (int half = 0; half < 2; ++half) {
            f32x4 acc2[4];
#pragma unroll
            for (int n2 = 0; n2 < 4; ++n2) acc2[n2] = (f32x4){0.f, 0.f, 0.f, 0.f};
#pragma unroll
            for (int ks = 0; ks < 4; ++ks) {
                bf16x8 b = *(const bf16x8*)&P[w][m + 16 * mf][32 * ks + 8 * g];
#pragma unroll
                for (int n2 = 0; n2 < 4; ++n2) {
                    int nf = half * 4 + n2;
                    bf16x8 a = *(const bf16x8*)(pA2 + ((ks * 8 + nf) * 64 + lane) * 8);
                    acc2[n2] = __builtin_amdgcn_mfma_f32_16x16x32_bf16(a, b, acc2[n2], 0, 0, 0);
                }
            }
            if (half == 0) {
                // defer packed outputs: writing LDS now would clobber columns
                // 0..63 that half 1's B-operand (ks=0,1) still reads.
#pragma unroll
                for (int n2 = 0; n2 < 4; ++n2) {
                    int nf = n2;
                    f32x4 bb = *(const f32x4*)(be2 + 16 * nf + 4 * g);
                    f32x4 c = acc2[n2];
                    defer[2 * n2] = pkbf(spf(c[0] + bb[0]), spf(c[1] + bb[1]));
                    defer[2 * n2 + 1] = pkbf(spf(c[2] + bb[2]), spf(c[3] + bb[3]));
                }
            } else {
                // write half 1 directly, then flush half 0's deferral
#pragma unroll
                for (int n2 = 0; n2 < 4; ++n2) {
                    int nf = 4 + n2;
                    f32x4 bb = *(const f32x4*)(be2 + 16 * nf + 4 * g);
                    f32x4 c = acc2[n2];
                    unsigned int* dst =
                        (unsigned int*)&Pf[32 * w + 16 * mf + m][16 * nf + 4 * g];
                    dst[0] = pkbf(spf(c[0] + bb[0]), spf(c[1] + bb[1]));
                    dst[1] = pkbf(spf(c[2] + bb[2]), spf(c[3] + bb[3]));
                }
#pragma unroll
                for (int n2 = 0; n2 < 4; ++n2) {
                    unsigned int* dst =
                        (unsigned int*)&Pf[32 * w + 16 * mf + m][16 * n2 + 4 * g];
                    dst[0] = defer[2 * n2];
                    dst[1] = defer[2 * n2 + 1];
                }
            }
        }
    }
    if (g == 0) {
        dstB[32 * w + m] = eD0;
        dstB[32 * w + 16 + m] = eD1;
    }
    __syncthreads();

    // ---- block-wide run-length segmented reduction ----
    int rbeg = 32 * w, rend = rbeg + 32;
    int r = rbeg;
    if (w) {  // skip rows continuing a run that started in a lower wave
        while (r < rend && dstB[r] == dstB[r - 1]) ++r;
    }
    while (r < rend) {
        int d = dstB[r];
        float a0 = 0.f, a1 = 0.f;
        int rr = r;
        do {
            unsigned int u = *(const unsigned int*)&Pf[rr][2 * lane];
            a0 += lo_bf(u);
            a1 += hi_bf(u);
            ++rr;
        } while (rr < 128 && dstB[rr] == d);
        int s0 = rowptr[d];
        bool interior = (s0 >= tile0) && (s0 + hist[d] <= tile0 + 128);
        float* base = aggr + (size_t)d * HD + 2 * lane;
        if (interior) {
            base[0] = a0;
            base[1] = a1;
        } else {
            atomicAdd(base, a0);
            atomicAdd(base + 1, a1);
        }
        r = rr;
    }
}

// ---------------- MFMA node update: 1-wave blocks, partial BN stats -----
__global__ __launch_bounds__(64, 3) void k_node_mfma(
    const unsigned short* __restrict__ h_bf, const float* __restrict__ aggr,
    const float* __restrict__ h,
    const unsigned short* __restrict__ pWn1, const float* __restrict__ bn1,
    const unsigned short* __restrict__ pWn2, const float* __restrict__ bn2,
    float* __restrict__ t, float* __restrict__ partU) {
    __shared__ unsigned short P[32][136];

    int lane = threadIdx.x;
    int m = lane & 15, g = lane >> 4;
    int wbase = blockIdx.x * 32;
    int n0 = wbase + m, n1 = wbase + 16 + m;
    bool v0 = n0 < N_NODES, v1 = n1 < N_NODES;
    int c0 = v0 ? n0 : N_NODES - 1;
    int c1 = v1 ? n1 : N_NODES - 1;

    f32x4 acc[2][8];
#pragma unroll
    for (int mf = 0; mf < 2; ++mf)
#pragma unroll
        for (int nf = 0; nf < 8; ++nf) acc[mf][nf] = (f32x4){0.f, 0.f, 0.f, 0.f};

    // ---- GEMM1: K = 192 (h 64 | aggr 128) ----
#pragma unroll
    for (int ks = 0; ks < 6; ++ks) {
        bf16x8 b0, b1;
        if (ks < 2) {
            b0 = *(const bf16x8*)(h_bf + (size_t)c0 * 64 + ks * 32 + 8 * g);
            b1 = *(const bf16x8*)(h_bf + (size_t)c1 * 64 + ks * 32 + 8 * g);
        } else {
            b0 = ld8_f32_bf(aggr + (size_t)c0 * 128 + (ks - 2) * 32 + 8 * g);
            b1 = ld8_f32_bf(aggr + (size_t)c1 * 128 + (ks - 2) * 32 + 8 * g);
        }
#pragma unroll
        for (int nf = 0; nf < 8; ++nf) {
            bf16x8 a = *(const bf16x8*)(pWn1 + ((ks * 8 + nf) * 64 + lane) * 8);
            acc[0][nf] = __builtin_amdgcn_mfma_f32_16x16x32_bf16(a, b0, acc[0][nf], 0, 0, 0);
            acc[1][nf] = __builtin_amdgcn_mfma_f32_16x16x32_bf16(a, b1, acc[1][nf], 0, 0, 0);
        }
    }

    // ---- epilogue 1: bias + fast softplus -> P (bf16) in LDS ----
#pragma unroll
    for (int nf = 0; nf < 8; ++nf) {
        f32x4 bb = *(const f32x4*)(bn1 + 16 * nf + 4 * g);
#pragma unroll
        for (int mf = 0; mf < 2; ++mf) {
            f32x4 c = acc[mf][nf];
            unsigned int u01 = pkbf(spf(c[0] + bb[0]), spf(c[1] + bb[1]));
            unsigned int u23 = pkbf(spf(c[2] + bb[2]), spf(c[3] + bb[3]));
            unsigned int* dst = (unsigned int*)&P[m + 16 * mf][16 * nf + 4 * g];
            dst[0] = u01; dst[1] = u23;
        }
    }

    f32x4 acc2[2][4];
#pragma unroll
    for (int mf = 0; mf < 2; ++mf)
#pragma unroll
        for (int nf = 0; nf < 4; ++nf) acc2[mf][nf] = (f32x4){0.f, 0.f, 0.f, 0.f};

    // ---- GEMM2: K = 128, N = 64 ----
#pragma unroll
    for (int ks = 0; ks < 4; ++ks) {
        bf16x8 b0 = *(const bf16x8*)&P[m][32 * ks + 8 * g];
        bf16x8 b1 = *(const bf16x8*)&P[m + 16][32 * ks + 8 * g];
#pragma unroll
        for (int nf = 0; nf < 4; ++nf) {
            bf16x8 a = *(const bf16x8*)(pWn2 + ((ks * 4 + nf) * 64 + lane) * 8);
            acc2[0][nf] = __builtin_amdgcn_mfma_f32_16x16x32_bf16(a, b0, acc2[0][nf], 0, 0, 0);
            acc2[1][nf] = __builtin_amdgcn_mfma_f32_16x16x32_bf16(a, b1, acc2[1][nf], 0, 0, 0);
        }
    }

    // ---- epilogue 2: +bn2 +h residual -> t; partial BN stats (no atomics)
#pragma unroll
    for (int nf = 0; nf < 4; ++nf) {
        f32x4 bb = *(const f32x4*)(bn2 + 16 * nf + 4 * g);
        f32x4 s0v = (f32x4){0.f, 0.f, 0.f, 0.f};
        f32x4 s1v = (f32x4){0.f, 0.f, 0.f, 0.f};
#pragma unroll
        for (int mf = 0; mf < 2; ++mf) {
            int cn = mf ? c1 : c0;
            bool vn = mf ? v1 : v0;
            f32x4 hv = *(const f32x4*)(h + (size_t)cn * 64 + 16 * nf + 4 * g);
            f32x4 c = acc2[mf][nf];
            f32x4 tn;
#pragma unroll
            for (int j = 0; j < 4; ++j) tn[j] = c[j] + bb[j] + hv[j];
            if (vn) *(f32x4*)(t + (size_t)cn * 64 + 16 * nf + 4 * g) = tn;
#pragma unroll
            for (int j = 0; j < 4; ++j) {
                float tv = vn ? tn[j] : 0.f;
                s0v[j] += tv;
                s1v[j] += tv * tv;
            }
        }
#pragma unroll
        for (int j = 0; j < 4; ++j) {
#pragma unroll
            for (int k = 1; k <= 8; k <<= 1) {
                s0v[j] += __shfl_xor(s0v[j], k);
                s1v[j] += __shfl_xor(s1v[j], k);
            }
        }
        if (m == 0) {
#pragma unroll
            for (int j = 0; j < 4; ++j) {
                int ch = 16 * nf + 4 * g + j;
                partU[(size_t)blockIdx.x * 128 + ch] = s0v[j];
                partU[(size_t)blockIdx.x * 128 + 64 + ch] = s1v[j];
            }
        }
    }
}

// ---------------- pooling + readout (unchanged) -------------------------
__global__ __launch_bounds__(256) void k_pool(
    const float* __restrict__ h, const int* __restrict__ batch,
    float* __restrict__ pooled, float* __restrict__ cnt) {
    int lane = threadIdx.x & 63;
    int wave = (blockIdx.x * blockDim.x + threadIdx.x) >> 6;
    int nw = (gridDim.x * blockDim.x) >> 6;
    int chunk = (N_NODES + nw - 1) / nw;
    int s = wave * chunk;
    int epos = min(N_NODES, s + chunk);
    if (s >= N_NODES) return;
    int curg = batch[s];
    float acc = 0.f, c = 0.f;
    for (int i = s; i < epos; ++i) {
        int g = batch[i];
        if (g != curg) {
            atomicAdd(&pooled[curg * ND + lane], acc);
            if (lane == 0) atomicAdd(&cnt[curg], c);
            acc = 0.f; c = 0.f; curg = g;
        }
        acc += h[i * ND + lane];
        c += 1.f;
    }
    atomicAdd(&pooled[curg * ND + lane], acc);
    if (lane == 0) atomicAdd(&cnt[curg], c);
}

__global__ __launch_bounds__(256) void k_readout(
    const float* __restrict__ pooled, const float* __restrict__ cnt,
    const float* __restrict__ Wo1, const float* __restrict__ bo1,
    const float* __restrict__ Wo2, const float* __restrict__ bo2,
    float* __restrict__ out) {
    __shared__ float pbuf[WPB][ND];
    int lane = threadIdx.x & 63;
    int wid = threadIdx.x >> 6;
    int g = blockIdx.x * WPB + wid;
    bool valid = g < N_GRAPH;
    int gc = valid ? g : N_GRAPH - 1;
    float c = fmaxf(cnt[gc], 1.f);
    pbuf[wid][lane] = pooled[gc * ND + lane] / c;
    __syncthreads();
    float h0 = bo1[lane], h1 = bo1[64 + lane];
#pragma unroll 8
    for (int k = 0; k < ND; ++k) {
        float pk = pbuf[wid][k];
        h0 += pk * Wo1[k * HD + lane];
        h1 += pk * Wo1[k * HD + 64 + lane];
    }
    float s = sp(h0) * Wo2[lane] + sp(h1) * Wo2[64 + lane];
#pragma unroll
    for (int off = 32; off; off >>= 1) s += __shfl_down(s, off);
    if (valid && lane == 0) out[g] = s + bo2[0];
}

extern "C" void kernel_launch(void* const* d_in, const int* in_sizes, int n_in,
                              void* d_out, int out_size, void* d_ws, size_t ws_size,
                              hipStream_t stream) {
    const float* x       = (const float*)d_in[0];
    const float* ea      = (const float*)d_in[1];
    const int*   ei      = (const int*)d_in[2];
    const int*   batch   = (const int*)d_in[3];
    const float* Wnp     = (const float*)d_in[4];
    const float* bnp     = (const float*)d_in[5];
    const float* g_np    = (const float*)d_in[6];
    const float* be_np   = (const float*)d_in[7];
    const float* Wep     = (const float*)d_in[8];
    const float* bep     = (const float*)d_in[9];
    const float* We1     = (const float*)d_in[10];
    const float* be1     = (const float*)d_in[11];
    const float* We2     = (const float*)d_in[12];
    const float* be2     = (const float*)d_in[13];
    const float* Wn1     = (const float*)d_in[14];
    const float* bn1     = (const float*)d_in[15];
    const float* Wn2     = (const float*)d_in[16];
    const float* bn2     = (const float*)d_in[17];
    const float* g_bn    = (const float*)d_in[18];
    const float* b_bn    = (const float*)d_in[19];
    const float* Wo1     = (const float*)d_in[20];
    const float* bo1     = (const float*)d_in[21];
    const float* Wo2     = (const float*)d_in[22];
    const float* bo2     = (const float*)d_in[23];

    float* ws = (float*)d_ws;
    size_t off = 0;
    float* h      = ws + off; off += (size_t)N_NODES * ND;
    float* t      = ws + off; off += (size_t)N_NODES * ND;
    float* aggr   = ws + off; off += (size_t)N_NODES * HD;
    float* ss     = ws + off; off += 2 * ND;
    float* pooled = ws + off; off += N_GRAPH * ND;
    float* cnt    = ws + off; off += 512;
    unsigned short* h_bf = (unsigned short*)(ws + off); off += (size_t)N_NODES * ND / 2;
    unsigned short* pA1  = (unsigned short*)(ws + off); off += 3 * 5 * 8 * 64 * 8 / 2;
    unsigned short* pA2  = (unsigned short*)(ws + off); off += 3 * 4 * 8 * 64 * 8 / 2;
    unsigned short* pWn1 = (unsigned short*)(ws + off); off += 3 * 6 * 8 * 64 * 8 / 2;
    unsigned short* pWn2 = (unsigned short*)(ws + off); off += 3 * 4 * 4 * 64 * 8 / 2;
    int* sD       = (int*)(ws + off); off += N_EDGES;
    int* sS       = (int*)(ws + off); off += N_EDGES;
    int* sE       = (int*)(ws + off); off += N_EDGES;
    int* hist     = (int*)(ws + off); off += N_NODES;
    int* cursor   = (int*)(ws + off); off += N_NODES;
    int* rowptr   = (int*)(ws + off); off += N_NODES;
    int* chunksum = (int*)(ws + off); off += 64;
    float* partN  = ws + off; off += 512 * 128;
    float* partU  = ws + off; off += (size_t)NBU * 128;
    size_t base_bytes = off * sizeof(float);
    unsigned short* e_bf = (unsigned short*)(ws + off);
    bool epre = (ws_size >= base_bytes + (size_t)N_EDGES * 32 * 2);

    float* outp = (float*)d_out;

    const int NCH = (N_NODES + 1023) / 1024;  // 49

    // ---- counting sort of edges by dst -> CSR (once per call) ----
    hipMemsetAsync(hist, 0, N_NODES * sizeof(int), stream);
    k_hist<<<(N_EDGES + 255) / 256, 256, 0, stream>>>(ei, hist);
    k_scan1<<<NCH, 1024, 0, stream>>>(hist, chunksum);
    k_scan2<<<1, 64, 0, stream>>>(chunksum, NCH);
    k_scan3<<<NCH, 1024, 0, stream>>>(hist, chunksum, cursor, rowptr);
    k_scatter<<<(N_EDGES + 255) / 256, 256, 0, stream>>>(ei, cursor, sD, sS, sE);
    if (epre)
        k_eproj_sorted<<<(int)(((long)N_EDGES * 32 + 255) / 256), 256, 0, stream>>>(
            ea, sE, Wep, bep, e_bf);

    // ---- pack all weights (3 layers x 4 matrices) in one launch ----
    k_pack_all<<<(3 * 8704 + 255) / 256, 256, 0, stream>>>(
        We1, We2, Wn1, Wn2, pA1, pA2, pWn1, pWn2);

    // ---- node projection + BN (two-stage stats, no contended atomics) ----
    k_node_proj<<<512, 256, 0, stream>>>(x, Wnp, bnp, t, partN);
    k_stats_reduce<<<1, 256, 0, stream>>>(partN, 512, g_np, be_np, ss);
    k_bn_apply<<<2048, 256, 0, stream>>>(t, ss, h, h_bf);

    for (int l = 0; l < 3; ++l) {
        hipMemsetAsync(aggr, 0, (size_t)N_NODES * HD * sizeof(float), stream);
        if (epre)
            k_edge_mfma_s<true><<<N_EDGES / 128, 256, 0, stream>>>(
                h_bf, e_bf, ea, sE, Wep, bep, sD, sS, rowptr, hist,
                pA1 + (size_t)l * 40 * 64 * 8, be1 + l * HD,
                pA2 + (size_t)l * 32 * 64 * 8, be2 + l * HD, aggr);
        else
            k_edge_mfma_s<false><<<N_EDGES / 128, 256, 0, stream>>>(
                h_bf, e_bf, ea, sE, Wep, bep, sD, sS, rowptr, hist,
                pA1 + (size_t)l * 40 * 64 * 8, be1 + l * HD,
                pA2 + (size_t)l * 32 * 64 * 8, be2 + l * HD, aggr);

        k_node_mfma<<<NBU, 64, 0, stream>>>(
            h_bf, aggr, h,
            pWn1 + (size_t)l * 48 * 64 * 8, bn1 + l * HD,
            pWn2 + (size_t)l * 16 * 64 * 8, bn2 + l * ND, t, partU);
        k_stats_reduce<<<1, 256, 0, stream>>>(partU, NBU, g_bn + l * ND, b_bn + l * ND, ss);
        k_bn_apply<<<2048, 256, 0, stream>>>(t, ss, h, h_bf);
    }

    hipMemsetAsync(pooled, 0, (size_t)(N_GRAPH * ND + 512) * sizeof(float), stream);
    k_pool<<<512, 256, 0, stream>>>(h, batch, pooled, cnt);
    k_readout<<<(N_GRAPH + WPB - 1) / WPB, 256, 0, stream>>>(
        pooled, cnt, Wo1, bo1, Wo2, bo2, outp);
}

// Round 24
// 1178.369 us; speedup vs baseline: 1.0031x; 1.0031x over previous
//
#include <hip/hip_runtime.h>
#include <hip/hip_bf16.h>

#define N_NODES 50000
#define N_EDGES 800000
#define N_GRAPH 500
#define ND 64
#define ED 32
#define HD 128
#define WPB 4   // waves per block (256 threads)
#define NBU ((N_NODES + 31) / 32)   // 1563 one-wave node blocks

typedef __attribute__((ext_vector_type(8))) short bf16x8;
typedef __attribute__((ext_vector_type(4))) float f32x4;

__device__ __forceinline__ float sp(float x) {
    return fmaxf(x, 0.f) + log1pf(expf(-fabsf(x)));
}

// fast softplus for the bf16 path (v_exp_f32/v_log_f32 based)
__device__ __forceinline__ float spf(float x) {
    return fmaxf(x, 0.f) + __logf(1.f + __expf(-fabsf(x)));
}

__device__ __forceinline__ unsigned short f2bf(float v) {
    __hip_bfloat16 b = __float2bfloat16(v);
    return *(unsigned short*)&b;
}

__device__ __forceinline__ unsigned int pkbf(float a, float b) {
    return (unsigned int)f2bf(a) | ((unsigned int)f2bf(b) << 16);
}

__device__ __forceinline__ float lo_bf(unsigned int u) { return __uint_as_float(u << 16); }
__device__ __forceinline__ float hi_bf(unsigned int u) { return __uint_as_float(u & 0xffff0000u); }

// load 8 fp32 and round to bf16x8 (same RNE as k_bn_apply/f2bf)
__device__ __forceinline__ bf16x8 ld8_f32_bf(const float* p) {
    f32x4 v0 = *(const f32x4*)p;
    f32x4 v1 = *(const f32x4*)(p + 4);
    bf16x8 r;
    r[0] = (short)f2bf(v0[0]); r[1] = (short)f2bf(v0[1]);
    r[2] = (short)f2bf(v0[2]); r[3] = (short)f2bf(v0[3]);
    r[4] = (short)f2bf(v1[0]); r[5] = (short)f2bf(v1[1]);
    r[6] = (short)f2bf(v1[2]); r[7] = (short)f2bf(v1[3]);
    return r;
}

// ---------------- node projection: partial BN stats per block -----------
__global__ __launch_bounds__(256) void k_node_proj(
    const float* __restrict__ x, const float* __restrict__ Wnp,
    const float* __restrict__ bnp, float* __restrict__ t,
    float* __restrict__ partN) {
    __shared__ float red0[4][64], red1[4][64];
    int lane = threadIdx.x & 63;
    int wid = threadIdx.x >> 6;
    int wave = (blockIdx.x * blockDim.x + threadIdx.x) >> 6;
    int nw = (gridDim.x * blockDim.x) >> 6;
    float w[13];
#pragma unroll
    for (int k = 0; k < 13; ++k) w[k] = Wnp[k * ND + lane];
    float bb = bnp[lane];
    float s0 = 0.f, s1 = 0.f;
    for (int i = wave; i < N_NODES; i += nw) {
        float acc = bb;
#pragma unroll
        for (int k = 0; k < 13; ++k) acc += x[i * 13 + k] * w[k];
        float v = sp(acc);
        t[i * ND + lane] = v;
        s0 += v; s1 += v * v;
    }
    red0[wid][lane] = s0;
    red1[wid][lane] = s1;
    __syncthreads();
    int tid = threadIdx.x;
    if (tid < 64)
        partN[blockIdx.x * 128 + tid] =
            red0[0][tid] + red0[1][tid] + red0[2][tid] + red0[3][tid];
    else if (tid < 128) {
        int c = tid - 64;
        partN[blockIdx.x * 128 + tid] =
            red1[0][c] + red1[1][c] + red1[2][c] + red1[3][c];
    }
}

// ---- two-stage BN stats: sum R partial rows, emit scale/shift ----------
__global__ void k_stats_reduce(const float* __restrict__ part, int R,
                               const float* __restrict__ g,
                               const float* __restrict__ b,
                               float* __restrict__ ss) {
    __shared__ float r0[4][64], r1[4][64];
    int q = threadIdx.x >> 6, c = threadIdx.x & 63;
    float S0 = 0.f, S1 = 0.f;
    for (int r = q; r < R; r += 4) {
        S0 += part[(size_t)r * 128 + c];
        S1 += part[(size_t)r * 128 + 64 + c];
    }
    r0[q][c] = S0; r1[q][c] = S1;
    __syncthreads();
    if (threadIdx.x < 64) {
        float s0 = r0[0][c] + r0[1][c] + r0[2][c] + r0[3][c];
        float s1 = r1[0][c] + r1[1][c] + r1[2][c] + r1[3][c];
        float inv_n = 1.f / (float)N_NODES;
        float mu = s0 * inv_n;
        float var = s1 * inv_n - mu * mu;
        float rs = rsqrtf(var + 1e-5f);
        float sc = rs * g[c];
        ss[c] = sc;
        ss[64 + c] = b[c] - mu * sc;
    }
}

// vectorized BN apply: 8 elements/thread (channels contiguous, 8 | 64)
__global__ __launch_bounds__(256) void k_bn_apply(
    const float* __restrict__ t, const float* __restrict__ ss,
    float* __restrict__ h, unsigned short* __restrict__ hb) {
    int idx = (blockIdx.x * 256 + threadIdx.x) * 8;
    if (idx >= N_NODES * ND) return;
    int c = idx & (ND - 1);
    f32x4 sc0 = *(const f32x4*)(ss + c);
    f32x4 sc1 = *(const f32x4*)(ss + c + 4);
    f32x4 sh0 = *(const f32x4*)(ss + ND + c);
    f32x4 sh1 = *(const f32x4*)(ss + ND + c + 4);
    f32x4 v0 = *(const f32x4*)(t + idx);
    f32x4 v1 = *(const f32x4*)(t + idx + 4);
    f32x4 r0, r1;
#pragma unroll
    for (int j = 0; j < 4; ++j) { r0[j] = v0[j] * sc0[j] + sh0[j]; r1[j] = v1[j] * sc1[j] + sh1[j]; }
    *(f32x4*)(h + idx) = r0;
    *(f32x4*)(h + idx + 4) = r1;
    bf16x8 rb;
    rb[0] = (short)f2bf(r0[0]); rb[1] = (short)f2bf(r0[1]);
    rb[2] = (short)f2bf(r0[2]); rb[3] = (short)f2bf(r0[3]);
    rb[4] = (short)f2bf(r1[0]); rb[5] = (short)f2bf(r1[1]);
    rb[6] = (short)f2bf(r1[2]); rb[7] = (short)f2bf(r1[3]);
    *(bf16x8*)(hb + idx) = rb;
}

// ---------------- counting sort of edges by dst -------------------------
__global__ __launch_bounds__(256) void k_hist(const int* __restrict__ ei,
                                              int* __restrict__ hist) {
    int e = blockIdx.x * 256 + threadIdx.x;
    if (e < N_EDGES) atomicAdd(&hist[ei[N_EDGES + e]], 1);
}

__global__ __launch_bounds__(1024) void k_scan1(const int* __restrict__ hist,
                                                int* __restrict__ chunksum) {
    __shared__ int s[1024];
    int t = threadIdx.x;
    int i = blockIdx.x * 1024 + t;
    s[t] = (i < N_NODES) ? hist[i] : 0;
    __syncthreads();
    for (int off = 512; off; off >>= 1) {
        if (t < off) s[t] += s[t + off];
        __syncthreads();
    }
    if (t == 0) chunksum[blockIdx.x] = s[0];
}

__global__ void k_scan2(int* __restrict__ chunksum, int n) {
    if (threadIdx.x == 0) {
        int acc = 0;
        for (int i = 0; i < n; ++i) { int v = chunksum[i]; chunksum[i] = acc; acc += v; }
    }
}

__global__ __launch_bounds__(1024) void k_scan3(const int* __restrict__ hist,
                                                const int* __restrict__ chunksum,
                                                int* __restrict__ cursor,
                                                int* __restrict__ rowptr) {
    __shared__ int s[1024];
    int t = threadIdx.x;
    int i = blockIdx.x * 1024 + t;
    int v = (i < N_NODES) ? hist[i] : 0;
    s[t] = v;
    __syncthreads();
    for (int off = 1; off < 1024; off <<= 1) {
        int u = (t >= off) ? s[t - off] : 0;
        __syncthreads();
        s[t] += u;
        __syncthreads();
    }
    if (i < N_NODES) {
        int ex = chunksum[blockIdx.x] + s[t] - v;  // exclusive
        cursor[i] = ex;
        rowptr[i] = ex;
    }
}

__global__ __launch_bounds__(256) void k_scatter(const int* __restrict__ ei,
                                                 int* __restrict__ cursor,
                                                 int* __restrict__ sD,
                                                 int* __restrict__ sS,
                                                 int* __restrict__ sE) {
    int e = blockIdx.x * 256 + threadIdx.x;
    if (e >= N_EDGES) return;
    int d = ei[N_EDGES + e];
    int pos = atomicAdd(&cursor[d], 1);
    sD[pos] = d;
    sS[pos] = ei[e];
    sE[pos] = e;
}

// edge projection into sorted order (layer-invariant, once per call)
__global__ __launch_bounds__(256) void k_eproj_sorted(
    const float* __restrict__ ea, const int* __restrict__ sE,
    const float* __restrict__ Wep, const float* __restrict__ bep,
    unsigned short* __restrict__ e_bf) {
    long idx = (long)blockIdx.x * blockDim.x + threadIdx.x;
    long tot = (long)N_EDGES * 32;
    if (idx >= tot) return;
    int p = (int)(idx >> 5), col = (int)(idx & 31);
    int e = sE[p];
    float v = spf(ea[2 * e] * Wep[col] + ea[2 * e + 1] * Wep[32 + col] + bep[col]);
    e_bf[idx] = f2bf(v);
}

// ---- fused weight pack: all 3 layers x {We1,We2,Wn1,Wn2} in ONE launch --
__global__ __launch_bounds__(256) void k_pack_all(
    const float* __restrict__ We1, const float* __restrict__ We2,
    const float* __restrict__ Wn1, const float* __restrict__ Wn2,
    unsigned short* __restrict__ pA1, unsigned short* __restrict__ pA2,
    unsigned short* __restrict__ pWn1, unsigned short* __restrict__ pWn2) {
    int tid = blockIdx.x * 256 + threadIdx.x;
    const int PER_L = (40 + 32 + 48 + 16) * 64;  // 8704
    if (tid >= 3 * PER_L) return;
    int layer = tid / PER_L;
    int r = tid % PER_L;
    const float* W;
    unsigned short* out;
    int ncols, lt;
    if (r < 40 * 64) {
        lt = r; W = We1 + (size_t)layer * 160 * 128; out = pA1 + (size_t)layer * 40 * 64 * 8;
        ncols = 128;
    } else if (r < 72 * 64) {
        lt = r - 40 * 64; W = We2 + (size_t)layer * 128 * 128; out = pA2 + (size_t)layer * 32 * 64 * 8;
        ncols = 128;
    } else if (r < 120 * 64) {
        lt = r - 72 * 64; W = Wn1 + (size_t)layer * 192 * 128; out = pWn1 + (size_t)layer * 48 * 64 * 8;
        ncols = 128;
    } else {
        lt = r - 120 * 64; W = Wn2 + (size_t)layer * 128 * 64; out = pWn2 + (size_t)layer * 16 * 64 * 8;
        ncols = 64;
    }
    int nfrag = ncols >> 4;
    int l = lt & 63; int fr = lt >> 6; int nf = fr % nfrag; int ks = fr / nfrag;
    int n = 16 * nf + (l & 15);
    int k0 = 32 * ks + 8 * (l >> 4);
#pragma unroll
    for (int rr = 0; rr < 8; ++rr)
        out[lt * 8 + rr] = f2bf(W[(k0 + rr) * ncols + n]);
}

// ---------------- MFMA edge conv on dst-sorted edges --------------------
// Fully register-bounded for 4 blocks/CU:
//  - GEMM1 in QUARTERS (2 nf): <=10 A-loads + 16 AGPR acc per region.
//  - GEMM2 per m-fragment in two nf-halves (16 A-loads, acc2[4]); half 0's
//    packed output deferred in 8 uints, half 1 writes both.
template <bool EPRE>
__global__ __launch_bounds__(256, 4) void k_edge_mfma_s(
    const unsigned short* __restrict__ h_bf, const unsigned short* __restrict__ e_bf,
    const float* __restrict__ ea, const int* __restrict__ sE,
    const float* __restrict__ Wep, const float* __restrict__ bep,
    const int* __restrict__ sD, const int* __restrict__ sS,
    const int* __restrict__ rowptr, const int* __restrict__ hist,
    const unsigned short* __restrict__ pA1, const float* __restrict__ be1,
    const unsigned short* __restrict__ pA2, const float* __restrict__ be2,
    float* __restrict__ aggr) {
    __shared__ unsigned short P[WPB][32][136];   // per-wave P; reused as 128-row stage
    __shared__ int dstB[128];
    __shared__ unsigned short eL[EPRE ? 64 : 128 * 32];

    int lane = threadIdx.x & 63;
    int w = threadIdx.x >> 6;
    int m = lane & 15, g = lane >> 4;
    int tile0 = blockIdx.x * 128;
    int wbase = tile0 + 32 * w;

    int eD0 = sD[wbase + m];
    int eD1 = sD[wbase + 16 + m];
    int eS0 = sS[wbase + m];
    int eS1 = sS[wbase + 16 + m];

    if constexpr (!EPRE) {
        int col = threadIdx.x & 31;
        int r0 = threadIdx.x >> 5;
        float w0 = Wep[col], w1 = Wep[32 + col], bb = bep[col];
#pragma unroll
        for (int i = 0; i < 16; ++i) {
            int em = r0 + 8 * i;
            int e = sE[tile0 + em];
            eL[em * 32 + col] = f2bf(spf(ea[2 * e] * w0 + ea[2 * e + 1] * w1 + bb));
        }
        __syncthreads();
    }

    // ---- GEMM1 (K=160) in four nf-quarters: acc = 16 AGPR per region ----
#pragma unroll
    for (int qt = 0; qt < 4; ++qt) {
        f32x4 acc[2][2];
#pragma unroll
        for (int mf = 0; mf < 2; ++mf)
#pragma unroll
            for (int n2 = 0; n2 < 2; ++n2) acc[mf][n2] = (f32x4){0.f, 0.f, 0.f, 0.f};
#pragma unroll
        for (int ks = 0; ks < 5; ++ks) {
            bf16x8 b0, b1;
            if (ks < 2) {
                b0 = *(const bf16x8*)(h_bf + (size_t)eD0 * 64 + ks * 32 + 8 * g);
                b1 = *(const bf16x8*)(h_bf + (size_t)eD1 * 64 + ks * 32 + 8 * g);
            } else if (ks < 4) {
                b0 = *(const bf16x8*)(h_bf + (size_t)eS0 * 64 + (ks - 2) * 32 + 8 * g);
                b1 = *(const bf16x8*)(h_bf + (size_t)eS1 * 64 + (ks - 2) * 32 + 8 * g);
            } else {
                if constexpr (EPRE) {
                    b0 = *(const bf16x8*)(e_bf + (size_t)(wbase + m) * 32 + 8 * g);
                    b1 = *(const bf16x8*)(e_bf + (size_t)(wbase + 16 + m) * 32 + 8 * g);
                } else {
                    b0 = *(const bf16x8*)&eL[(32 * w + m) * 32 + 8 * g];
                    b1 = *(const bf16x8*)&eL[(32 * w + 16 + m) * 32 + 8 * g];
                }
            }
#pragma unroll
            for (int n2 = 0; n2 < 2; ++n2) {
                int nf = qt * 2 + n2;
                bf16x8 a = *(const bf16x8*)(pA1 + ((ks * 8 + nf) * 64 + lane) * 8);
                acc[0][n2] = __builtin_amdgcn_mfma_f32_16x16x32_bf16(a, b0, acc[0][n2], 0, 0, 0);
                acc[1][n2] = __builtin_amdgcn_mfma_f32_16x16x32_bf16(a, b1, acc[1][n2], 0, 0, 0);
            }
        }
        // epilogue 1 (this quarter): bias + fast softplus -> P (bf16) in LDS
#pragma unroll
        for (int n2 = 0; n2 < 2; ++n2) {
            int nf = qt * 2 + n2;
            f32x4 bb = *(const f32x4*)(be1 + 16 * nf + 4 * g);
#pragma unroll
            for (int mf = 0; mf < 2; ++mf) {
                f32x4 c = acc[mf][n2];
                unsigned int u01 = pkbf(spf(c[0] + bb[0]), spf(c[1] + bb[1]));
                unsigned int u23 = pkbf(spf(c[2] + bb[2]), spf(c[3] + bb[3]));
                unsigned int* dst = (unsigned int*)&P[w][m + 16 * mf][16 * nf + 4 * g];
                dst[0] = u01; dst[1] = u23;
            }
        }
    }

    // ---- GEMM2 (K=128) per m-fragment, two nf-halves; 8-reg deferral ----
    unsigned short (*Pf)[136] = (unsigned short(*)[136]) & P[0][0][0];
#pragma unroll
    for (int mf = 0; mf < 2; ++mf) {
        unsigned int defer[8];
#pragma unroll
        for (int half = 0; half < 2; ++half) {
            f32x4 acc2[4];
#pragma unroll
            for (int n2 = 0; n2 < 4; ++n2) acc2[n2] = (f32x4){0.f, 0.f, 0.f, 0.f};
#pragma unroll
            for (int ks = 0; ks < 4; ++ks) {
                bf16x8 b = *(const bf16x8*)&P[w][m + 16 * mf][32 * ks + 8 * g];
#pragma unroll
                for (int n2 = 0; n2 < 4; ++n2) {
                    int nf = half * 4 + n2;
                    bf16x8 a = *(const bf16x8*)(pA2 + ((ks * 8 + nf) * 64 + lane) * 8);
                    acc2[n2] = __builtin_amdgcn_mfma_f32_16x16x32_bf16(a, b, acc2[n2], 0, 0, 0);
                }
            }
            if (half == 0) {
#pragma unroll
                for (int n2 = 0; n2 < 4; ++n2) {
                    int nf = n2;
                    f32x4 bb = *(const f32x4*)(be2 + 16 * nf + 4 * g);
                    f32x4 c = acc2[n2];
                    defer[2 * n2] = pkbf(spf(c[0] + bb[0]), spf(c[1] + bb[1]));
                    defer[2 * n2 + 1] = pkbf(spf(c[2] + bb[2]), spf(c[3] + bb[3]));
                }
            } else {
#pragma unroll
                for (int n2 = 0; n2 < 4; ++n2) {
                    int nf = 4 + n2;
                    f32x4 bb = *(const f32x4*)(be2 + 16 * nf + 4 * g);
                    f32x4 c = acc2[n2];
                    unsigned int* dst =
                        (unsigned int*)&Pf[32 * w + 16 * mf + m][16 * nf + 4 * g];
                    dst[0] = pkbf(spf(c[0] + bb[0]), spf(c[1] + bb[1]));
                    dst[1] = pkbf(spf(c[2] + bb[2]), spf(c[3] + bb[3]));
                }
#pragma unroll
                for (int n2 = 0; n2 < 4; ++n2) {
                    unsigned int* dst =
                        (unsigned int*)&Pf[32 * w + 16 * mf + m][16 * n2 + 4 * g];
                    dst[0] = defer[2 * n2];
                    dst[1] = defer[2 * n2 + 1];
                }
            }
        }
    }
    if (g == 0) {
        dstB[32 * w + m] = eD0;
        dstB[32 * w + 16 + m] = eD1;
    }
    __syncthreads();

    // ---- block-wide run-length segmented reduction ----
    int rbeg = 32 * w, rend = rbeg + 32;
    int r = rbeg;
    if (w) {  // skip rows continuing a run that started in a lower wave
        while (r < rend && dstB[r] == dstB[r - 1]) ++r;
    }
    while (r < rend) {
        int d = dstB[r];
        float a0 = 0.f, a1 = 0.f;
        int rr = r;
        do {
            unsigned int u = *(const unsigned int*)&Pf[rr][2 * lane];
            a0 += lo_bf(u);
            a1 += hi_bf(u);
            ++rr;
        } while (rr < 128 && dstB[rr] == d);
        int s0 = rowptr[d];
        bool interior = (s0 >= tile0) && (s0 + hist[d] <= tile0 + 128);
        float* base = aggr + (size_t)d * HD + 2 * lane;
        if (interior) {
            base[0] = a0;
            base[1] = a1;
        } else {
            atomicAdd(base, a0);
            atomicAdd(base + 1, a1);
        }
        r = rr;
    }
}

// ---------------- MFMA node update: 1-wave blocks, partial BN stats -----
// (64,2): 256-reg cap removes any GEMM1 A-hoist spill; grid (1563 blocks,
// ~6/CU) is grid-limited so the looser bound costs no occupancy.
__global__ __launch_bounds__(64, 2) void k_node_mfma(
    const unsigned short* __restrict__ h_bf, const float* __restrict__ aggr,
    const float* __restrict__ h,
    const unsigned short* __restrict__ pWn1, const float* __restrict__ bn1,
    const unsigned short* __restrict__ pWn2, const float* __restrict__ bn2,
    float* __restrict__ t, float* __restrict__ partU) {
    __shared__ unsigned short P[32][136];

    int lane = threadIdx.x;
    int m = lane & 15, g = lane >> 4;
    int wbase = blockIdx.x * 32;
    int n0 = wbase + m, n1 = wbase + 16 + m;
    bool v0 = n0 < N_NODES, v1 = n1 < N_NODES;
    int c0 = v0 ? n0 : N_NODES - 1;
    int c1 = v1 ? n1 : N_NODES - 1;

    f32x4 acc[2][8];
#pragma unroll
    for (int mf = 0; mf < 2; ++mf)
#pragma unroll
        for (int nf = 0; nf < 8; ++nf) acc[mf][nf] = (f32x4){0.f, 0.f, 0.f, 0.f};

    // ---- GEMM1: K = 192 (h 64 | aggr 128) ----
#pragma unroll
    for (int ks = 0; ks < 6; ++ks) {
        bf16x8 b0, b1;
        if (ks < 2) {
            b0 = *(const bf16x8*)(h_bf + (size_t)c0 * 64 + ks * 32 + 8 * g);
            b1 = *(const bf16x8*)(h_bf + (size_t)c1 * 64 + ks * 32 + 8 * g);
        } else {
            b0 = ld8_f32_bf(aggr + (size_t)c0 * 128 + (ks - 2) * 32 + 8 * g);
            b1 = ld8_f32_bf(aggr + (size_t)c1 * 128 + (ks - 2) * 32 + 8 * g);
        }
#pragma unroll
        for (int nf = 0; nf < 8; ++nf) {
            bf16x8 a = *(const bf16x8*)(pWn1 + ((ks * 8 + nf) * 64 + lane) * 8);
            acc[0][nf] = __builtin_amdgcn_mfma_f32_16x16x32_bf16(a, b0, acc[0][nf], 0, 0, 0);
            acc[1][nf] = __builtin_amdgcn_mfma_f32_16x16x32_bf16(a, b1, acc[1][nf], 0, 0, 0);
        }
    }

    // ---- epilogue 1: bias + fast softplus -> P (bf16) in LDS ----
#pragma unroll
    for (int nf = 0; nf < 8; ++nf) {
        f32x4 bb = *(const f32x4*)(bn1 + 16 * nf + 4 * g);
#pragma unroll
        for (int mf = 0; mf < 2; ++mf) {
            f32x4 c = acc[mf][nf];
            unsigned int u01 = pkbf(spf(c[0] + bb[0]), spf(c[1] + bb[1]));
            unsigned int u23 = pkbf(spf(c[2] + bb[2]), spf(c[3] + bb[3]));
            unsigned int* dst = (unsigned int*)&P[m + 16 * mf][16 * nf + 4 * g];
            dst[0] = u01; dst[1] = u23;
        }
    }

    f32x4 acc2[2][4];
#pragma unroll
    for (int mf = 0; mf < 2; ++mf)
#pragma unroll
        for (int nf = 0; nf < 4; ++nf) acc2[mf][nf] = (f32x4){0.f, 0.f, 0.f, 0.f};

    // ---- GEMM2: K = 128, N = 64 ----
#pragma unroll
    for (int ks = 0; ks < 4; ++ks) {
        bf16x8 b0 = *(const bf16x8*)&P[m][32 * ks + 8 * g];
        bf16x8 b1 = *(const bf16x8*)&P[m + 16][32 * ks + 8 * g];
#pragma unroll
        for (int nf = 0; nf < 4; ++nf) {
            bf16x8 a = *(const bf16x8*)(pWn2 + ((ks * 4 + nf) * 64 + lane) * 8);
            acc2[0][nf] = __builtin_amdgcn_mfma_f32_16x16x32_bf16(a, b0, acc2[0][nf], 0, 0, 0);
            acc2[1][nf] = __builtin_amdgcn_mfma_f32_16x16x32_bf16(a, b1, acc2[1][nf], 0, 0, 0);
        }
    }

    // ---- epilogue 2: +bn2 +h residual -> t; partial BN stats (no atomics)
#pragma unroll
    for (int nf = 0; nf < 4; ++nf) {
        f32x4 bb = *(const f32x4*)(bn2 + 16 * nf + 4 * g);
        f32x4 s0v = (f32x4){0.f, 0.f, 0.f, 0.f};
        f32x4 s1v = (f32x4){0.f, 0.f, 0.f, 0.f};
#pragma unroll
        for (int mf = 0; mf < 2; ++mf) {
            int cn = mf ? c1 : c0;
            bool vn = mf ? v1 : v0;
            f32x4 hv = *(const f32x4*)(h + (size_t)cn * 64 + 16 * nf + 4 * g);
            f32x4 c = acc2[mf][nf];
            f32x4 tn;
#pragma unroll
            for (int j = 0; j < 4; ++j) tn[j] = c[j] + bb[j] + hv[j];
            if (vn) *(f32x4*)(t + (size_t)cn * 64 + 16 * nf + 4 * g) = tn;
#pragma unroll
            for (int j = 0; j < 4; ++j) {
                float tv = vn ? tn[j] : 0.f;
                s0v[j] += tv;
                s1v[j] += tv * tv;
            }
        }
#pragma unroll
        for (int j = 0; j < 4; ++j) {
#pragma unroll
            for (int k = 1; k <= 8; k <<= 1) {
                s0v[j] += __shfl_xor(s0v[j], k);
                s1v[j] += __shfl_xor(s1v[j], k);
            }
        }
        if (m == 0) {
#pragma unroll
            for (int j = 0; j < 4; ++j) {
                int ch = 16 * nf + 4 * g + j;
                partU[(size_t)blockIdx.x * 128 + ch] = s0v[j];
                partU[(size_t)blockIdx.x * 128 + 64 + ch] = s1v[j];
            }
        }
    }
}

// ---------------- pooling + readout (unchanged) -------------------------
__global__ __launch_bounds__(256) void k_pool(
    const float* __restrict__ h, const int* __restrict__ batch,
    float* __restrict__ pooled, float* __restrict__ cnt) {
    int lane = threadIdx.x & 63;
    int wave = (blockIdx.x * blockDim.x + threadIdx.x) >> 6;
    int nw = (gridDim.x * blockDim.x) >> 6;
    int chunk = (N_NODES + nw - 1) / nw;
    int s = wave * chunk;
    int epos = min(N_NODES, s + chunk);
    if (s >= N_NODES) return;
    int curg = batch[s];
    float acc = 0.f, c = 0.f;
    for (int i = s; i < epos; ++i) {
        int g = batch[i];
        if (g != curg) {
            atomicAdd(&pooled[curg * ND + lane], acc);
            if (lane == 0) atomicAdd(&cnt[curg], c);
            acc = 0.f; c = 0.f; curg = g;
        }
        acc += h[i * ND + lane];
        c += 1.f;
    }
    atomicAdd(&pooled[curg * ND + lane], acc);
    if (lane == 0) atomicAdd(&cnt[curg], c);
}

__global__ __launch_bounds__(256) void k_readout(
    const float* __restrict__ pooled, const float* __restrict__ cnt,
    const float* __restrict__ Wo1, const float* __restrict__ bo1,
    const float* __restrict__ Wo2, const float* __restrict__ bo2,
    float* __restrict__ out) {
    __shared__ float pbuf[WPB][ND];
    int lane = threadIdx.x & 63;
    int wid = threadIdx.x >> 6;
    int g = blockIdx.x * WPB + wid;
    bool valid = g < N_GRAPH;
    int gc = valid ? g : N_GRAPH - 1;
    float c = fmaxf(cnt[gc], 1.f);
    pbuf[wid][lane] = pooled[gc * ND + lane] / c;
    __syncthreads();
    float h0 = bo1[lane], h1 = bo1[64 + lane];
#pragma unroll 8
    for (int k = 0; k < ND; ++k) {
        float pk = pbuf[wid][k];
        h0 += pk * Wo1[k * HD + lane];
        h1 += pk * Wo1[k * HD + 64 + lane];
    }
    float s = sp(h0) * Wo2[lane] + sp(h1) * Wo2[64 + lane];
#pragma unroll
    for (int off = 32; off; off >>= 1) s += __shfl_down(s, off);
    if (valid && lane == 0) out[g] = s + bo2[0];
}

extern "C" void kernel_launch(void* const* d_in, const int* in_sizes, int n_in,
                              void* d_out, int out_size, void* d_ws, size_t ws_size,
                              hipStream_t stream) {
    const float* x       = (const float*)d_in[0];
    const float* ea      = (const float*)d_in[1];
    const int*   ei      = (const int*)d_in[2];
    const int*   batch   = (const int*)d_in[3];
    const float* Wnp     = (const float*)d_in[4];
    const float* bnp     = (const float*)d_in[5];
    const float* g_np    = (const float*)d_in[6];
    const float* be_np   = (const float*)d_in[7];
    const float* Wep     = (const float*)d_in[8];
    const float* bep     = (const float*)d_in[9];
    const float* We1     = (const float*)d_in[10];
    const float* be1     = (const float*)d_in[11];
    const float* We2     = (const float*)d_in[12];
    const float* be2     = (const float*)d_in[13];
    const float* Wn1     = (const float*)d_in[14];
    const float* bn1     = (const float*)d_in[15];
    const float* Wn2     = (const float*)d_in[16];
    const float* bn2     = (const float*)d_in[17];
    const float* g_bn    = (const float*)d_in[18];
    const float* b_bn    = (const float*)d_in[19];
    const float* Wo1     = (const float*)d_in[20];
    const float* bo1     = (const float*)d_in[21];
    const float* Wo2     = (const float*)d_in[22];
    const float* bo2     = (const float*)d_in[23];

    float* ws = (float*)d_ws;
    size_t off = 0;
    float* h      = ws + off; off += (size_t)N_NODES * ND;
    float* t      = ws + off; off += (size_t)N_NODES * ND;
    float* aggr   = ws + off; off += (size_t)N_NODES * HD;
    float* ss     = ws + off; off += 2 * ND;
    float* pooled = ws + off; off += N_GRAPH * ND;
    float* cnt    = ws + off; off += 512;
    unsigned short* h_bf = (unsigned short*)(ws + off); off += (size_t)N_NODES * ND / 2;
    unsigned short* pA1  = (unsigned short*)(ws + off); off += 3 * 5 * 8 * 64 * 8 / 2;
    unsigned short* pA2  = (unsigned short*)(ws + off); off += 3 * 4 * 8 * 64 * 8 / 2;
    unsigned short* pWn1 = (unsigned short*)(ws + off); off += 3 * 6 * 8 * 64 * 8 / 2;
    unsigned short* pWn2 = (unsigned short*)(ws + off); off += 3 * 4 * 4 * 64 * 8 / 2;
    int* sD       = (int*)(ws + off); off += N_EDGES;
    int* sS       = (int*)(ws + off); off += N_EDGES;
    int* sE       = (int*)(ws + off); off += N_EDGES;
    int* hist     = (int*)(ws + off); off += N_NODES;
    int* cursor   = (int*)(ws + off); off += N_NODES;
    int* rowptr   = (int*)(ws + off); off += N_NODES;
    int* chunksum = (int*)(ws + off); off += 64;
    float* partN  = ws + off; off += 512 * 128;
    float* partU  = ws + off; off += (size_t)NBU * 128;
    size_t base_bytes = off * sizeof(float);
    unsigned short* e_bf = (unsigned short*)(ws + off);
    bool epre = (ws_size >= base_bytes + (size_t)N_EDGES * 32 * 2);

    float* outp = (float*)d_out;

    const int NCH = (N_NODES + 1023) / 1024;  // 49

    // ---- counting sort of edges by dst -> CSR (once per call) ----
    hipMemsetAsync(hist, 0, N_NODES * sizeof(int), stream);
    k_hist<<<(N_EDGES + 255) / 256, 256, 0, stream>>>(ei, hist);
    k_scan1<<<NCH, 1024, 0, stream>>>(hist, chunksum);
    k_scan2<<<1, 64, 0, stream>>>(chunksum, NCH);
    k_scan3<<<NCH, 1024, 0, stream>>>(hist, chunksum, cursor, rowptr);
    k_scatter<<<(N_EDGES + 255) / 256, 256, 0, stream>>>(ei, cursor, sD, sS, sE);
    if (epre)
        k_eproj_sorted<<<(int)(((long)N_EDGES * 32 + 255) / 256), 256, 0, stream>>>(
            ea, sE, Wep, bep, e_bf);

    // ---- pack all weights (3 layers x 4 matrices) in one launch ----
    k_pack_all<<<(3 * 8704 + 255) / 256, 256, 0, stream>>>(
        We1, We2, Wn1, Wn2, pA1, pA2, pWn1, pWn2);

    // ---- node projection + BN (two-stage stats, no contended atomics) ----
    k_node_proj<<<512, 256, 0, stream>>>(x, Wnp, bnp, t, partN);
    k_stats_reduce<<<1, 256, 0, stream>>>(partN, 512, g_np, be_np, ss);
    k_bn_apply<<<(N_NODES * ND / 8 + 255) / 256, 256, 0, stream>>>(t, ss, h, h_bf);

    for (int l = 0; l < 3; ++l) {
        hipMemsetAsync(aggr, 0, (size_t)N_NODES * HD * sizeof(float), stream);
        if (epre)
            k_edge_mfma_s<true><<<N_EDGES / 128, 256, 0, stream>>>(
                h_bf, e_bf, ea, sE, Wep, bep, sD, sS, rowptr, hist,
                pA1 + (size_t)l * 40 * 64 * 8, be1 + l * HD,
                pA2 + (size_t)l * 32 * 64 * 8, be2 + l * HD, aggr);
        else
            k_edge_mfma_s<false><<<N_EDGES / 128, 256, 0, stream>>>(
                h_bf, e_bf, ea, sE, Wep, bep, sD, sS, rowptr, hist,
                pA1 + (size_t)l * 40 * 64 * 8, be1 + l * HD,
                pA2 + (size_t)l * 32 * 64 * 8, be2 + l * HD, aggr);

        k_node_mfma<<<NBU, 64, 0, stream>>>(
            h_bf, aggr, h,
            pWn1 + (size_t)l * 48 * 64 * 8, bn1 + l * HD,
            pWn2 + (size_t)l * 16 * 64 * 8, bn2 + l * ND, t, partU);
        k_stats_reduce<<<1, 256, 0, stream>>>(partU, NBU, g_bn + l * ND, b_bn + l * ND, ss);
        k_bn_apply<<<(N_NODES * ND / 8 + 255) / 256, 256, 0, stream>>>(t, ss, h, h_bf);
    }

    hipMemsetAsync(pooled, 0, (size_t)(N_GRAPH * ND + 512) * sizeof(float), stream);
    k_pool<<<512, 256, 0, stream>>>(h, batch, pooled, cnt);
    k_readout<<<(N_GRAPH + WPB - 1) / WPB, 256, 0, stream>>>(
        pooled, cnt, Wo1, bo1, Wo2, bo2, outp);
}

// Round 25
// 885.224 us; speedup vs baseline: 1.3352x; 1.3312x over previous
//
#include <hip/hip_runtime.h>
#include <hip/hip_bf16.h>

#define N_NODES 50000
#define N_EDGES 800000
#define N_GRAPH 500
#define ND 64
#define ED 32
#define HD 128
#define WPB 4   // waves per block (256 threads)
#define NBU ((N_NODES + 31) / 32)   // 1563 node blocks (32 nodes each)

typedef __attribute__((ext_vector_type(8))) short bf16x8;
typedef __attribute__((ext_vector_type(4))) float f32x4;

__device__ __forceinline__ float sp(float x) {
    return fmaxf(x, 0.f) + log1pf(expf(-fabsf(x)));
}

// fast softplus for the bf16 path (v_exp_f32/v_log_f32 based)
__device__ __forceinline__ float spf(float x) {
    return fmaxf(x, 0.f) + __logf(1.f + __expf(-fabsf(x)));
}

__device__ __forceinline__ unsigned short f2bf(float v) {
    __hip_bfloat16 b = __float2bfloat16(v);
    return *(unsigned short*)&b;
}

__device__ __forceinline__ unsigned int pkbf(float a, float b) {
    return (unsigned int)f2bf(a) | ((unsigned int)f2bf(b) << 16);
}

__device__ __forceinline__ float lo_bf(unsigned int u) { return __uint_as_float(u << 16); }
__device__ __forceinline__ float hi_bf(unsigned int u) { return __uint_as_float(u & 0xffff0000u); }

// load 8 fp32 and round to bf16x8 (same RNE as k_bn_apply/f2bf)
__device__ __forceinline__ bf16x8 ld8_f32_bf(const float* p) {
    f32x4 v0 = *(const f32x4*)p;
    f32x4 v1 = *(const f32x4*)(p + 4);
    bf16x8 r;
    r[0] = (short)f2bf(v0[0]); r[1] = (short)f2bf(v0[1]);
    r[2] = (short)f2bf(v0[2]); r[3] = (short)f2bf(v0[3]);
    r[4] = (short)f2bf(v1[0]); r[5] = (short)f2bf(v1[1]);
    r[6] = (short)f2bf(v1[2]); r[7] = (short)f2bf(v1[3]);
    return r;
}

// ---------------- node projection: partial BN stats per block -----------
__global__ __launch_bounds__(256) void k_node_proj(
    const float* __restrict__ x, const float* __restrict__ Wnp,
    const float* __restrict__ bnp, float* __restrict__ t,
    float* __restrict__ partN) {
    __shared__ float red0[4][64], red1[4][64];
    int lane = threadIdx.x & 63;
    int wid = threadIdx.x >> 6;
    int wave = (blockIdx.x * blockDim.x + threadIdx.x) >> 6;
    int nw = (gridDim.x * blockDim.x) >> 6;
    float w[13];
#pragma unroll
    for (int k = 0; k < 13; ++k) w[k] = Wnp[k * ND + lane];
    float bb = bnp[lane];
    float s0 = 0.f, s1 = 0.f;
    for (int i = wave; i < N_NODES; i += nw) {
        float acc = bb;
#pragma unroll
        for (int k = 0; k < 13; ++k) acc += x[i * 13 + k] * w[k];
        float v = sp(acc);
        t[i * ND + lane] = v;
        s0 += v; s1 += v * v;
    }
    red0[wid][lane] = s0;
    red1[wid][lane] = s1;
    __syncthreads();
    int tid = threadIdx.x;
    if (tid < 64)
        partN[blockIdx.x * 128 + tid] =
            red0[0][tid] + red0[1][tid] + red0[2][tid] + red0[3][tid];
    else if (tid < 128) {
        int c = tid - 64;
        partN[blockIdx.x * 128 + tid] =
            red1[0][c] + red1[1][c] + red1[2][c] + red1[3][c];
    }
}

// ---- stage A: 16 blocks reduce R partial rows -> part2[16][128] --------
__global__ __launch_bounds__(256) void k_stats_part(
    const float* __restrict__ part, int R, float* __restrict__ part2) {
    __shared__ float r0[4][64], r1[4][64];
    int q = threadIdx.x >> 6, c = threadIdx.x & 63;
    float S0 = 0.f, S1 = 0.f;
    for (int r = blockIdx.x * 4 + q; r < R; r += 64) {
        S0 += part[(size_t)r * 128 + c];
        S1 += part[(size_t)r * 128 + 64 + c];
    }
    r0[q][c] = S0; r1[q][c] = S1;
    __syncthreads();
    if (threadIdx.x < 64)
        part2[blockIdx.x * 128 + c] = r0[0][c] + r0[1][c] + r0[2][c] + r0[3][c];
    else if (threadIdx.x < 128) {
        int cc = threadIdx.x - 64;
        part2[blockIdx.x * 128 + 64 + cc] =
            r1[0][cc] + r1[1][cc] + r1[2][cc] + r1[3][cc];
    }
}

// ---- stage B: sum R partial rows (small R), emit scale/shift -----------
__global__ void k_stats_reduce(const float* __restrict__ part, int R,
                               const float* __restrict__ g,
                               const float* __restrict__ b,
                               float* __restrict__ ss) {
    __shared__ float r0[4][64], r1[4][64];
    int q = threadIdx.x >> 6, c = threadIdx.x & 63;
    float S0 = 0.f, S1 = 0.f;
    for (int r = q; r < R; r += 4) {
        S0 += part[(size_t)r * 128 + c];
        S1 += part[(size_t)r * 128 + 64 + c];
    }
    r0[q][c] = S0; r1[q][c] = S1;
    __syncthreads();
    if (threadIdx.x < 64) {
        float s0 = r0[0][c] + r0[1][c] + r0[2][c] + r0[3][c];
        float s1 = r1[0][c] + r1[1][c] + r1[2][c] + r1[3][c];
        float inv_n = 1.f / (float)N_NODES;
        float mu = s0 * inv_n;
        float var = s1 * inv_n - mu * mu;
        float rs = rsqrtf(var + 1e-5f);
        float sc = rs * g[c];
        ss[c] = sc;
        ss[64 + c] = b[c] - mu * sc;
    }
}

// vectorized BN apply: 8 elements/thread (channels contiguous, 8 | 64)
__global__ __launch_bounds__(256) void k_bn_apply(
    const float* __restrict__ t, const float* __restrict__ ss,
    float* __restrict__ h, unsigned short* __restrict__ hb) {
    int idx = (blockIdx.x * 256 + threadIdx.x) * 8;
    if (idx >= N_NODES * ND) return;
    int c = idx & (ND - 1);
    f32x4 sc0 = *(const f32x4*)(ss + c);
    f32x4 sc1 = *(const f32x4*)(ss + c + 4);
    f32x4 sh0 = *(const f32x4*)(ss + ND + c);
    f32x4 sh1 = *(const f32x4*)(ss + ND + c + 4);
    f32x4 v0 = *(const f32x4*)(t + idx);
    f32x4 v1 = *(const f32x4*)(t + idx + 4);
    f32x4 r0, r1;
#pragma unroll
    for (int j = 0; j < 4; ++j) { r0[j] = v0[j] * sc0[j] + sh0[j]; r1[j] = v1[j] * sc1[j] + sh1[j]; }
    *(f32x4*)(h + idx) = r0;
    *(f32x4*)(h + idx + 4) = r1;
    bf16x8 rb;
    rb[0] = (short)f2bf(r0[0]); rb[1] = (short)f2bf(r0[1]);
    rb[2] = (short)f2bf(r0[2]); rb[3] = (short)f2bf(r0[3]);
    rb[4] = (short)f2bf(r1[0]); rb[5] = (short)f2bf(r1[1]);
    rb[6] = (short)f2bf(r1[2]); rb[7] = (short)f2bf(r1[3]);
    *(bf16x8*)(hb + idx) = rb;
}

// ---------------- counting sort of edges by dst -------------------------
__global__ __launch_bounds__(256) void k_hist(const int* __restrict__ ei,
                                              int* __restrict__ hist) {
    int e = blockIdx.x * 256 + threadIdx.x;
    if (e < N_EDGES) atomicAdd(&hist[ei[N_EDGES + e]], 1);
}

__global__ __launch_bounds__(1024) void k_scan1(const int* __restrict__ hist,
                                                int* __restrict__ chunksum) {
    __shared__ int s[1024];
    int t = threadIdx.x;
    int i = blockIdx.x * 1024 + t;
    s[t] = (i < N_NODES) ? hist[i] : 0;
    __syncthreads();
    for (int off = 512; off; off >>= 1) {
        if (t < off) s[t] += s[t + off];
        __syncthreads();
    }
    if (t == 0) chunksum[blockIdx.x] = s[0];
}

__global__ void k_scan2(int* __restrict__ chunksum, int n) {
    if (threadIdx.x == 0) {
        int acc = 0;
        for (int i = 0; i < n; ++i) { int v = chunksum[i]; chunksum[i] = acc; acc += v; }
    }
}

__global__ __launch_bounds__(1024) void k_scan3(const int* __restrict__ hist,
                                                const int* __restrict__ chunksum,
                                                int* __restrict__ cursor,
                                                int* __restrict__ rowptr) {
    __shared__ int s[1024];
    int t = threadIdx.x;
    int i = blockIdx.x * 1024 + t;
    int v = (i < N_NODES) ? hist[i] : 0;
    s[t] = v;
    __syncthreads();
    for (int off = 1; off < 1024; off <<= 1) {
        int u = (t >= off) ? s[t - off] : 0;
        __syncthreads();
        s[t] += u;
        __syncthreads();
    }
    if (i < N_NODES) {
        int ex = chunksum[blockIdx.x] + s[t] - v;  // exclusive
        cursor[i] = ex;
        rowptr[i] = ex;
    }
}

__global__ __launch_bounds__(256) void k_scatter(const int* __restrict__ ei,
                                                 int* __restrict__ cursor,
                                                 int* __restrict__ sD,
                                                 int* __restrict__ sS,
                                                 int* __restrict__ sE) {
    int e = blockIdx.x * 256 + threadIdx.x;
    if (e >= N_EDGES) return;
    int d = ei[N_EDGES + e];
    int pos = atomicAdd(&cursor[d], 1);
    sD[pos] = d;
    sS[pos] = ei[e];
    sE[pos] = e;
}

// edge projection into sorted order (layer-invariant, once per call)
__global__ __launch_bounds__(256) void k_eproj_sorted(
    const float* __restrict__ ea, const int* __restrict__ sE,
    const float* __restrict__ Wep, const float* __restrict__ bep,
    unsigned short* __restrict__ e_bf) {
    long idx = (long)blockIdx.x * blockDim.x + threadIdx.x;
    long tot = (long)N_EDGES * 32;
    if (idx >= tot) return;
    int p = (int)(idx >> 5), col = (int)(idx & 31);
    int e = sE[p];
    float v = spf(ea[2 * e] * Wep[col] + ea[2 * e + 1] * Wep[32 + col] + bep[col]);
    e_bf[idx] = f2bf(v);
}

// ---- fused weight pack: all 3 layers x {We1,We2,Wn1,Wn2} in ONE launch --
__global__ __launch_bounds__(256) void k_pack_all(
    const float* __restrict__ We1, const float* __restrict__ We2,
    const float* __restrict__ Wn1, const float* __restrict__ Wn2,
    unsigned short* __restrict__ pA1, unsigned short* __restrict__ pA2,
    unsigned short* __restrict__ pWn1, unsigned short* __restrict__ pWn2) {
    int tid = blockIdx.x * 256 + threadIdx.x;
    const int PER_L = (40 + 32 + 48 + 16) * 64;  // 8704
    if (tid >= 3 * PER_L) return;
    int layer = tid / PER_L;
    int r = tid % PER_L;
    const float* W;
    unsigned short* out;
    int ncols, lt;
    if (r < 40 * 64) {
        lt = r; W = We1 + (size_t)layer * 160 * 128; out = pA1 + (size_t)layer * 40 * 64 * 8;
        ncols = 128;
    } else if (r < 72 * 64) {
        lt = r - 40 * 64; W = We2 + (size_t)layer * 128 * 128; out = pA2 + (size_t)layer * 32 * 64 * 8;
        ncols = 128;
    } else if (r < 120 * 64) {
        lt = r - 72 * 64; W = Wn1 + (size_t)layer * 192 * 128; out = pWn1 + (size_t)layer * 48 * 64 * 8;
        ncols = 128;
    } else {
        lt = r - 120 * 64; W = Wn2 + (size_t)layer * 128 * 64; out = pWn2 + (size_t)layer * 16 * 64 * 8;
        ncols = 64;
    }
    int nfrag = ncols >> 4;
    int l = lt & 63; int fr = lt >> 6; int nf = fr % nfrag; int ks = fr / nfrag;
    int n = 16 * nf + (l & 15);
    int k0 = 32 * ks + 8 * (l >> 4);
#pragma unroll
    for (int rr = 0; rr < 8; ++rr)
        out[lt * 8 + rr] = f2bf(W[(k0 + rr) * ncols + n]);
}

// ---------------- MFMA edge conv on dst-sorted edges (round-23 form) ----
template <bool EPRE>
__global__ __launch_bounds__(256, 4) void k_edge_mfma_s(
    const unsigned short* __restrict__ h_bf, const unsigned short* __restrict__ e_bf,
    const float* __restrict__ ea, const int* __restrict__ sE,
    const float* __restrict__ Wep, const float* __restrict__ bep,
    const int* __restrict__ sD, const int* __restrict__ sS,
    const int* __restrict__ rowptr, const int* __restrict__ hist,
    const unsigned short* __restrict__ pA1, const float* __restrict__ be1,
    const unsigned short* __restrict__ pA2, const float* __restrict__ be2,
    float* __restrict__ aggr) {
    __shared__ unsigned short P[WPB][32][136];   // per-wave P; reused as 128-row stage
    __shared__ int dstB[128];
    __shared__ unsigned short eL[EPRE ? 64 : 128 * 32];

    int lane = threadIdx.x & 63;
    int w = threadIdx.x >> 6;
    int m = lane & 15, g = lane >> 4;
    int tile0 = blockIdx.x * 128;
    int wbase = tile0 + 32 * w;

    int eD0 = sD[wbase + m];
    int eD1 = sD[wbase + 16 + m];
    int eS0 = sS[wbase + m];
    int eS1 = sS[wbase + 16 + m];

    if constexpr (!EPRE) {
        int col = threadIdx.x & 31;
        int r0 = threadIdx.x >> 5;
        float w0 = Wep[col], w1 = Wep[32 + col], bb = bep[col];
#pragma unroll
        for (int i = 0; i < 16; ++i) {
            int em = r0 + 8 * i;
            int e = sE[tile0 + em];
            eL[em * 32 + col] = f2bf(spf(ea[2 * e] * w0 + ea[2 * e + 1] * w1 + bb));
        }
        __syncthreads();
    }

    // ---- GEMM1 (K=160) in four nf-quarters: acc = 16 AGPR per region ----
#pragma unroll
    for (int qt = 0; qt < 4; ++qt) {
        f32x4 acc[2][2];
#pragma unroll
        for (int mf = 0; mf < 2; ++mf)
#pragma unroll
            for (int n2 = 0; n2 < 2; ++n2) acc[mf][n2] = (f32x4){0.f, 0.f, 0.f, 0.f};
#pragma unroll
        for (int ks = 0; ks < 5; ++ks) {
            bf16x8 b0, b1;
            if (ks < 2) {
                b0 = *(const bf16x8*)(h_bf + (size_t)eD0 * 64 + ks * 32 + 8 * g);
                b1 = *(const bf16x8*)(h_bf + (size_t)eD1 * 64 + ks * 32 + 8 * g);
            } else if (ks < 4) {
                b0 = *(const bf16x8*)(h_bf + (size_t)eS0 * 64 + (ks - 2) * 32 + 8 * g);
                b1 = *(const bf16x8*)(h_bf + (size_t)eS1 * 64 + (ks - 2) * 32 + 8 * g);
            } else {
                if constexpr (EPRE) {
                    b0 = *(const bf16x8*)(e_bf + (size_t)(wbase + m) * 32 + 8 * g);
                    b1 = *(const bf16x8*)(e_bf + (size_t)(wbase + 16 + m) * 32 + 8 * g);
                } else {
                    b0 = *(const bf16x8*)&eL[(32 * w + m) * 32 + 8 * g];
                    b1 = *(const bf16x8*)&eL[(32 * w + 16 + m) * 32 + 8 * g];
                }
            }
#pragma unroll
            for (int n2 = 0; n2 < 2; ++n2) {
                int nf = qt * 2 + n2;
                bf16x8 a = *(const bf16x8*)(pA1 + ((ks * 8 + nf) * 64 + lane) * 8);
                acc[0][n2] = __builtin_amdgcn_mfma_f32_16x16x32_bf16(a, b0, acc[0][n2], 0, 0, 0);
                acc[1][n2] = __builtin_amdgcn_mfma_f32_16x16x32_bf16(a, b1, acc[1][n2], 0, 0, 0);
            }
        }
        // epilogue 1 (this quarter): bias + fast softplus -> P (bf16) in LDS
#pragma unroll
        for (int n2 = 0; n2 < 2; ++n2) {
            int nf = qt * 2 + n2;
            f32x4 bb = *(const f32x4*)(be1 + 16 * nf + 4 * g);
#pragma unroll
            for (int mf = 0; mf < 2; ++mf) {
                f32x4 c = acc[mf][n2];
                unsigned int u01 = pkbf(spf(c[0] + bb[0]), spf(c[1] + bb[1]));
                unsigned int u23 = pkbf(spf(c[2] + bb[2]), spf(c[3] + bb[3]));
                unsigned int* dst = (unsigned int*)&P[w][m + 16 * mf][16 * nf + 4 * g];
                dst[0] = u01; dst[1] = u23;
            }
        }
    }

    // ---- GEMM2 (K=128) per m-fragment, two nf-halves; 8-reg deferral ----
    unsigned short (*Pf)[136] = (unsigned short(*)[136]) & P[0][0][0];
#pragma unroll
    for (int mf = 0; mf < 2; ++mf) {
        unsigned int defer[8];
#pragma unroll
        for (int half = 0; half < 2; ++half) {
            f32x4 acc2[4];
#pragma unroll
            for (int n2 = 0; n2 < 4; ++n2) acc2[n2] = (f32x4){0.f, 0.f, 0.f, 0.f};
#pragma unroll
            for (int ks = 0; ks < 4; ++ks) {
                bf16x8 b = *(const bf16x8*)&P[w][m + 16 * mf][32 * ks + 8 * g];
#pragma unroll
                for (int n2 = 0; n2 < 4; ++n2) {
                    int nf = half * 4 + n2;
                    bf16x8 a = *(const bf16x8*)(pA2 + ((ks * 8 + nf) * 64 + lane) * 8);
                    acc2[n2] = __builtin_amdgcn_mfma_f32_16x16x32_bf16(a, b, acc2[n2], 0, 0, 0);
                }
            }
            if (half == 0) {
#pragma unroll
                for (int n2 = 0; n2 < 4; ++n2) {
                    int nf = n2;
                    f32x4 bb = *(const f32x4*)(be2 + 16 * nf + 4 * g);
                    f32x4 c = acc2[n2];
                    defer[2 * n2] = pkbf(spf(c[0] + bb[0]), spf(c[1] + bb[1]));
                    defer[2 * n2 + 1] = pkbf(spf(c[2] + bb[2]), spf(c[3] + bb[3]));
                }
            } else {
#pragma unroll
                for (int n2 = 0; n2 < 4; ++n2) {
                    int nf = 4 + n2;
                    f32x4 bb = *(const f32x4*)(be2 + 16 * nf + 4 * g);
                    f32x4 c = acc2[n2];
                    unsigned int* dst =
                        (unsigned int*)&Pf[32 * w + 16 * mf + m][16 * nf + 4 * g];
                    dst[0] = pkbf(spf(c[0] + bb[0]), spf(c[1] + bb[1]));
                    dst[1] = pkbf(spf(c[2] + bb[2]), spf(c[3] + bb[3]));
                }
#pragma unroll
                for (int n2 = 0; n2 < 4; ++n2) {
                    unsigned int* dst =
                        (unsigned int*)&Pf[32 * w + 16 * mf + m][16 * n2 + 4 * g];
                    dst[0] = defer[2 * n2];
                    dst[1] = defer[2 * n2 + 1];
                }
            }
        }
    }
    if (g == 0) {
        dstB[32 * w + m] = eD0;
        dstB[32 * w + 16 + m] = eD1;
    }
    __syncthreads();

    // ---- block-wide run-length segmented reduction ----
    int rbeg = 32 * w, rend = rbeg + 32;
    int r = rbeg;
    if (w) {  // skip rows continuing a run that started in a lower wave
        while (r < rend && dstB[r] == dstB[r - 1]) ++r;
    }
    while (r < rend) {
        int d = dstB[r];
        float a0 = 0.f, a1 = 0.f;
        int rr = r;
        do {
            unsigned int u = *(const unsigned int*)&Pf[rr][2 * lane];
            a0 += lo_bf(u);
            a1 += hi_bf(u);
            ++rr;
        } while (rr < 128 && dstB[rr] == d);
        int s0 = rowptr[d];
        bool interior = (s0 >= tile0) && (s0 + hist[d] <= tile0 + 128);
        float* base = aggr + (size_t)d * HD + 2 * lane;
        if (interior) {
            base[0] = a0;
            base[1] = a1;
        } else {
            atomicAdd(base, a0);
            atomicAdd(base + 1, a1);
        }
        r = rr;
    }
}

// ---------------- MFMA node update: 2 waves / 32 nodes ------------------
// Wave w computes GEMM1 nf in [4w,4w+4) into shared P; sync; GEMM2
// nf in [2w,2w+2) + residual/stats for its 32 channels. 3126 waves
// (~12/CU) vs 1563 before: halves the latency-bound critical path.
__global__ __launch_bounds__(128, 2) void k_node_mfma(
    const unsigned short* __restrict__ h_bf, const float* __restrict__ aggr,
    const float* __restrict__ h,
    const unsigned short* __restrict__ pWn1, const float* __restrict__ bn1,
    const unsigned short* __restrict__ pWn2, const float* __restrict__ bn2,
    float* __restrict__ t, float* __restrict__ partU) {
    __shared__ unsigned short P[32][136];

    int lane = threadIdx.x & 63;
    int wv = threadIdx.x >> 6;   // 0 or 1
    int m = lane & 15, g = lane >> 4;
    int wbase = blockIdx.x * 32;
    int n0 = wbase + m, n1 = wbase + 16 + m;
    bool v0 = n0 < N_NODES, v1 = n1 < N_NODES;
    int c0 = v0 ? n0 : N_NODES - 1;
    int c1 = v1 ? n1 : N_NODES - 1;

    f32x4 acc[2][4];
#pragma unroll
    for (int mf = 0; mf < 2; ++mf)
#pragma unroll
        for (int n2 = 0; n2 < 4; ++n2) acc[mf][n2] = (f32x4){0.f, 0.f, 0.f, 0.f};

    // ---- GEMM1: K = 192 (h 64 | aggr 128); this wave: nf = 4*wv..4*wv+3
#pragma unroll
    for (int ks = 0; ks < 6; ++ks) {
        bf16x8 b0, b1;
        if (ks < 2) {
            b0 = *(const bf16x8*)(h_bf + (size_t)c0 * 64 + ks * 32 + 8 * g);
            b1 = *(const bf16x8*)(h_bf + (size_t)c1 * 64 + ks * 32 + 8 * g);
        } else {
            b0 = ld8_f32_bf(aggr + (size_t)c0 * 128 + (ks - 2) * 32 + 8 * g);
            b1 = ld8_f32_bf(aggr + (size_t)c1 * 128 + (ks - 2) * 32 + 8 * g);
        }
#pragma unroll
        for (int n2 = 0; n2 < 4; ++n2) {
            int nf = 4 * wv + n2;
            bf16x8 a = *(const bf16x8*)(pWn1 + ((ks * 8 + nf) * 64 + lane) * 8);
            acc[0][n2] = __builtin_amdgcn_mfma_f32_16x16x32_bf16(a, b0, acc[0][n2], 0, 0, 0);
            acc[1][n2] = __builtin_amdgcn_mfma_f32_16x16x32_bf16(a, b1, acc[1][n2], 0, 0, 0);
        }
    }

    // ---- epilogue 1: bias + fast softplus -> P columns of this wave ----
#pragma unroll
    for (int n2 = 0; n2 < 4; ++n2) {
        int nf = 4 * wv + n2;
        f32x4 bb = *(const f32x4*)(bn1 + 16 * nf + 4 * g);
#pragma unroll
        for (int mf = 0; mf < 2; ++mf) {
            f32x4 c = acc[mf][n2];
            unsigned int u01 = pkbf(spf(c[0] + bb[0]), spf(c[1] + bb[1]));
            unsigned int u23 = pkbf(spf(c[2] + bb[2]), spf(c[3] + bb[3]));
            unsigned int* dst = (unsigned int*)&P[m + 16 * mf][16 * nf + 4 * g];
            dst[0] = u01; dst[1] = u23;
        }
    }
    __syncthreads();

    f32x4 acc2[2][2];
#pragma unroll
    for (int mf = 0; mf < 2; ++mf)
#pragma unroll
        for (int n2 = 0; n2 < 2; ++n2) acc2[mf][n2] = (f32x4){0.f, 0.f, 0.f, 0.f};

    // ---- GEMM2: K = 128, N = 64; this wave: nf = 2*wv..2*wv+1 ----
#pragma unroll
    for (int ks = 0; ks < 4; ++ks) {
        bf16x8 b0 = *(const bf16x8*)&P[m][32 * ks + 8 * g];
        bf16x8 b1 = *(const bf16x8*)&P[m + 16][32 * ks + 8 * g];
#pragma unroll
        for (int n2 = 0; n2 < 2; ++n2) {
            int nf = 2 * wv + n2;
            bf16x8 a = *(const bf16x8*)(pWn2 + ((ks * 4 + nf) * 64 + lane) * 8);
            acc2[0][n2] = __builtin_amdgcn_mfma_f32_16x16x32_bf16(a, b0, acc2[0][n2], 0, 0, 0);
            acc2[1][n2] = __builtin_amdgcn_mfma_f32_16x16x32_bf16(a, b1, acc2[1][n2], 0, 0, 0);
        }
    }

    // ---- epilogue 2: +bn2 +h residual -> t; partial BN stats -----------
#pragma unroll
    for (int n2 = 0; n2 < 2; ++n2) {
        int nf = 2 * wv + n2;
        f32x4 bb = *(const f32x4*)(bn2 + 16 * nf + 4 * g);
        f32x4 s0v = (f32x4){0.f, 0.f, 0.f, 0.f};
        f32x4 s1v = (f32x4){0.f, 0.f, 0.f, 0.f};
#pragma unroll
        for (int mf = 0; mf < 2; ++mf) {
            int cn = mf ? c1 : c0;
            bool vn = mf ? v1 : v0;
            f32x4 hv = *(const f32x4*)(h + (size_t)cn * 64 + 16 * nf + 4 * g);
            f32x4 c = acc2[mf][n2];
            f32x4 tn;
#pragma unroll
            for (int j = 0; j < 4; ++j) tn[j] = c[j] + bb[j] + hv[j];
            if (vn) *(f32x4*)(t + (size_t)cn * 64 + 16 * nf + 4 * g) = tn;
#pragma unroll
            for (int j = 0; j < 4; ++j) {
                float tv = vn ? tn[j] : 0.f;
                s0v[j] += tv;
                s1v[j] += tv * tv;
            }
        }
#pragma unroll
        for (int j = 0; j < 4; ++j) {
#pragma unroll
            for (int k = 1; k <= 8; k <<= 1) {
                s0v[j] += __shfl_xor(s0v[j], k);
                s1v[j] += __shfl_xor(s1v[j], k);
            }
        }
        if (m == 0) {
#pragma unroll
            for (int j = 0; j < 4; ++j) {
                int ch = 16 * nf + 4 * g + j;
                partU[(size_t)blockIdx.x * 128 + ch] = s0v[j];
                partU[(size_t)blockIdx.x * 128 + 64 + ch] = s1v[j];
            }
        }
    }
}

// ---------------- pooling + readout (unchanged) -------------------------
__global__ __launch_bounds__(256) void k_pool(
    const float* __restrict__ h, const int* __restrict__ batch,
    float* __restrict__ pooled, float* __restrict__ cnt) {
    int lane = threadIdx.x & 63;
    int wave = (blockIdx.x * blockDim.x + threadIdx.x) >> 6;
    int nw = (gridDim.x * blockDim.x) >> 6;
    int chunk = (N_NODES + nw - 1) / nw;
    int s = wave * chunk;
    int epos = min(N_NODES, s + chunk);
    if (s >= N_NODES) return;
    int curg = batch[s];
    float acc = 0.f, c = 0.f;
    for (int i = s; i < epos; ++i) {
        int g = batch[i];
        if (g != curg) {
            atomicAdd(&pooled[curg * ND + lane], acc);
            if (lane == 0) atomicAdd(&cnt[curg], c);
            acc = 0.f; c = 0.f; curg = g;
        }
        acc += h[i * ND + lane];
        c += 1.f;
    }
    atomicAdd(&pooled[curg * ND + lane], acc);
    if (lane == 0) atomicAdd(&cnt[curg], c);
}

__global__ __launch_bounds__(256) void k_readout(
    const float* __restrict__ pooled, const float* __restrict__ cnt,
    const float* __restrict__ Wo1, const float* __restrict__ bo1,
    const float* __restrict__ Wo2, const float* __restrict__ bo2,
    float* __restrict__ out) {
    __shared__ float pbuf[WPB][ND];
    int lane = threadIdx.x & 63;
    int wid = threadIdx.x >> 6;
    int g = blockIdx.x * WPB + wid;
    bool valid = g < N_GRAPH;
    int gc = valid ? g : N_GRAPH - 1;
    float c = fmaxf(cnt[gc], 1.f);
    pbuf[wid][lane] = pooled[gc * ND + lane] / c;
    __syncthreads();
    float h0 = bo1[lane], h1 = bo1[64 + lane];
#pragma unroll 8
    for (int k = 0; k < ND; ++k) {
        float pk = pbuf[wid][k];
        h0 += pk * Wo1[k * HD + lane];
        h1 += pk * Wo1[k * HD + 64 + lane];
    }
    float s = sp(h0) * Wo2[lane] + sp(h1) * Wo2[64 + lane];
#pragma unroll
    for (int off = 32; off; off >>= 1) s += __shfl_down(s, off);
    if (valid && lane == 0) out[g] = s + bo2[0];
}

extern "C" void kernel_launch(void* const* d_in, const int* in_sizes, int n_in,
                              void* d_out, int out_size, void* d_ws, size_t ws_size,
                              hipStream_t stream) {
    const float* x       = (const float*)d_in[0];
    const float* ea      = (const float*)d_in[1];
    const int*   ei      = (const int*)d_in[2];
    const int*   batch   = (const int*)d_in[3];
    const float* Wnp     = (const float*)d_in[4];
    const float* bnp     = (const float*)d_in[5];
    const float* g_np    = (const float*)d_in[6];
    const float* be_np   = (const float*)d_in[7];
    const float* Wep     = (const float*)d_in[8];
    const float* bep     = (const float*)d_in[9];
    const float* We1     = (const float*)d_in[10];
    const float* be1     = (const float*)d_in[11];
    const float* We2     = (const float*)d_in[12];
    const float* be2     = (const float*)d_in[13];
    const float* Wn1     = (const float*)d_in[14];
    const float* bn1     = (const float*)d_in[15];
    const float* Wn2     = (const float*)d_in[16];
    const float* bn2     = (const float*)d_in[17];
    const float* g_bn    = (const float*)d_in[18];
    const float* b_bn    = (const float*)d_in[19];
    const float* Wo1     = (const float*)d_in[20];
    const float* bo1     = (const float*)d_in[21];
    const float* Wo2     = (const float*)d_in[22];
    const float* bo2     = (const float*)d_in[23];

    float* ws = (float*)d_ws;
    size_t off = 0;
    float* h      = ws + off; off += (size_t)N_NODES * ND;
    float* t      = ws + off; off += (size_t)N_NODES * ND;
    float* aggr   = ws + off; off += (size_t)N_NODES * HD;
    float* ss     = ws + off; off += 2 * ND;
    float* pooled = ws + off; off += N_GRAPH * ND;
    float* cnt    = ws + off; off += 512;
    unsigned short* h_bf = (unsigned short*)(ws + off); off += (size_t)N_NODES * ND / 2;
    unsigned short* pA1  = (unsigned short*)(ws + off); off += 3 * 5 * 8 * 64 * 8 / 2;
    unsigned short* pA2  = (unsigned short*)(ws + off); off += 3 * 4 * 8 * 64 * 8 / 2;
    unsigned short* pWn1 = (unsigned short*)(ws + off); off += 3 * 6 * 8 * 64 * 8 / 2;
    unsigned short* pWn2 = (unsigned short*)(ws + off); off += 3 * 4 * 4 * 64 * 8 / 2;
    int* sD       = (int*)(ws + off); off += N_EDGES;
    int* sS       = (int*)(ws + off); off += N_EDGES;
    int* sE       = (int*)(ws + off); off += N_EDGES;
    int* hist     = (int*)(ws + off); off += N_NODES;
    int* cursor   = (int*)(ws + off); off += N_NODES;
    int* rowptr   = (int*)(ws + off); off += N_NODES;
    int* chunksum = (int*)(ws + off); off += 64;
    float* partN  = ws + off; off += 512 * 128;
    float* partU  = ws + off; off += (size_t)NBU * 128;
    float* part2  = ws + off; off += 16 * 128;
    size_t base_bytes = off * sizeof(float);
    unsigned short* e_bf = (unsigned short*)(ws + off);
    bool epre = (ws_size >= base_bytes + (size_t)N_EDGES * 32 * 2);

    float* outp = (float*)d_out;

    const int NCH = (N_NODES + 1023) / 1024;  // 49

    // ---- counting sort of edges by dst -> CSR (once per call) ----
    hipMemsetAsync(hist, 0, N_NODES * sizeof(int), stream);
    k_hist<<<(N_EDGES + 255) / 256, 256, 0, stream>>>(ei, hist);
    k_scan1<<<NCH, 1024, 0, stream>>>(hist, chunksum);
    k_scan2<<<1, 64, 0, stream>>>(chunksum, NCH);
    k_scan3<<<NCH, 1024, 0, stream>>>(hist, chunksum, cursor, rowptr);
    k_scatter<<<(N_EDGES + 255) / 256, 256, 0, stream>>>(ei, cursor, sD, sS, sE);
    if (epre)
        k_eproj_sorted<<<(int)(((long)N_EDGES * 32 + 255) / 256), 256, 0, stream>>>(
            ea, sE, Wep, bep, e_bf);

    // ---- pack all weights (3 layers x 4 matrices) in one launch ----
    k_pack_all<<<(3 * 8704 + 255) / 256, 256, 0, stream>>>(
        We1, We2, Wn1, Wn2, pA1, pA2, pWn1, pWn2);

    // ---- node projection + BN (two-stage parallel stats) ----
    k_node_proj<<<512, 256, 0, stream>>>(x, Wnp, bnp, t, partN);
    k_stats_part<<<16, 256, 0, stream>>>(partN, 512, part2);
    k_stats_reduce<<<1, 256, 0, stream>>>(part2, 16, g_np, be_np, ss);
    k_bn_apply<<<(N_NODES * ND / 8 + 255) / 256, 256, 0, stream>>>(t, ss, h, h_bf);

    for (int l = 0; l < 3; ++l) {
        hipMemsetAsync(aggr, 0, (size_t)N_NODES * HD * sizeof(float), stream);
        if (epre)
            k_edge_mfma_s<true><<<N_EDGES / 128, 256, 0, stream>>>(
                h_bf, e_bf, ea, sE, Wep, bep, sD, sS, rowptr, hist,
                pA1 + (size_t)l * 40 * 64 * 8, be1 + l * HD,
                pA2 + (size_t)l * 32 * 64 * 8, be2 + l * HD, aggr);
        else
            k_edge_mfma_s<false><<<N_EDGES / 128, 256, 0, stream>>>(
                h_bf, e_bf, ea, sE, Wep, bep, sD, sS, rowptr, hist,
                pA1 + (size_t)l * 40 * 64 * 8, be1 + l * HD,
                pA2 + (size_t)l * 32 * 64 * 8, be2 + l * HD, aggr);

        k_node_mfma<<<NBU, 128, 0, stream>>>(
            h_bf, aggr, h,
            pWn1 + (size_t)l * 48 * 64 * 8, bn1 + l * HD,
            pWn2 + (size_t)l * 16 * 64 * 8, bn2 + l * ND, t, partU);
        k_stats_part<<<16, 256, 0, stream>>>(partU, NBU, part2);
        k_stats_reduce<<<1, 256, 0, stream>>>(part2, 16, g_bn + l * ND, b_bn + l * ND, ss);
        k_bn_apply<<<(N_NODES * ND / 8 + 255) / 256, 256, 0, stream>>>(t, ss, h, h_bf);
    }

    hipMemsetAsync(pooled, 0, (size_t)(N_GRAPH * ND + 512) * sizeof(float), stream);
    k_pool<<<512, 256, 0, stream>>>(h, batch, pooled, cnt);
    k_readout<<<(N_GRAPH + WPB - 1) / WPB, 256, 0, stream>>>(
        pooled, cnt, Wo1, bo1, Wo2, bo2, outp);
}

// Round 26
// 878.960 us; speedup vs baseline: 1.3448x; 1.0071x over previous
//
#include <hip/hip_runtime.h>
#include <hip/hip_bf16.h>

#define N_NODES 50000
#define N_EDGES 800000
#define N_GRAPH 500
#define ND 64
#define ED 32
#define HD 128
#define WPB 4   // waves per block (256 threads)
#define NBU ((N_NODES + 31) / 32)   // 1563 node blocks (32 nodes each)

typedef __attribute__((ext_vector_type(8))) short bf16x8;
typedef __attribute__((ext_vector_type(4))) float f32x4;
typedef __attribute__((ext_vector_type(4))) unsigned int u32x4;

__device__ __forceinline__ float sp(float x) {
    return fmaxf(x, 0.f) + log1pf(expf(-fabsf(x)));
}

// fast softplus for the bf16 path (v_exp_f32/v_log_f32 based)
__device__ __forceinline__ float spf(float x) {
    return fmaxf(x, 0.f) + __logf(1.f + __expf(-fabsf(x)));
}

__device__ __forceinline__ unsigned short f2bf(float v) {
    __hip_bfloat16 b = __float2bfloat16(v);
    return *(unsigned short*)&b;
}

// single-instruction pack: lo=bf16(a), hi=bf16(b)  (v_cvt_pk_bf16_f32, RNE)
__device__ __forceinline__ unsigned int cvtpk(float a, float b) {
    unsigned int r;
    asm("v_cvt_pk_bf16_f32 %0, %1, %2" : "=v"(r) : "v"(a), "v"(b));
    return r;
}

__device__ __forceinline__ float lo_bf(unsigned int u) { return __uint_as_float(u << 16); }
__device__ __forceinline__ float hi_bf(unsigned int u) { return __uint_as_float(u & 0xffff0000u); }

// load 8 fp32 and round to bf16x8 via 4 cvt_pk
__device__ __forceinline__ bf16x8 ld8_f32_bf(const float* p) {
    f32x4 v0 = *(const f32x4*)p;
    f32x4 v1 = *(const f32x4*)(p + 4);
    u32x4 u;
    u[0] = cvtpk(v0[0], v0[1]);
    u[1] = cvtpk(v0[2], v0[3]);
    u[2] = cvtpk(v1[0], v1[1]);
    u[3] = cvtpk(v1[2], v1[3]);
    return *(bf16x8*)&u;
}

// ---------------- node projection: partial BN stats per block -----------
__global__ __launch_bounds__(256) void k_node_proj(
    const float* __restrict__ x, const float* __restrict__ Wnp,
    const float* __restrict__ bnp, float* __restrict__ t,
    float* __restrict__ partN) {
    __shared__ float red0[4][64], red1[4][64];
    int lane = threadIdx.x & 63;
    int wid = threadIdx.x >> 6;
    int wave = (blockIdx.x * blockDim.x + threadIdx.x) >> 6;
    int nw = (gridDim.x * blockDim.x) >> 6;
    float w[13];
#pragma unroll
    for (int k = 0; k < 13; ++k) w[k] = Wnp[k * ND + lane];
    float bb = bnp[lane];
    float s0 = 0.f, s1 = 0.f;
    for (int i = wave; i < N_NODES; i += nw) {
        float acc = bb;
#pragma unroll
        for (int k = 0; k < 13; ++k) acc += x[i * 13 + k] * w[k];
        float v = sp(acc);
        t[i * ND + lane] = v;
        s0 += v; s1 += v * v;
    }
    red0[wid][lane] = s0;
    red1[wid][lane] = s1;
    __syncthreads();
    int tid = threadIdx.x;
    if (tid < 64)
        partN[blockIdx.x * 128 + tid] =
            red0[0][tid] + red0[1][tid] + red0[2][tid] + red0[3][tid];
    else if (tid < 128) {
        int c = tid - 64;
        partN[blockIdx.x * 128 + tid] =
            red1[0][c] + red1[1][c] + red1[2][c] + red1[3][c];
    }
}

// ---- stage A: 16 blocks reduce R partial rows -> part2[16][128] --------
__global__ __launch_bounds__(256) void k_stats_part(
    const float* __restrict__ part, int R, float* __restrict__ part2) {
    __shared__ float r0[4][64], r1[4][64];
    int q = threadIdx.x >> 6, c = threadIdx.x & 63;
    float S0 = 0.f, S1 = 0.f;
    for (int r = blockIdx.x * 4 + q; r < R; r += 64) {
        S0 += part[(size_t)r * 128 + c];
        S1 += part[(size_t)r * 128 + 64 + c];
    }
    r0[q][c] = S0; r1[q][c] = S1;
    __syncthreads();
    if (threadIdx.x < 64)
        part2[blockIdx.x * 128 + c] = r0[0][c] + r0[1][c] + r0[2][c] + r0[3][c];
    else if (threadIdx.x < 128) {
        int cc = threadIdx.x - 64;
        part2[blockIdx.x * 128 + 64 + cc] =
            r1[0][cc] + r1[1][cc] + r1[2][cc] + r1[3][cc];
    }
}

// ---- stage B: sum R partial rows (small R), emit scale/shift -----------
__global__ void k_stats_reduce(const float* __restrict__ part, int R,
                               const float* __restrict__ g,
                               const float* __restrict__ b,
                               float* __restrict__ ss) {
    __shared__ float r0[4][64], r1[4][64];
    int q = threadIdx.x >> 6, c = threadIdx.x & 63;
    float S0 = 0.f, S1 = 0.f;
    for (int r = q; r < R; r += 4) {
        S0 += part[(size_t)r * 128 + c];
        S1 += part[(size_t)r * 128 + 64 + c];
    }
    r0[q][c] = S0; r1[q][c] = S1;
    __syncthreads();
    if (threadIdx.x < 64) {
        float s0 = r0[0][c] + r0[1][c] + r0[2][c] + r0[3][c];
        float s1 = r1[0][c] + r1[1][c] + r1[2][c] + r1[3][c];
        float inv_n = 1.f / (float)N_NODES;
        float mu = s0 * inv_n;
        float var = s1 * inv_n - mu * mu;
        float rs = rsqrtf(var + 1e-5f);
        float sc = rs * g[c];
        ss[c] = sc;
        ss[64 + c] = b[c] - mu * sc;
    }
}

// vectorized BN apply: 8 elements/thread (channels contiguous, 8 | 64)
__global__ __launch_bounds__(256) void k_bn_apply(
    const float* __restrict__ t, const float* __restrict__ ss,
    float* __restrict__ h, unsigned short* __restrict__ hb) {
    int idx = (blockIdx.x * 256 + threadIdx.x) * 8;
    if (idx >= N_NODES * ND) return;
    int c = idx & (ND - 1);
    f32x4 sc0 = *(const f32x4*)(ss + c);
    f32x4 sc1 = *(const f32x4*)(ss + c + 4);
    f32x4 sh0 = *(const f32x4*)(ss + ND + c);
    f32x4 sh1 = *(const f32x4*)(ss + ND + c + 4);
    f32x4 v0 = *(const f32x4*)(t + idx);
    f32x4 v1 = *(const f32x4*)(t + idx + 4);
    f32x4 r0, r1;
#pragma unroll
    for (int j = 0; j < 4; ++j) { r0[j] = v0[j] * sc0[j] + sh0[j]; r1[j] = v1[j] * sc1[j] + sh1[j]; }
    *(f32x4*)(h + idx) = r0;
    *(f32x4*)(h + idx + 4) = r1;
    u32x4 u;
    u[0] = cvtpk(r0[0], r0[1]);
    u[1] = cvtpk(r0[2], r0[3]);
    u[2] = cvtpk(r1[0], r1[1]);
    u[3] = cvtpk(r1[2], r1[3]);
    *(u32x4*)(hb + idx) = u;
}

// ---------------- counting sort of edges by dst -------------------------
__global__ __launch_bounds__(256) void k_hist(const int* __restrict__ ei,
                                              int* __restrict__ hist) {
    int e = blockIdx.x * 256 + threadIdx.x;
    if (e < N_EDGES) atomicAdd(&hist[ei[N_EDGES + e]], 1);
}

__global__ __launch_bounds__(1024) void k_scan1(const int* __restrict__ hist,
                                                int* __restrict__ chunksum) {
    __shared__ int s[1024];
    int t = threadIdx.x;
    int i = blockIdx.x * 1024 + t;
    s[t] = (i < N_NODES) ? hist[i] : 0;
    __syncthreads();
    for (int off = 512; off; off >>= 1) {
        if (t < off) s[t] += s[t + off];
        __syncthreads();
    }
    if (t == 0) chunksum[blockIdx.x] = s[0];
}

__global__ void k_scan2(int* __restrict__ chunksum, int n) {
    if (threadIdx.x == 0) {
        int acc = 0;
        for (int i = 0; i < n; ++i) { int v = chunksum[i]; chunksum[i] = acc; acc += v; }
    }
}

__global__ __launch_bounds__(1024) void k_scan3(const int* __restrict__ hist,
                                                const int* __restrict__ chunksum,
                                                int* __restrict__ cursor,
                                                int* __restrict__ rowptr) {
    __shared__ int s[1024];
    int t = threadIdx.x;
    int i = blockIdx.x * 1024 + t;
    int v = (i < N_NODES) ? hist[i] : 0;
    s[t] = v;
    __syncthreads();
    for (int off = 1; off < 1024; off <<= 1) {
        int u = (t >= off) ? s[t - off] : 0;
        __syncthreads();
        s[t] += u;
        __syncthreads();
    }
    if (i < N_NODES) {
        int ex = chunksum[blockIdx.x] + s[t] - v;  // exclusive
        cursor[i] = ex;
        rowptr[i] = ex;
    }
}

__global__ __launch_bounds__(256) void k_scatter(const int* __restrict__ ei,
                                                 int* __restrict__ cursor,
                                                 int* __restrict__ sD,
                                                 int* __restrict__ sS,
                                                 int* __restrict__ sE) {
    int e = blockIdx.x * 256 + threadIdx.x;
    if (e >= N_EDGES) return;
    int d = ei[N_EDGES + e];
    int pos = atomicAdd(&cursor[d], 1);
    sD[pos] = d;
    sS[pos] = ei[e];
    sE[pos] = e;
}

// edge projection into sorted order (layer-invariant, once per call)
__global__ __launch_bounds__(256) void k_eproj_sorted(
    const float* __restrict__ ea, const int* __restrict__ sE,
    const float* __restrict__ Wep, const float* __restrict__ bep,
    unsigned short* __restrict__ e_bf) {
    long idx = (long)blockIdx.x * blockDim.x + threadIdx.x;
    long tot = (long)N_EDGES * 32;
    if (idx >= tot) return;
    int p = (int)(idx >> 5), col = (int)(idx & 31);
    int e = sE[p];
    float v = spf(ea[2 * e] * Wep[col] + ea[2 * e + 1] * Wep[32 + col] + bep[col]);
    e_bf[idx] = f2bf(v);
}

// ---- fused weight pack: all 3 layers x {We1,We2,Wn1,Wn2} in ONE launch --
__global__ __launch_bounds__(256) void k_pack_all(
    const float* __restrict__ We1, const float* __restrict__ We2,
    const float* __restrict__ Wn1, const float* __restrict__ Wn2,
    unsigned short* __restrict__ pA1, unsigned short* __restrict__ pA2,
    unsigned short* __restrict__ pWn1, unsigned short* __restrict__ pWn2) {
    int tid = blockIdx.x * 256 + threadIdx.x;
    const int PER_L = (40 + 32 + 48 + 16) * 64;  // 8704
    if (tid >= 3 * PER_L) return;
    int layer = tid / PER_L;
    int r = tid % PER_L;
    const float* W;
    unsigned short* out;
    int ncols, lt;
    if (r < 40 * 64) {
        lt = r; W = We1 + (size_t)layer * 160 * 128; out = pA1 + (size_t)layer * 40 * 64 * 8;
        ncols = 128;
    } else if (r < 72 * 64) {
        lt = r - 40 * 64; W = We2 + (size_t)layer * 128 * 128; out = pA2 + (size_t)layer * 32 * 64 * 8;
        ncols = 128;
    } else if (r < 120 * 64) {
        lt = r - 72 * 64; W = Wn1 + (size_t)layer * 192 * 128; out = pWn1 + (size_t)layer * 48 * 64 * 8;
        ncols = 128;
    } else {
        lt = r - 120 * 64; W = Wn2 + (size_t)layer * 128 * 64; out = pWn2 + (size_t)layer * 16 * 64 * 8;
        ncols = 64;
    }
    int nfrag = ncols >> 4;
    int l = lt & 63; int fr = lt >> 6; int nf = fr % nfrag; int ks = fr / nfrag;
    int n = 16 * nf + (l & 15);
    int k0 = 32 * ks + 8 * (l >> 4);
#pragma unroll
    for (int rr = 0; rr < 8; ++rr)
        out[lt * 8 + rr] = f2bf(W[(k0 + rr) * ncols + n]);
}

// ---------------- MFMA edge conv on dst-sorted edges --------------------
// Round-23 register-bounded form + cvt_pk packing in both epilogues.
template <bool EPRE>
__global__ __launch_bounds__(256, 4) void k_edge_mfma_s(
    const unsigned short* __restrict__ h_bf, const unsigned short* __restrict__ e_bf,
    const float* __restrict__ ea, const int* __restrict__ sE,
    const float* __restrict__ Wep, const float* __restrict__ bep,
    const int* __restrict__ sD, const int* __restrict__ sS,
    const int* __restrict__ rowptr, const int* __restrict__ hist,
    const unsigned short* __restrict__ pA1, const float* __restrict__ be1,
    const unsigned short* __restrict__ pA2, const float* __restrict__ be2,
    float* __restrict__ aggr) {
    __shared__ unsigned short P[WPB][32][136];   // per-wave P; reused as 128-row stage
    __shared__ int dstB[128];
    __shared__ unsigned short eL[EPRE ? 64 : 128 * 32];

    int lane = threadIdx.x & 63;
    int w = threadIdx.x >> 6;
    int m = lane & 15, g = lane >> 4;
    int tile0 = blockIdx.x * 128;
    int wbase = tile0 + 32 * w;

    int eD0 = sD[wbase + m];
    int eD1 = sD[wbase + 16 + m];
    int eS0 = sS[wbase + m];
    int eS1 = sS[wbase + 16 + m];

    if constexpr (!EPRE) {
        int col = threadIdx.x & 31;
        int r0 = threadIdx.x >> 5;
        float w0 = Wep[col], w1 = Wep[32 + col], bb = bep[col];
#pragma unroll
        for (int i = 0; i < 16; ++i) {
            int em = r0 + 8 * i;
            int e = sE[tile0 + em];
            eL[em * 32 + col] = f2bf(spf(ea[2 * e] * w0 + ea[2 * e + 1] * w1 + bb));
        }
        __syncthreads();
    }

    // ---- GEMM1 (K=160) in four nf-quarters: acc = 16 AGPR per region ----
#pragma unroll
    for (int qt = 0; qt < 4; ++qt) {
        f32x4 acc[2][2];
#pragma unroll
        for (int mf = 0; mf < 2; ++mf)
#pragma unroll
            for (int n2 = 0; n2 < 2; ++n2) acc[mf][n2] = (f32x4){0.f, 0.f, 0.f, 0.f};
#pragma unroll
        for (int ks = 0; ks < 5; ++ks) {
            bf16x8 b0, b1;
            if (ks < 2) {
                b0 = *(const bf16x8*)(h_bf + (size_t)eD0 * 64 + ks * 32 + 8 * g);
                b1 = *(const bf16x8*)(h_bf + (size_t)eD1 * 64 + ks * 32 + 8 * g);
            } else if (ks < 4) {
                b0 = *(const bf16x8*)(h_bf + (size_t)eS0 * 64 + (ks - 2) * 32 + 8 * g);
                b1 = *(const bf16x8*)(h_bf + (size_t)eS1 * 64 + (ks - 2) * 32 + 8 * g);
            } else {
                if constexpr (EPRE) {
                    b0 = *(const bf16x8*)(e_bf + (size_t)(wbase + m) * 32 + 8 * g);
                    b1 = *(const bf16x8*)(e_bf + (size_t)(wbase + 16 + m) * 32 + 8 * g);
                } else {
                    b0 = *(const bf16x8*)&eL[(32 * w + m) * 32 + 8 * g];
                    b1 = *(const bf16x8*)&eL[(32 * w + 16 + m) * 32 + 8 * g];
                }
            }
#pragma unroll
            for (int n2 = 0; n2 < 2; ++n2) {
                int nf = qt * 2 + n2;
                bf16x8 a = *(const bf16x8*)(pA1 + ((ks * 8 + nf) * 64 + lane) * 8);
                acc[0][n2] = __builtin_amdgcn_mfma_f32_16x16x32_bf16(a, b0, acc[0][n2], 0, 0, 0);
                acc[1][n2] = __builtin_amdgcn_mfma_f32_16x16x32_bf16(a, b1, acc[1][n2], 0, 0, 0);
            }
        }
        // epilogue 1 (this quarter): bias + fast softplus -> P (bf16) in LDS
#pragma unroll
        for (int n2 = 0; n2 < 2; ++n2) {
            int nf = qt * 2 + n2;
            f32x4 bb = *(const f32x4*)(be1 + 16 * nf + 4 * g);
#pragma unroll
            for (int mf = 0; mf < 2; ++mf) {
                f32x4 c = acc[mf][n2];
                unsigned int u01 = cvtpk(spf(c[0] + bb[0]), spf(c[1] + bb[1]));
                unsigned int u23 = cvtpk(spf(c[2] + bb[2]), spf(c[3] + bb[3]));
                unsigned int* dst = (unsigned int*)&P[w][m + 16 * mf][16 * nf + 4 * g];
                dst[0] = u01; dst[1] = u23;
            }
        }
    }

    // ---- GEMM2 (K=128) per m-fragment, two nf-halves; 8-reg deferral ----
    unsigned short (*Pf)[136] = (unsigned short(*)[136]) & P[0][0][0];
#pragma unroll
    for (int mf = 0; mf < 2; ++mf) {
        unsigned int defer[8];
#pragma unroll
        for (int half = 0; half < 2; ++half) {
            f32x4 acc2[4];
#pragma unroll
            for (int n2 = 0; n2 < 4; ++n2) acc2[n2] = (f32x4){0.f, 0.f, 0.f, 0.f};
#pragma unroll
            for (int ks = 0; ks < 4; ++ks) {
                bf16x8 b = *(const bf16x8*)&P[w][m + 16 * mf][32 * ks + 8 * g];
#pragma unroll
                for (int n2 = 0; n2 < 4; ++n2) {
                    int nf = half * 4 + n2;
                    bf16x8 a = *(const bf16x8*)(pA2 + ((ks * 8 + nf) * 64 + lane) * 8);
                    acc2[n2] = __builtin_amdgcn_mfma_f32_16x16x32_bf16(a, b, acc2[n2], 0, 0, 0);
                }
            }
            if (half == 0) {
#pragma unroll
                for (int n2 = 0; n2 < 4; ++n2) {
                    int nf = n2;
                    f32x4 bb = *(const f32x4*)(be2 + 16 * nf + 4 * g);
                    f32x4 c = acc2[n2];
                    defer[2 * n2] = cvtpk(spf(c[0] + bb[0]), spf(c[1] + bb[1]));
                    defer[2 * n2 + 1] = cvtpk(spf(c[2] + bb[2]), spf(c[3] + bb[3]));
                }
            } else {
#pragma unroll
                for (int n2 = 0; n2 < 4; ++n2) {
                    int nf = 4 + n2;
                    f32x4 bb = *(const f32x4*)(be2 + 16 * nf + 4 * g);
                    f32x4 c = acc2[n2];
                    unsigned int* dst =
                        (unsigned int*)&Pf[32 * w + 16 * mf + m][16 * nf + 4 * g];
                    dst[0] = cvtpk(spf(c[0] + bb[0]), spf(c[1] + bb[1]));
                    dst[1] = cvtpk(spf(c[2] + bb[2]), spf(c[3] + bb[3]));
                }
#pragma unroll
                for (int n2 = 0; n2 < 4; ++n2) {
                    unsigned int* dst =
                        (unsigned int*)&Pf[32 * w + 16 * mf + m][16 * n2 + 4 * g];
                    dst[0] = defer[2 * n2];
                    dst[1] = defer[2 * n2 + 1];
                }
            }
        }
    }
    if (g == 0) {
        dstB[32 * w + m] = eD0;
        dstB[32 * w + 16 + m] = eD1;
    }
    __syncthreads();

    // ---- block-wide run-length segmented reduction ----
    int rbeg = 32 * w, rend = rbeg + 32;
    int r = rbeg;
    if (w) {  // skip rows continuing a run that started in a lower wave
        while (r < rend && dstB[r] == dstB[r - 1]) ++r;
    }
    while (r < rend) {
        int d = dstB[r];
        float a0 = 0.f, a1 = 0.f;
        int rr = r;
        do {
            unsigned int u = *(const unsigned int*)&Pf[rr][2 * lane];
            a0 += lo_bf(u);
            a1 += hi_bf(u);
            ++rr;
        } while (rr < 128 && dstB[rr] == d);
        int s0 = rowptr[d];
        bool interior = (s0 >= tile0) && (s0 + hist[d] <= tile0 + 128);
        float* base = aggr + (size_t)d * HD + 2 * lane;
        if (interior) {
            base[0] = a0;
            base[1] = a1;
        } else {
            atomicAdd(base, a0);
            atomicAdd(base + 1, a1);
        }
        r = rr;
    }
}

// ---------------- MFMA node update: 2 waves / 32 nodes ------------------
__global__ __launch_bounds__(128, 2) void k_node_mfma(
    const unsigned short* __restrict__ h_bf, const float* __restrict__ aggr,
    const float* __restrict__ h,
    const unsigned short* __restrict__ pWn1, const float* __restrict__ bn1,
    const unsigned short* __restrict__ pWn2, const float* __restrict__ bn2,
    float* __restrict__ t, float* __restrict__ partU) {
    __shared__ unsigned short P[32][136];

    int lane = threadIdx.x & 63;
    int wv = threadIdx.x >> 6;   // 0 or 1
    int m = lane & 15, g = lane >> 4;
    int wbase = blockIdx.x * 32;
    int n0 = wbase + m, n1 = wbase + 16 + m;
    bool v0 = n0 < N_NODES, v1 = n1 < N_NODES;
    int c0 = v0 ? n0 : N_NODES - 1;
    int c1 = v1 ? n1 : N_NODES - 1;

    f32x4 acc[2][4];
#pragma unroll
    for (int mf = 0; mf < 2; ++mf)
#pragma unroll
        for (int n2 = 0; n2 < 4; ++n2) acc[mf][n2] = (f32x4){0.f, 0.f, 0.f, 0.f};

    // ---- GEMM1: K = 192 (h 64 | aggr 128); this wave: nf = 4*wv..4*wv+3
#pragma unroll
    for (int ks = 0; ks < 6; ++ks) {
        bf16x8 b0, b1;
        if (ks < 2) {
            b0 = *(const bf16x8*)(h_bf + (size_t)c0 * 64 + ks * 32 + 8 * g);
            b1 = *(const bf16x8*)(h_bf + (size_t)c1 * 64 + ks * 32 + 8 * g);
        } else {
            b0 = ld8_f32_bf(aggr + (size_t)c0 * 128 + (ks - 2) * 32 + 8 * g);
            b1 = ld8_f32_bf(aggr + (size_t)c1 * 128 + (ks - 2) * 32 + 8 * g);
        }
#pragma unroll
        for (int n2 = 0; n2 < 4; ++n2) {
            int nf = 4 * wv + n2;
            bf16x8 a = *(const bf16x8*)(pWn1 + ((ks * 8 + nf) * 64 + lane) * 8);
            acc[0][n2] = __builtin_amdgcn_mfma_f32_16x16x32_bf16(a, b0, acc[0][n2], 0, 0, 0);
            acc[1][n2] = __builtin_amdgcn_mfma_f32_16x16x32_bf16(a, b1, acc[1][n2], 0, 0, 0);
        }
    }

    // ---- epilogue 1: bias + fast softplus -> P columns of this wave ----
#pragma unroll
    for (int n2 = 0; n2 < 4; ++n2) {
        int nf = 4 * wv + n2;
        f32x4 bb = *(const f32x4*)(bn1 + 16 * nf + 4 * g);
#pragma unroll
        for (int mf = 0; mf < 2; ++mf) {
            f32x4 c = acc[mf][n2];
            unsigned int u01 = cvtpk(spf(c[0] + bb[0]), spf(c[1] + bb[1]));
            unsigned int u23 = cvtpk(spf(c[2] + bb[2]), spf(c[3] + bb[3]));
            unsigned int* dst = (unsigned int*)&P[m + 16 * mf][16 * nf + 4 * g];
            dst[0] = u01; dst[1] = u23;
        }
    }
    __syncthreads();

    f32x4 acc2[2][2];
#pragma unroll
    for (int mf = 0; mf < 2; ++mf)
#pragma unroll
        for (int n2 = 0; n2 < 2; ++n2) acc2[mf][n2] = (f32x4){0.f, 0.f, 0.f, 0.f};

    // ---- GEMM2: K = 128, N = 64; this wave: nf = 2*wv..2*wv+1 ----
#pragma unroll
    for (int ks = 0; ks < 4; ++ks) {
        bf16x8 b0 = *(const bf16x8*)&P[m][32 * ks + 8 * g];
        bf16x8 b1 = *(const bf16x8*)&P[m + 16][32 * ks + 8 * g];
#pragma unroll
        for (int n2 = 0; n2 < 2; ++n2) {
            int nf = 2 * wv + n2;
            bf16x8 a = *(const bf16x8*)(pWn2 + ((ks * 4 + nf) * 64 + lane) * 8);
            acc2[0][n2] = __builtin_amdgcn_mfma_f32_16x16x32_bf16(a, b0, acc2[0][n2], 0, 0, 0);
            acc2[1][n2] = __builtin_amdgcn_mfma_f32_16x16x32_bf16(a, b1, acc2[1][n2], 0, 0, 0);
        }
    }

    // ---- epilogue 2: +bn2 +h residual -> t; partial BN stats -----------
#pragma unroll
    for (int n2 = 0; n2 < 2; ++n2) {
        int nf = 2 * wv + n2;
        f32x4 bb = *(const f32x4*)(bn2 + 16 * nf + 4 * g);
        f32x4 s0v = (f32x4){0.f, 0.f, 0.f, 0.f};
        f32x4 s1v = (f32x4){0.f, 0.f, 0.f, 0.f};
#pragma unroll
        for (int mf = 0; mf < 2; ++mf) {
            int cn = mf ? c1 : c0;
            bool vn = mf ? v1 : v0;
            f32x4 hv = *(const f32x4*)(h + (size_t)cn * 64 + 16 * nf + 4 * g);
            f32x4 c = acc2[mf][n2];
            f32x4 tn;
#pragma unroll
            for (int j = 0; j < 4; ++j) tn[j] = c[j] + bb[j] + hv[j];
            if (vn) *(f32x4*)(t + (size_t)cn * 64 + 16 * nf + 4 * g) = tn;
#pragma unroll
            for (int j = 0; j < 4; ++j) {
                float tv = vn ? tn[j] : 0.f;
                s0v[j] += tv;
                s1v[j] += tv * tv;
            }
        }
#pragma unroll
        for (int j = 0; j < 4; ++j) {
#pragma unroll
            for (int k = 1; k <= 8; k <<= 1) {
                s0v[j] += __shfl_xor(s0v[j], k);
                s1v[j] += __shfl_xor(s1v[j], k);
            }
        }
        if (m == 0) {
#pragma unroll
            for (int j = 0; j < 4; ++j) {
                int ch = 16 * nf + 4 * g + j;
                partU[(size_t)blockIdx.x * 128 + ch] = s0v[j];
                partU[(size_t)blockIdx.x * 128 + 64 + ch] = s1v[j];
            }
        }
    }
}

// ---------------- pooling + readout (unchanged) -------------------------
__global__ __launch_bounds__(256) void k_pool(
    const float* __restrict__ h, const int* __restrict__ batch,
    float* __restrict__ pooled, float* __restrict__ cnt) {
    int lane = threadIdx.x & 63;
    int wave = (blockIdx.x * blockDim.x + threadIdx.x) >> 6;
    int nw = (gridDim.x * blockDim.x) >> 6;
    int chunk = (N_NODES + nw - 1) / nw;
    int s = wave * chunk;
    int epos = min(N_NODES, s + chunk);
    if (s >= N_NODES) return;
    int curg = batch[s];
    float acc = 0.f, c = 0.f;
    for (int i = s; i < epos; ++i) {
        int g = batch[i];
        if (g != curg) {
            atomicAdd(&pooled[curg * ND + lane], acc);
            if (lane == 0) atomicAdd(&cnt[curg], c);
            acc = 0.f; c = 0.f; curg = g;
        }
        acc += h[i * ND + lane];
        c += 1.f;
    }
    atomicAdd(&pooled[curg * ND + lane], acc);
    if (lane == 0) atomicAdd(&cnt[curg], c);
}

__global__ __launch_bounds__(256) void k_readout(
    const float* __restrict__ pooled, const float* __restrict__ cnt,
    const float* __restrict__ Wo1, const float* __restrict__ bo1,
    const float* __restrict__ Wo2, const float* __restrict__ bo2,
    float* __restrict__ out) {
    __shared__ float pbuf[WPB][ND];
    int lane = threadIdx.x & 63;
    int wid = threadIdx.x >> 6;
    int g = blockIdx.x * WPB + wid;
    bool valid = g < N_GRAPH;
    int gc = valid ? g : N_GRAPH - 1;
    float c = fmaxf(cnt[gc], 1.f);
    pbuf[wid][lane] = pooled[gc * ND + lane] / c;
    __syncthreads();
    float h0 = bo1[lane], h1 = bo1[64 + lane];
#pragma unroll 8
    for (int k = 0; k < ND; ++k) {
        float pk = pbuf[wid][k];
        h0 += pk * Wo1[k * HD + lane];
        h1 += pk * Wo1[k * HD + 64 + lane];
    }
    float s = sp(h0) * Wo2[lane] + sp(h1) * Wo2[64 + lane];
#pragma unroll
    for (int off = 32; off; off >>= 1) s += __shfl_down(s, off);
    if (valid && lane == 0) out[g] = s + bo2[0];
}

extern "C" void kernel_launch(void* const* d_in, const int* in_sizes, int n_in,
                              void* d_out, int out_size, void* d_ws, size_t ws_size,
                              hipStream_t stream) {
    const float* x       = (const float*)d_in[0];
    const float* ea      = (const float*)d_in[1];
    const int*   ei      = (const int*)d_in[2];
    const int*   batch   = (const int*)d_in[3];
    const float* Wnp     = (const float*)d_in[4];
    const float* bnp     = (const float*)d_in[5];
    const float* g_np    = (const float*)d_in[6];
    const float* be_np   = (const float*)d_in[7];
    const float* Wep     = (const float*)d_in[8];
    const float* bep     = (const float*)d_in[9];
    const float* We1     = (const float*)d_in[10];
    const float* be1     = (const float*)d_in[11];
    const float* We2     = (const float*)d_in[12];
    const float* be2     = (const float*)d_in[13];
    const float* Wn1     = (const float*)d_in[14];
    const float* bn1     = (const float*)d_in[15];
    const float* Wn2     = (const float*)d_in[16];
    const float* bn2     = (const float*)d_in[17];
    const float* g_bn    = (const float*)d_in[18];
    const float* b_bn    = (const float*)d_in[19];
    const float* Wo1     = (const float*)d_in[20];
    const float* bo1     = (const float*)d_in[21];
    const float* Wo2     = (const float*)d_in[22];
    const float* bo2     = (const float*)d_in[23];

    float* ws = (float*)d_ws;
    size_t off = 0;
    float* h      = ws + off; off += (size_t)N_NODES * ND;
    float* t      = ws + off; off += (size_t)N_NODES * ND;
    float* aggr   = ws + off; off += (size_t)N_NODES * HD;
    float* ss     = ws + off; off += 2 * ND;
    float* pooled = ws + off; off += N_GRAPH * ND;
    float* cnt    = ws + off; off += 512;
    unsigned short* h_bf = (unsigned short*)(ws + off); off += (size_t)N_NODES * ND / 2;
    unsigned short* pA1  = (unsigned short*)(ws + off); off += 3 * 5 * 8 * 64 * 8 / 2;
    unsigned short* pA2  = (unsigned short*)(ws + off); off += 3 * 4 * 8 * 64 * 8 / 2;
    unsigned short* pWn1 = (unsigned short*)(ws + off); off += 3 * 6 * 8 * 64 * 8 / 2;
    unsigned short* pWn2 = (unsigned short*)(ws + off); off += 3 * 4 * 4 * 64 * 8 / 2;
    int* sD       = (int*)(ws + off); off += N_EDGES;
    int* sS       = (int*)(ws + off); off += N_EDGES;
    int* sE       = (int*)(ws + off); off += N_EDGES;
    int* hist     = (int*)(ws + off); off += N_NODES;
    int* cursor   = (int*)(ws + off); off += N_NODES;
    int* rowptr   = (int*)(ws + off); off += N_NODES;
    int* chunksum = (int*)(ws + off); off += 64;
    float* partN  = ws + off; off += 512 * 128;
    float* partU  = ws + off; off += (size_t)NBU * 128;
    float* part2  = ws + off; off += 16 * 128;
    size_t base_bytes = off * sizeof(float);
    unsigned short* e_bf = (unsigned short*)(ws + off);
    bool epre = (ws_size >= base_bytes + (size_t)N_EDGES * 32 * 2);

    float* outp = (float*)d_out;

    const int NCH = (N_NODES + 1023) / 1024;  // 49

    // ---- counting sort of edges by dst -> CSR (once per call) ----
    hipMemsetAsync(hist, 0, N_NODES * sizeof(int), stream);
    k_hist<<<(N_EDGES + 255) / 256, 256, 0, stream>>>(ei, hist);
    k_scan1<<<NCH, 1024, 0, stream>>>(hist, chunksum);
    k_scan2<<<1, 64, 0, stream>>>(chunksum, NCH);
    k_scan3<<<NCH, 1024, 0, stream>>>(hist, chunksum, cursor, rowptr);
    k_scatter<<<(N_EDGES + 255) / 256, 256, 0, stream>>>(ei, cursor, sD, sS, sE);
    if (epre)
        k_eproj_sorted<<<(int)(((long)N_EDGES * 32 + 255) / 256), 256, 0, stream>>>(
            ea, sE, Wep, bep, e_bf);

    // ---- pack all weights (3 layers x 4 matrices) in one launch ----
    k_pack_all<<<(3 * 8704 + 255) / 256, 256, 0, stream>>>(
        We1, We2, Wn1, Wn2, pA1, pA2, pWn1, pWn2);

    // ---- node projection + BN (two-stage parallel stats) ----
    k_node_proj<<<512, 256, 0, stream>>>(x, Wnp, bnp, t, partN);
    k_stats_part<<<16, 256, 0, stream>>>(partN, 512, part2);
    k_stats_reduce<<<1, 256, 0, stream>>>(part2, 16, g_np, be_np, ss);
    k_bn_apply<<<(N_NODES * ND / 8 + 255) / 256, 256, 0, stream>>>(t, ss, h, h_bf);

    for (int l = 0; l < 3; ++l) {
        hipMemsetAsync(aggr, 0, (size_t)N_NODES * HD * sizeof(float), stream);
        if (epre)
            k_edge_mfma_s<true><<<N_EDGES / 128, 256, 0, stream>>>(
                h_bf, e_bf, ea, sE, Wep, bep, sD, sS, rowptr, hist,
                pA1 + (size_t)l * 40 * 64 * 8, be1 + l * HD,
                pA2 + (size_t)l * 32 * 64 * 8, be2 + l * HD, aggr);
        else
            k_edge_mfma_s<false><<<N_EDGES / 128, 256, 0, stream>>>(
                h_bf, e_bf, ea, sE, Wep, bep, sD, sS, rowptr, hist,
                pA1 + (size_t)l * 40 * 64 * 8, be1 + l * HD,
                pA2 + (size_t)l * 32 * 64 * 8, be2 + l * HD, aggr);

        k_node_mfma<<<NBU, 128, 0, stream>>>(
            h_bf, aggr, h,
            pWn1 + (size_t)l * 48 * 64 * 8, bn1 + l * HD,
            pWn2 + (size_t)l * 16 * 64 * 8, bn2 + l * ND, t, partU);
        k_stats_part<<<16, 256, 0, stream>>>(partU, NBU, part2);
        k_stats_reduce<<<1, 256, 0, stream>>>(part2, 16, g_bn + l * ND, b_bn + l * ND, ss);
        k_bn_apply<<<(N_NODES * ND / 8 + 255) / 256, 256, 0, stream>>>(t, ss, h, h_bf);
    }

    hipMemsetAsync(pooled, 0, (size_t)(N_GRAPH * ND + 512) * sizeof(float), stream);
    k_pool<<<512, 256, 0, stream>>>(h, batch, pooled, cnt);
    k_readout<<<(N_GRAPH + WPB - 1) / WPB, 256, 0, stream>>>(
        pooled, cnt, Wo1, bo1, Wo2, bo2, outp);
}

// Round 27
// 878.775 us; speedup vs baseline: 1.3450x; 1.0002x over previous
//
#include <hip/hip_runtime.h>
#include <hip/hip_bf16.h>

#define N_NODES 50000
#define N_EDGES 800000
#define N_GRAPH 500
#define ND 64
#define ED 32
#define HD 128
#define WPB 4   // waves per block (256 threads)
#define NBU ((N_NODES + 31) / 32)   // 1563 node blocks (32 nodes each)

typedef __attribute__((ext_vector_type(8))) short bf16x8;
typedef __attribute__((ext_vector_type(4))) float f32x4;
typedef __attribute__((ext_vector_type(2))) float f32x2;
typedef __attribute__((ext_vector_type(4))) unsigned int u32x4;

__device__ __forceinline__ float sp(float x) {
    return fmaxf(x, 0.f) + log1pf(expf(-fabsf(x)));
}

// fast softplus for the bf16 path (v_exp_f32/v_log_f32 based)
__device__ __forceinline__ float spf(float x) {
    return fmaxf(x, 0.f) + __logf(1.f + __expf(-fabsf(x)));
}

__device__ __forceinline__ unsigned short f2bf(float v) {
    __hip_bfloat16 b = __float2bfloat16(v);
    return *(unsigned short*)&b;
}

// single-instruction pack: lo=bf16(a), hi=bf16(b)  (v_cvt_pk_bf16_f32, RNE)
__device__ __forceinline__ unsigned int cvtpk(float a, float b) {
    unsigned int r;
    asm("v_cvt_pk_bf16_f32 %0, %1, %2" : "=v"(r) : "v"(a), "v"(b));
    return r;
}

__device__ __forceinline__ float lo_bf(unsigned int u) { return __uint_as_float(u << 16); }
__device__ __forceinline__ float hi_bf(unsigned int u) { return __uint_as_float(u & 0xffff0000u); }

// load 8 fp32 and round to bf16x8 via 4 cvt_pk
__device__ __forceinline__ bf16x8 ld8_f32_bf(const float* p) {
    f32x4 v0 = *(const f32x4*)p;
    f32x4 v1 = *(const f32x4*)(p + 4);
    u32x4 u;
    u[0] = cvtpk(v0[0], v0[1]);
    u[1] = cvtpk(v0[2], v0[3]);
    u[2] = cvtpk(v1[0], v1[1]);
    u[3] = cvtpk(v1[2], v1[3]);
    return *(bf16x8*)&u;
}

// ---------------- node projection: partial BN stats per block -----------
__global__ __launch_bounds__(256) void k_node_proj(
    const float* __restrict__ x, const float* __restrict__ Wnp,
    const float* __restrict__ bnp, float* __restrict__ t,
    float* __restrict__ partN) {
    __shared__ float red0[4][64], red1[4][64];
    int lane = threadIdx.x & 63;
    int wid = threadIdx.x >> 6;
    int wave = (blockIdx.x * blockDim.x + threadIdx.x) >> 6;
    int nw = (gridDim.x * blockDim.x) >> 6;
    float w[13];
#pragma unroll
    for (int k = 0; k < 13; ++k) w[k] = Wnp[k * ND + lane];
    float bb = bnp[lane];
    float s0 = 0.f, s1 = 0.f;
    for (int i = wave; i < N_NODES; i += nw) {
        float acc = bb;
#pragma unroll
        for (int k = 0; k < 13; ++k) acc += x[i * 13 + k] * w[k];
        float v = sp(acc);
        t[i * ND + lane] = v;
        s0 += v; s1 += v * v;
    }
    red0[wid][lane] = s0;
    red1[wid][lane] = s1;
    __syncthreads();
    int tid = threadIdx.x;
    if (tid < 64)
        partN[blockIdx.x * 128 + tid] =
            red0[0][tid] + red0[1][tid] + red0[2][tid] + red0[3][tid];
    else if (tid < 128) {
        int c = tid - 64;
        partN[blockIdx.x * 128 + tid] =
            red1[0][c] + red1[1][c] + red1[2][c] + red1[3][c];
    }
}

// ---- stage A: 16 blocks reduce R partial rows -> part2[16][128] --------
__global__ __launch_bounds__(256) void k_stats_part(
    const float* __restrict__ part, int R, float* __restrict__ part2) {
    __shared__ float r0[4][64], r1[4][64];
    int q = threadIdx.x >> 6, c = threadIdx.x & 63;
    float S0 = 0.f, S1 = 0.f;
    for (int r = blockIdx.x * 4 + q; r < R; r += 64) {
        S0 += part[(size_t)r * 128 + c];
        S1 += part[(size_t)r * 128 + 64 + c];
    }
    r0[q][c] = S0; r1[q][c] = S1;
    __syncthreads();
    if (threadIdx.x < 64)
        part2[blockIdx.x * 128 + c] = r0[0][c] + r0[1][c] + r0[2][c] + r0[3][c];
    else if (threadIdx.x < 128) {
        int cc = threadIdx.x - 64;
        part2[blockIdx.x * 128 + 64 + cc] =
            r1[0][cc] + r1[1][cc] + r1[2][cc] + r1[3][cc];
    }
}

// ---- stage B: sum R partial rows (small R), emit scale/shift -----------
__global__ void k_stats_reduce(const float* __restrict__ part, int R,
                               const float* __restrict__ g,
                               const float* __restrict__ b,
                               float* __restrict__ ss) {
    __shared__ float r0[4][64], r1[4][64];
    int q = threadIdx.x >> 6, c = threadIdx.x & 63;
    float S0 = 0.f, S1 = 0.f;
    for (int r = q; r < R; r += 4) {
        S0 += part[(size_t)r * 128 + c];
        S1 += part[(size_t)r * 128 + 64 + c];
    }
    r0[q][c] = S0; r1[q][c] = S1;
    __syncthreads();
    if (threadIdx.x < 64) {
        float s0 = r0[0][c] + r0[1][c] + r0[2][c] + r0[3][c];
        float s1 = r1[0][c] + r1[1][c] + r1[2][c] + r1[3][c];
        float inv_n = 1.f / (float)N_NODES;
        float mu = s0 * inv_n;
        float var = s1 * inv_n - mu * mu;
        float rs = rsqrtf(var + 1e-5f);
        float sc = rs * g[c];
        ss[c] = sc;
        ss[64 + c] = b[c] - mu * sc;
    }
}

// vectorized BN apply: 8 elements/thread (channels contiguous, 8 | 64)
__global__ __launch_bounds__(256) void k_bn_apply(
    const float* __restrict__ t, const float* __restrict__ ss,
    float* __restrict__ h, unsigned short* __restrict__ hb) {
    int idx = (blockIdx.x * 256 + threadIdx.x) * 8;
    if (idx >= N_NODES * ND) return;
    int c = idx & (ND - 1);
    f32x4 sc0 = *(const f32x4*)(ss + c);
    f32x4 sc1 = *(const f32x4*)(ss + c + 4);
    f32x4 sh0 = *(const f32x4*)(ss + ND + c);
    f32x4 sh1 = *(const f32x4*)(ss + ND + c + 4);
    f32x4 v0 = *(const f32x4*)(t + idx);
    f32x4 v1 = *(const f32x4*)(t + idx + 4);
    f32x4 r0, r1;
#pragma unroll
    for (int j = 0; j < 4; ++j) { r0[j] = v0[j] * sc0[j] + sh0[j]; r1[j] = v1[j] * sc1[j] + sh1[j]; }
    *(f32x4*)(h + idx) = r0;
    *(f32x4*)(h + idx + 4) = r1;
    u32x4 u;
    u[0] = cvtpk(r0[0], r0[1]);
    u[1] = cvtpk(r0[2], r0[3]);
    u[2] = cvtpk(r1[0], r1[1]);
    u[3] = cvtpk(r1[2], r1[3]);
    *(u32x4*)(hb + idx) = u;
}

// ---------------- counting sort of edges by dst -------------------------
__global__ __launch_bounds__(256) void k_hist(const int* __restrict__ ei,
                                              int* __restrict__ hist) {
    int e = blockIdx.x * 256 + threadIdx.x;
    if (e < N_EDGES) atomicAdd(&hist[ei[N_EDGES + e]], 1);
}

__global__ __launch_bounds__(1024) void k_scan1(const int* __restrict__ hist,
                                                int* __restrict__ chunksum) {
    __shared__ int s[1024];
    int t = threadIdx.x;
    int i = blockIdx.x * 1024 + t;
    s[t] = (i < N_NODES) ? hist[i] : 0;
    __syncthreads();
    for (int off = 512; off; off >>= 1) {
        if (t < off) s[t] += s[t + off];
        __syncthreads();
    }
    if (t == 0) chunksum[blockIdx.x] = s[0];
}

__global__ void k_scan2(int* __restrict__ chunksum, int n) {
    if (threadIdx.x == 0) {
        int acc = 0;
        for (int i = 0; i < n; ++i) { int v = chunksum[i]; chunksum[i] = acc; acc += v; }
    }
}

__global__ __launch_bounds__(1024) void k_scan3(const int* __restrict__ hist,
                                                const int* __restrict__ chunksum,
                                                int* __restrict__ cursor,
                                                int* __restrict__ rowptr) {
    __shared__ int s[1024];
    int t = threadIdx.x;
    int i = blockIdx.x * 1024 + t;
    int v = (i < N_NODES) ? hist[i] : 0;
    s[t] = v;
    __syncthreads();
    for (int off = 1; off < 1024; off <<= 1) {
        int u = (t >= off) ? s[t - off] : 0;
        __syncthreads();
        s[t] += u;
        __syncthreads();
    }
    if (i < N_NODES) {
        int ex = chunksum[blockIdx.x] + s[t] - v;  // exclusive
        cursor[i] = ex;
        rowptr[i] = ex;
    }
}

__global__ __launch_bounds__(256) void k_scatter(const int* __restrict__ ei,
                                                 int* __restrict__ cursor,
                                                 int* __restrict__ sD,
                                                 int* __restrict__ sS,
                                                 int* __restrict__ sE) {
    int e = blockIdx.x * 256 + threadIdx.x;
    if (e >= N_EDGES) return;
    int d = ei[N_EDGES + e];
    int pos = atomicAdd(&cursor[d], 1);
    sD[pos] = d;
    sS[pos] = ei[e];
    sE[pos] = e;
}

// mark nodes needing zero-init: run crosses a 128-edge tile boundary, or deg==0
__global__ __launch_bounds__(256) void k_mark(
    const int* __restrict__ rowptr, const int* __restrict__ hist,
    unsigned char* __restrict__ bflag) {
    int i = blockIdx.x * 256 + threadIdx.x;
    if (i >= N_NODES) return;
    int s = rowptr[i], d = hist[i];
    bflag[i] = (d == 0) || ((s >> 7) != ((s + d - 1) >> 7));
}

// zero only flagged aggr rows (layer-invariant flag set)
__global__ __launch_bounds__(256) void k_zero_rows(
    const unsigned char* __restrict__ bflag, float* __restrict__ aggr) {
    int idx = blockIdx.x * 256 + threadIdx.x;   // node*64 + pair
    if (idx >= N_NODES * 64) return;
    int node = idx >> 6;
    if (!bflag[node]) return;
    f32x2 z = (f32x2){0.f, 0.f};
    *(f32x2*)(aggr + (size_t)node * HD + 2 * (idx & 63)) = z;
}

// edge projection into sorted order (layer-invariant, once per call)
__global__ __launch_bounds__(256) void k_eproj_sorted(
    const float* __restrict__ ea, const int* __restrict__ sE,
    const float* __restrict__ Wep, const float* __restrict__ bep,
    unsigned short* __restrict__ e_bf) {
    long idx = (long)blockIdx.x * blockDim.x + threadIdx.x;
    long tot = (long)N_EDGES * 32;
    if (idx >= tot) return;
    int p = (int)(idx >> 5), col = (int)(idx & 31);
    int e = sE[p];
    float v = spf(ea[2 * e] * Wep[col] + ea[2 * e + 1] * Wep[32 + col] + bep[col]);
    e_bf[idx] = f2bf(v);
}

// ---- fused weight pack: all 3 layers x {We1,We2,Wn1,Wn2} in ONE launch --
__global__ __launch_bounds__(256) void k_pack_all(
    const float* __restrict__ We1, const float* __restrict__ We2,
    const float* __restrict__ Wn1, const float* __restrict__ Wn2,
    unsigned short* __restrict__ pA1, unsigned short* __restrict__ pA2,
    unsigned short* __restrict__ pWn1, unsigned short* __restrict__ pWn2) {
    int tid = blockIdx.x * 256 + threadIdx.x;
    const int PER_L = (40 + 32 + 48 + 16) * 64;  // 8704
    if (tid >= 3 * PER_L) return;
    int layer = tid / PER_L;
    int r = tid % PER_L;
    const float* W;
    unsigned short* out;
    int ncols, lt;
    if (r < 40 * 64) {
        lt = r; W = We1 + (size_t)layer * 160 * 128; out = pA1 + (size_t)layer * 40 * 64 * 8;
        ncols = 128;
    } else if (r < 72 * 64) {
        lt = r - 40 * 64; W = We2 + (size_t)layer * 128 * 128; out = pA2 + (size_t)layer * 32 * 64 * 8;
        ncols = 128;
    } else if (r < 120 * 64) {
        lt = r - 72 * 64; W = Wn1 + (size_t)layer * 192 * 128; out = pWn1 + (size_t)layer * 48 * 64 * 8;
        ncols = 128;
    } else {
        lt = r - 120 * 64; W = Wn2 + (size_t)layer * 128 * 64; out = pWn2 + (size_t)layer * 16 * 64 * 8;
        ncols = 64;
    }
    int nfrag = ncols >> 4;
    int l = lt & 63; int fr = lt >> 6; int nf = fr % nfrag; int ks = fr / nfrag;
    int n = 16 * nf + (l & 15);
    int k0 = 32 * ks + 8 * (l >> 4);
#pragma unroll
    for (int rr = 0; rr < 8; ++rr)
        out[lt * 8 + rr] = f2bf(W[(k0 + rr) * ncols + n]);
}

// ---------------- MFMA edge conv on dst-sorted edges --------------------
// Round-23 register-bounded form + cvt_pk packing in both epilogues.
template <bool EPRE>
__global__ __launch_bounds__(256, 4) void k_edge_mfma_s(
    const unsigned short* __restrict__ h_bf, const unsigned short* __restrict__ e_bf,
    const float* __restrict__ ea, const int* __restrict__ sE,
    const float* __restrict__ Wep, const float* __restrict__ bep,
    const int* __restrict__ sD, const int* __restrict__ sS,
    const int* __restrict__ rowptr, const int* __restrict__ hist,
    const unsigned short* __restrict__ pA1, const float* __restrict__ be1,
    const unsigned short* __restrict__ pA2, const float* __restrict__ be2,
    float* __restrict__ aggr) {
    __shared__ unsigned short P[WPB][32][136];   // per-wave P; reused as 128-row stage
    __shared__ int dstB[128];
    __shared__ unsigned short eL[EPRE ? 64 : 128 * 32];

    int lane = threadIdx.x & 63;
    int w = threadIdx.x >> 6;
    int m = lane & 15, g = lane >> 4;
    int tile0 = blockIdx.x * 128;
    int wbase = tile0 + 32 * w;

    int eD0 = sD[wbase + m];
    int eD1 = sD[wbase + 16 + m];
    int eS0 = sS[wbase + m];
    int eS1 = sS[wbase + 16 + m];

    if constexpr (!EPRE) {
        int col = threadIdx.x & 31;
        int r0 = threadIdx.x >> 5;
        float w0 = Wep[col], w1 = Wep[32 + col], bb = bep[col];
#pragma unroll
        for (int i = 0; i < 16; ++i) {
            int em = r0 + 8 * i;
            int e = sE[tile0 + em];
            eL[em * 32 + col] = f2bf(spf(ea[2 * e] * w0 + ea[2 * e + 1] * w1 + bb));
        }
        __syncthreads();
    }

    // ---- GEMM1 (K=160) in four nf-quarters: acc = 16 AGPR per region ----
#pragma unroll
    for (int qt = 0; qt < 4; ++qt) {
        f32x4 acc[2][2];
#pragma unroll
        for (int mf = 0; mf < 2; ++mf)
#pragma unroll
            for (int n2 = 0; n2 < 2; ++n2) acc[mf][n2] = (f32x4){0.f, 0.f, 0.f, 0.f};
#pragma unroll
        for (int ks = 0; ks < 5; ++ks) {
            bf16x8 b0, b1;
            if (ks < 2) {
                b0 = *(const bf16x8*)(h_bf + (size_t)eD0 * 64 + ks * 32 + 8 * g);
                b1 = *(const bf16x8*)(h_bf + (size_t)eD1 * 64 + ks * 32 + 8 * g);
            } else if (ks < 4) {
                b0 = *(const bf16x8*)(h_bf + (size_t)eS0 * 64 + (ks - 2) * 32 + 8 * g);
                b1 = *(const bf16x8*)(h_bf + (size_t)eS1 * 64 + (ks - 2) * 32 + 8 * g);
            } else {
                if constexpr (EPRE) {
                    b0 = *(const bf16x8*)(e_bf + (size_t)(wbase + m) * 32 + 8 * g);
                    b1 = *(const bf16x8*)(e_bf + (size_t)(wbase + 16 + m) * 32 + 8 * g);
                } else {
                    b0 = *(const bf16x8*)&eL[(32 * w + m) * 32 + 8 * g];
                    b1 = *(const bf16x8*)&eL[(32 * w + 16 + m) * 32 + 8 * g];
                }
            }
#pragma unroll
            for (int n2 = 0; n2 < 2; ++n2) {
                int nf = qt * 2 + n2;
                bf16x8 a = *(const bf16x8*)(pA1 + ((ks * 8 + nf) * 64 + lane) * 8);
                acc[0][n2] = __builtin_amdgcn_mfma_f32_16x16x32_bf16(a, b0, acc[0][n2], 0, 0, 0);
                acc[1][n2] = __builtin_amdgcn_mfma_f32_16x16x32_bf16(a, b1, acc[1][n2], 0, 0, 0);
            }
        }
        // epilogue 1 (this quarter): bias + fast softplus -> P (bf16) in LDS
#pragma unroll
        for (int n2 = 0; n2 < 2; ++n2) {
            int nf = qt * 2 + n2;
            f32x4 bb = *(const f32x4*)(be1 + 16 * nf + 4 * g);
#pragma unroll
            for (int mf = 0; mf < 2; ++mf) {
                f32x4 c = acc[mf][n2];
                unsigned int u01 = cvtpk(spf(c[0] + bb[0]), spf(c[1] + bb[1]));
                unsigned int u23 = cvtpk(spf(c[2] + bb[2]), spf(c[3] + bb[3]));
                unsigned int* dst = (unsigned int*)&P[w][m + 16 * mf][16 * nf + 4 * g];
                dst[0] = u01; dst[1] = u23;
            }
        }
    }

    // ---- GEMM2 (K=128) per m-fragment, two nf-halves; 8-reg deferral ----
    unsigned short (*Pf)[136] = (unsigned short(*)[136]) & P[0][0][0];
#pragma unroll
    for (int mf = 0; mf < 2; ++mf) {
        unsigned int defer[8];
#pragma unroll
        for (int half = 0; half < 2; ++half) {
            f32x4 acc2[4];
#pragma unroll
            for (int n2 = 0; n2 < 4; ++n2) acc2[n2] = (f32x4){0.f, 0.f, 0.f, 0.f};
#pragma unroll
            for (int ks = 0; ks < 4; ++ks) {
                bf16x8 b = *(const bf16x8*)&P[w][m + 16 * mf][32 * ks + 8 * g];
#pragma unroll
                for (int n2 = 0; n2 < 4; ++n2) {
                    int nf = half * 4 + n2;
                    bf16x8 a = *(const bf16x8*)(pA2 + ((ks * 8 + nf) * 64 + lane) * 8);
                    acc2[n2] = __builtin_amdgcn_mfma_f32_16x16x32_bf16(a, b, acc2[n2], 0, 0, 0);
                }
            }
            if (half == 0) {
#pragma unroll
                for (int n2 = 0; n2 < 4; ++n2) {
                    int nf = n2;
                    f32x4 bb = *(const f32x4*)(be2 + 16 * nf + 4 * g);
                    f32x4 c = acc2[n2];
                    defer[2 * n2] = cvtpk(spf(c[0] + bb[0]), spf(c[1] + bb[1]));
                    defer[2 * n2 + 1] = cvtpk(spf(c[2] + bb[2]), spf(c[3] + bb[3]));
                }
            } else {
#pragma unroll
                for (int n2 = 0; n2 < 4; ++n2) {
                    int nf = 4 + n2;
                    f32x4 bb = *(const f32x4*)(be2 + 16 * nf + 4 * g);
                    f32x4 c = acc2[n2];
                    unsigned int* dst =
                        (unsigned int*)&Pf[32 * w + 16 * mf + m][16 * nf + 4 * g];
                    dst[0] = cvtpk(spf(c[0] + bb[0]), spf(c[1] + bb[1]));
                    dst[1] = cvtpk(spf(c[2] + bb[2]), spf(c[3] + bb[3]));
                }
#pragma unroll
                for (int n2 = 0; n2 < 4; ++n2) {
                    unsigned int* dst =
                        (unsigned int*)&Pf[32 * w + 16 * mf + m][16 * n2 + 4 * g];
                    dst[0] = defer[2 * n2];
                    dst[1] = defer[2 * n2 + 1];
                }
            }
        }
    }
    if (g == 0) {
        dstB[32 * w + m] = eD0;
        dstB[32 * w + 16 + m] = eD1;
    }
    __syncthreads();

    // ---- block-wide run-length segmented reduction ----
    int rbeg = 32 * w, rend = rbeg + 32;
    int r = rbeg;
    if (w) {  // skip rows continuing a run that started in a lower wave
        while (r < rend && dstB[r] == dstB[r - 1]) ++r;
    }
    while (r < rend) {
        int d = dstB[r];
        float a0 = 0.f, a1 = 0.f;
        int rr = r;
        do {
            unsigned int u = *(const unsigned int*)&Pf[rr][2 * lane];
            a0 += lo_bf(u);
            a1 += hi_bf(u);
            ++rr;
        } while (rr < 128 && dstB[rr] == d);
        int s0 = rowptr[d];
        bool interior = (s0 >= tile0) && (s0 + hist[d] <= tile0 + 128);
        float* base = aggr + (size_t)d * HD + 2 * lane;
        if (interior) {
            base[0] = a0;
            base[1] = a1;
        } else {
            atomicAdd(base, a0);
            atomicAdd(base + 1, a1);
        }
        r = rr;
    }
}

// ---------------- MFMA node update: 2 waves / 32 nodes ------------------
__global__ __launch_bounds__(128, 2) void k_node_mfma(
    const unsigned short* __restrict__ h_bf, const float* __restrict__ aggr,
    const float* __restrict__ h,
    const unsigned short* __restrict__ pWn1, const float* __restrict__ bn1,
    const unsigned short* __restrict__ pWn2, const float* __restrict__ bn2,
    float* __restrict__ t, float* __restrict__ partU) {
    __shared__ unsigned short P[32][136];

    int lane = threadIdx.x & 63;
    int wv = threadIdx.x >> 6;   // 0 or 1
    int m = lane & 15, g = lane >> 4;
    int wbase = blockIdx.x * 32;
    int n0 = wbase + m, n1 = wbase + 16 + m;
    bool v0 = n0 < N_NODES, v1 = n1 < N_NODES;
    int c0 = v0 ? n0 : N_NODES - 1;
    int c1 = v1 ? n1 : N_NODES - 1;

    f32x4 acc[2][4];
#pragma unroll
    for (int mf = 0; mf < 2; ++mf)
#pragma unroll
        for (int n2 = 0; n2 < 4; ++n2) acc[mf][n2] = (f32x4){0.f, 0.f, 0.f, 0.f};

    // ---- GEMM1: K = 192 (h 64 | aggr 128); this wave: nf = 4*wv..4*wv+3
#pragma unroll
    for (int ks = 0; ks < 6; ++ks) {
        bf16x8 b0, b1;
        if (ks < 2) {
            b0 = *(const bf16x8*)(h_bf + (size_t)c0 * 64 + ks * 32 + 8 * g);
            b1 = *(const bf16x8*)(h_bf + (size_t)c1 * 64 + ks * 32 + 8 * g);
        } else {
            b0 = ld8_f32_bf(aggr + (size_t)c0 * 128 + (ks - 2) * 32 + 8 * g);
            b1 = ld8_f32_bf(aggr + (size_t)c1 * 128 + (ks - 2) * 32 + 8 * g);
        }
#pragma unroll
        for (int n2 = 0; n2 < 4; ++n2) {
            int nf = 4 * wv + n2;
            bf16x8 a = *(const bf16x8*)(pWn1 + ((ks * 8 + nf) * 64 + lane) * 8);
            acc[0][n2] = __builtin_amdgcn_mfma_f32_16x16x32_bf16(a, b0, acc[0][n2], 0, 0, 0);
            acc[1][n2] = __builtin_amdgcn_mfma_f32_16x16x32_bf16(a, b1, acc[1][n2], 0, 0, 0);
        }
    }

    // ---- epilogue 1: bias + fast softplus -> P columns of this wave ----
#pragma unroll
    for (int n2 = 0; n2 < 4; ++n2) {
        int nf = 4 * wv + n2;
        f32x4 bb = *(const f32x4*)(bn1 + 16 * nf + 4 * g);
#pragma unroll
        for (int mf = 0; mf < 2; ++mf) {
            f32x4 c = acc[mf][n2];
            unsigned int u01 = cvtpk(spf(c[0] + bb[0]), spf(c[1] + bb[1]));
            unsigned int u23 = cvtpk(spf(c[2] + bb[2]), spf(c[3] + bb[3]));
            unsigned int* dst = (unsigned int*)&P[m + 16 * mf][16 * nf + 4 * g];
            dst[0] = u01; dst[1] = u23;
        }
    }
    __syncthreads();

    f32x4 acc2[2][2];
#pragma unroll
    for (int mf = 0; mf < 2; ++mf)
#pragma unroll
        for (int n2 = 0; n2 < 2; ++n2) acc2[mf][n2] = (f32x4){0.f, 0.f, 0.f, 0.f};

    // ---- GEMM2: K = 128, N = 64; this wave: nf = 2*wv..2*wv+1 ----
#pragma unroll
    for (int ks = 0; ks < 4; ++ks) {
        bf16x8 b0 = *(const bf16x8*)&P[m][32 * ks + 8 * g];
        bf16x8 b1 = *(const bf16x8*)&P[m + 16][32 * ks + 8 * g];
#pragma unroll
        for (int n2 = 0; n2 < 2; ++n2) {
            int nf = 2 * wv + n2;
            bf16x8 a = *(const bf16x8*)(pWn2 + ((ks * 4 + nf) * 64 + lane) * 8);
            acc2[0][n2] = __builtin_amdgcn_mfma_f32_16x16x32_bf16(a, b0, acc2[0][n2], 0, 0, 0);
            acc2[1][n2] = __builtin_amdgcn_mfma_f32_16x16x32_bf16(a, b1, acc2[1][n2], 0, 0, 0);
        }
    }

    // ---- epilogue 2: +bn2 +h residual -> t; partial BN stats -----------
#pragma unroll
    for (int n2 = 0; n2 < 2; ++n2) {
        int nf = 2 * wv + n2;
        f32x4 bb = *(const f32x4*)(bn2 + 16 * nf + 4 * g);
        f32x4 s0v = (f32x4){0.f, 0.f, 0.f, 0.f};
        f32x4 s1v = (f32x4){0.f, 0.f, 0.f, 0.f};
#pragma unroll
        for (int mf = 0; mf < 2; ++mf) {
            int cn = mf ? c1 : c0;
            bool vn = mf ? v1 : v0;
            f32x4 hv = *(const f32x4*)(h + (size_t)cn * 64 + 16 * nf + 4 * g);
            f32x4 c = acc2[mf][n2];
            f32x4 tn;
#pragma unroll
            for (int j = 0; j < 4; ++j) tn[j] = c[j] + bb[j] + hv[j];
            if (vn) *(f32x4*)(t + (size_t)cn * 64 + 16 * nf + 4 * g) = tn;
#pragma unroll
            for (int j = 0; j < 4; ++j) {
                float tv = vn ? tn[j] : 0.f;
                s0v[j] += tv;
                s1v[j] += tv * tv;
            }
        }
#pragma unroll
        for (int j = 0; j < 4; ++j) {
#pragma unroll
            for (int k = 1; k <= 8; k <<= 1) {
                s0v[j] += __shfl_xor(s0v[j], k);
                s1v[j] += __shfl_xor(s1v[j], k);
            }
        }
        if (m == 0) {
#pragma unroll
            for (int j = 0; j < 4; ++j) {
                int ch = 16 * nf + 4 * g + j;
                partU[(size_t)blockIdx.x * 128 + ch] = s0v[j];
                partU[(size_t)blockIdx.x * 128 + 64 + ch] = s1v[j];
            }
        }
    }
}

// ---------------- pooling + readout (unchanged) -------------------------
__global__ __launch_bounds__(256) void k_pool(
    const float* __restrict__ h, const int* __restrict__ batch,
    float* __restrict__ pooled, float* __restrict__ cnt) {
    int lane = threadIdx.x & 63;
    int wave = (blockIdx.x * blockDim.x + threadIdx.x) >> 6;
    int nw = (gridDim.x * blockDim.x) >> 6;
    int chunk = (N_NODES + nw - 1) / nw;
    int s = wave * chunk;
    int epos = min(N_NODES, s + chunk);
    if (s >= N_NODES) return;
    int curg = batch[s];
    float acc = 0.f, c = 0.f;
    for (int i = s; i < epos; ++i) {
        int g = batch[i];
        if (g != curg) {
            atomicAdd(&pooled[curg * ND + lane], acc);
            if (lane == 0) atomicAdd(&cnt[curg], c);
            acc = 0.f; c = 0.f; curg = g;
        }
        acc += h[i * ND + lane];
        c += 1.f;
    }
    atomicAdd(&pooled[curg * ND + lane], acc);
    if (lane == 0) atomicAdd(&cnt[curg], c);
}

__global__ __launch_bounds__(256) void k_readout(
    const float* __restrict__ pooled, const float* __restrict__ cnt,
    const float* __restrict__ Wo1, const float* __restrict__ bo1,
    const float* __restrict__ Wo2, const float* __restrict__ bo2,
    float* __restrict__ out) {
    __shared__ float pbuf[WPB][ND];
    int lane = threadIdx.x & 63;
    int wid = threadIdx.x >> 6;
    int g = blockIdx.x * WPB + wid;
    bool valid = g < N_GRAPH;
    int gc = valid ? g : N_GRAPH - 1;
    float c = fmaxf(cnt[gc], 1.f);
    pbuf[wid][lane] = pooled[gc * ND + lane] / c;
    __syncthreads();
    float h0 = bo1[lane], h1 = bo1[64 + lane];
#pragma unroll 8
    for (int k = 0; k < ND; ++k) {
        float pk = pbuf[wid][k];
        h0 += pk * Wo1[k * HD + lane];
        h1 += pk * Wo1[k * HD + 64 + lane];
    }
    float s = sp(h0) * Wo2[lane] + sp(h1) * Wo2[64 + lane];
#pragma unroll
    for (int off = 32; off; off >>= 1) s += __shfl_down(s, off);
    if (valid && lane == 0) out[g] = s + bo2[0];
}

extern "C" void kernel_launch(void* const* d_in, const int* in_sizes, int n_in,
                              void* d_out, int out_size, void* d_ws, size_t ws_size,
                              hipStream_t stream) {
    const float* x       = (const float*)d_in[0];
    const float* ea      = (const float*)d_in[1];
    const int*   ei      = (const int*)d_in[2];
    const int*   batch   = (const int*)d_in[3];
    const float* Wnp     = (const float*)d_in[4];
    const float* bnp     = (const float*)d_in[5];
    const float* g_np    = (const float*)d_in[6];
    const float* be_np   = (const float*)d_in[7];
    const float* Wep     = (const float*)d_in[8];
    const float* bep     = (const float*)d_in[9];
    const float* We1     = (const float*)d_in[10];
    const float* be1     = (const float*)d_in[11];
    const float* We2     = (const float*)d_in[12];
    const float* be2     = (const float*)d_in[13];
    const float* Wn1     = (const float*)d_in[14];
    const float* bn1     = (const float*)d_in[15];
    const float* Wn2     = (const float*)d_in[16];
    const float* bn2     = (const float*)d_in[17];
    const float* g_bn    = (const float*)d_in[18];
    const float* b_bn    = (const float*)d_in[19];
    const float* Wo1     = (const float*)d_in[20];
    const float* bo1     = (const float*)d_in[21];
    const float* Wo2     = (const float*)d_in[22];
    const float* bo2     = (const float*)d_in[23];

    float* ws = (float*)d_ws;
    size_t off = 0;
    float* h      = ws + off; off += (size_t)N_NODES * ND;
    float* t      = ws + off; off += (size_t)N_NODES * ND;
    float* aggr   = ws + off; off += (size_t)N_NODES * HD;
    float* ss     = ws + off; off += 2 * ND;
    float* pooled = ws + off; off += N_GRAPH * ND;
    float* cnt    = ws + off; off += 512;
    unsigned short* h_bf = (unsigned short*)(ws + off); off += (size_t)N_NODES * ND / 2;
    unsigned short* pA1  = (unsigned short*)(ws + off); off += 3 * 5 * 8 * 64 * 8 / 2;
    unsigned short* pA2  = (unsigned short*)(ws + off); off += 3 * 4 * 8 * 64 * 8 / 2;
    unsigned short* pWn1 = (unsigned short*)(ws + off); off += 3 * 6 * 8 * 64 * 8 / 2;
    unsigned short* pWn2 = (unsigned short*)(ws + off); off += 3 * 4 * 4 * 64 * 8 / 2;
    int* sD       = (int*)(ws + off); off += N_EDGES;
    int* sS       = (int*)(ws + off); off += N_EDGES;
    int* sE       = (int*)(ws + off); off += N_EDGES;
    int* hist     = (int*)(ws + off); off += N_NODES;
    int* cursor   = (int*)(ws + off); off += N_NODES;
    int* rowptr   = (int*)(ws + off); off += N_NODES;
    int* chunksum = (int*)(ws + off); off += 64;
    float* partN  = ws + off; off += 512 * 128;
    float* partU  = ws + off; off += (size_t)NBU * 128;
    float* part2  = ws + off; off += 16 * 128;
    unsigned char* bflag = (unsigned char*)(ws + off); off += (N_NODES + 3) / 4 + 16;
    size_t base_bytes = off * sizeof(float);
    unsigned short* e_bf = (unsigned short*)(ws + off);
    bool epre = (ws_size >= base_bytes + (size_t)N_EDGES * 32 * 2);

    float* outp = (float*)d_out;

    const int NCH = (N_NODES + 1023) / 1024;  // 49

    // ---- counting sort of edges by dst -> CSR (once per call) ----
    hipMemsetAsync(hist, 0, N_NODES * sizeof(int), stream);
    k_hist<<<(N_EDGES + 255) / 256, 256, 0, stream>>>(ei, hist);
    k_scan1<<<NCH, 1024, 0, stream>>>(hist, chunksum);
    k_scan2<<<1, 64, 0, stream>>>(chunksum, NCH);
    k_scan3<<<NCH, 1024, 0, stream>>>(hist, chunksum, cursor, rowptr);
    k_scatter<<<(N_EDGES + 255) / 256, 256, 0, stream>>>(ei, cursor, sD, sS, sE);
    k_mark<<<(N_NODES + 255) / 256, 256, 0, stream>>>(rowptr, hist, bflag);
    if (epre)
        k_eproj_sorted<<<(int)(((long)N_EDGES * 32 + 255) / 256), 256, 0, stream>>>(
            ea, sE, Wep, bep, e_bf);

    // ---- pack all weights (3 layers x 4 matrices) in one launch ----
    k_pack_all<<<(3 * 8704 + 255) / 256, 256, 0, stream>>>(
        We1, We2, Wn1, Wn2, pA1, pA2, pWn1, pWn2);

    // ---- node projection + BN (two-stage parallel stats) ----
    k_node_proj<<<512, 256, 0, stream>>>(x, Wnp, bnp, t, partN);
    k_stats_part<<<16, 256, 0, stream>>>(partN, 512, part2);
    k_stats_reduce<<<1, 256, 0, stream>>>(part2, 16, g_np, be_np, ss);
    k_bn_apply<<<(N_NODES * ND / 8 + 255) / 256, 256, 0, stream>>>(t, ss, h, h_bf);

    for (int l = 0; l < 3; ++l) {
        // zero only boundary/deg-0 aggr rows (interior rows are overwritten)
        k_zero_rows<<<(N_NODES * 64 + 255) / 256, 256, 0, stream>>>(bflag, aggr);
        if (epre)
            k_edge_mfma_s<true><<<N_EDGES / 128, 256, 0, stream>>>(
                h_bf, e_bf, ea, sE, Wep, bep, sD, sS, rowptr, hist,
                pA1 + (size_t)l * 40 * 64 * 8, be1 + l * HD,
                pA2 + (size_t)l * 32 * 64 * 8, be2 + l * HD, aggr);
        else
            k_edge_mfma_s<false><<<N_EDGES / 128, 256, 0, stream>>>(
                h_bf, e_bf, ea, sE, Wep, bep, sD, sS, rowptr, hist,
                pA1 + (size_t)l * 40 * 64 * 8, be1 + l * HD,
                pA2 + (size_t)l * 32 * 64 * 8, be2 + l * HD, aggr);

        k_node_mfma<<<NBU, 128, 0, stream>>>(
            h_bf, aggr, h,
            pWn1 + (size_t)l * 48 * 64 * 8, bn1 + l * HD,
            pWn2 + (size_t)l * 16 * 64 * 8, bn2 + l * ND, t, partU);
        k_stats_part<<<16, 256, 0, stream>>>(partU, NBU, part2);
        k_stats_reduce<<<1, 256, 0, stream>>>(part2, 16, g_bn + l * ND, b_bn + l * ND, ss);
        k_bn_apply<<<(N_NODES * ND / 8 + 255) / 256, 256, 0, stream>>>(t, ss, h, h_bf);
    }

    hipMemsetAsync(pooled, 0, (size_t)(N_GRAPH * ND + 512) * sizeof(float), stream);
    k_pool<<<512, 256, 0, stream>>>(h, batch, pooled, cnt);
    k_readout<<<(N_GRAPH + WPB - 1) / WPB, 256, 0, stream>>>(
        pooled, cnt, Wo1, bo1, Wo2, bo2, outp);
}

// Round 28
// 811.468 us; speedup vs baseline: 1.4566x; 1.0829x over previous
//
#include <hip/hip_runtime.h>
#include <hip/hip_bf16.h>

#define N_NODES 50000
#define N_EDGES 800000
#define N_GRAPH 500
#define ND 64
#define ED 32
#define HD 128
#define WPB 4   // waves per block (256 threads)
#define NBB ((N_NODES + 63) / 64)   // 782 node blocks (64 nodes each)
#define NBU2 (2 * NBB)              // 1564 partial-stat rows

typedef __attribute__((ext_vector_type(8))) short bf16x8;
typedef __attribute__((ext_vector_type(4))) float f32x4;
typedef __attribute__((ext_vector_type(2))) float f32x2;
typedef __attribute__((ext_vector_type(4))) unsigned int u32x4;

__device__ __forceinline__ float sp(float x) {
    return fmaxf(x, 0.f) + log1pf(expf(-fabsf(x)));
}

// fast softplus for the bf16 path (v_exp_f32/v_log_f32 based)
__device__ __forceinline__ float spf(float x) {
    return fmaxf(x, 0.f) + __logf(1.f + __expf(-fabsf(x)));
}

__device__ __forceinline__ unsigned short f2bf(float v) {
    __hip_bfloat16 b = __float2bfloat16(v);
    return *(unsigned short*)&b;
}

// single-instruction pack: lo=bf16(a), hi=bf16(b)  (v_cvt_pk_bf16_f32, RNE)
__device__ __forceinline__ unsigned int cvtpk(float a, float b) {
    unsigned int r;
    asm("v_cvt_pk_bf16_f32 %0, %1, %2" : "=v"(r) : "v"(a), "v"(b));
    return r;
}

__device__ __forceinline__ float lo_bf(unsigned int u) { return __uint_as_float(u << 16); }
__device__ __forceinline__ float hi_bf(unsigned int u) { return __uint_as_float(u & 0xffff0000u); }

// load 8 fp32 and round to bf16x8 via 4 cvt_pk
__device__ __forceinline__ bf16x8 ld8_f32_bf(const float* p) {
    f32x4 v0 = *(const f32x4*)p;
    f32x4 v1 = *(const f32x4*)(p + 4);
    u32x4 u;
    u[0] = cvtpk(v0[0], v0[1]);
    u[1] = cvtpk(v0[2], v0[3]);
    u[2] = cvtpk(v1[0], v1[1]);
    u[3] = cvtpk(v1[2], v1[3]);
    return *(bf16x8*)&u;
}

// ---------------- node projection: partial BN stats per block -----------
__global__ __launch_bounds__(256) void k_node_proj(
    const float* __restrict__ x, const float* __restrict__ Wnp,
    const float* __restrict__ bnp, float* __restrict__ t,
    float* __restrict__ partN) {
    __shared__ float red0[4][64], red1[4][64];
    int lane = threadIdx.x & 63;
    int wid = threadIdx.x >> 6;
    int wave = (blockIdx.x * blockDim.x + threadIdx.x) >> 6;
    int nw = (gridDim.x * blockDim.x) >> 6;
    float w[13];
#pragma unroll
    for (int k = 0; k < 13; ++k) w[k] = Wnp[k * ND + lane];
    float bb = bnp[lane];
    float s0 = 0.f, s1 = 0.f;
    for (int i = wave; i < N_NODES; i += nw) {
        float acc = bb;
#pragma unroll
        for (int k = 0; k < 13; ++k) acc += x[i * 13 + k] * w[k];
        float v = sp(acc);
        t[i * ND + lane] = v;
        s0 += v; s1 += v * v;
    }
    red0[wid][lane] = s0;
    red1[wid][lane] = s1;
    __syncthreads();
    int tid = threadIdx.x;
    if (tid < 64)
        partN[blockIdx.x * 128 + tid] =
            red0[0][tid] + red0[1][tid] + red0[2][tid] + red0[3][tid];
    else if (tid < 128) {
        int c = tid - 64;
        partN[blockIdx.x * 128 + tid] =
            red1[0][c] + red1[1][c] + red1[2][c] + red1[3][c];
    }
}

// ---- stage A: 16 blocks reduce R partial rows -> part2[16][128] --------
__global__ __launch_bounds__(256) void k_stats_part(
    const float* __restrict__ part, int R, float* __restrict__ part2) {
    __shared__ float r0[4][64], r1[4][64];
    int q = threadIdx.x >> 6, c = threadIdx.x & 63;
    float S0 = 0.f, S1 = 0.f;
    for (int r = blockIdx.x * 4 + q; r < R; r += 64) {
        S0 += part[(size_t)r * 128 + c];
        S1 += part[(size_t)r * 128 + 64 + c];
    }
    r0[q][c] = S0; r1[q][c] = S1;
    __syncthreads();
    if (threadIdx.x < 64)
        part2[blockIdx.x * 128 + c] = r0[0][c] + r0[1][c] + r0[2][c] + r0[3][c];
    else if (threadIdx.x < 128) {
        int cc = threadIdx.x - 64;
        part2[blockIdx.x * 128 + 64 + cc] =
            r1[0][cc] + r1[1][cc] + r1[2][cc] + r1[3][cc];
    }
}

// ---- stage B: sum R partial rows (small R), emit scale/shift -----------
__global__ void k_stats_reduce(const float* __restrict__ part, int R,
                               const float* __restrict__ g,
                               const float* __restrict__ b,
                               float* __restrict__ ss) {
    __shared__ float r0[4][64], r1[4][64];
    int q = threadIdx.x >> 6, c = threadIdx.x & 63;
    float S0 = 0.f, S1 = 0.f;
    for (int r = q; r < R; r += 4) {
        S0 += part[(size_t)r * 128 + c];
        S1 += part[(size_t)r * 128 + 64 + c];
    }
    r0[q][c] = S0; r1[q][c] = S1;
    __syncthreads();
    if (threadIdx.x < 64) {
        float s0 = r0[0][c] + r0[1][c] + r0[2][c] + r0[3][c];
        float s1 = r1[0][c] + r1[1][c] + r1[2][c] + r1[3][c];
        float inv_n = 1.f / (float)N_NODES;
        float mu = s0 * inv_n;
        float var = s1 * inv_n - mu * mu;
        float rs = rsqrtf(var + 1e-5f);
        float sc = rs * g[c];
        ss[c] = sc;
        ss[64 + c] = b[c] - mu * sc;
    }
}

// vectorized BN apply: 8 elements/thread (channels contiguous, 8 | 64)
__global__ __launch_bounds__(256) void k_bn_apply(
    const float* __restrict__ t, const float* __restrict__ ss,
    float* __restrict__ h, unsigned short* __restrict__ hb) {
    int idx = (blockIdx.x * 256 + threadIdx.x) * 8;
    if (idx >= N_NODES * ND) return;
    int c = idx & (ND - 1);
    f32x4 sc0 = *(const f32x4*)(ss + c);
    f32x4 sc1 = *(const f32x4*)(ss + c + 4);
    f32x4 sh0 = *(const f32x4*)(ss + ND + c);
    f32x4 sh1 = *(const f32x4*)(ss + ND + c + 4);
    f32x4 v0 = *(const f32x4*)(t + idx);
    f32x4 v1 = *(const f32x4*)(t + idx + 4);
    f32x4 r0, r1;
#pragma unroll
    for (int j = 0; j < 4; ++j) { r0[j] = v0[j] * sc0[j] + sh0[j]; r1[j] = v1[j] * sc1[j] + sh1[j]; }
    *(f32x4*)(h + idx) = r0;
    *(f32x4*)(h + idx + 4) = r1;
    u32x4 u;
    u[0] = cvtpk(r0[0], r0[1]);
    u[1] = cvtpk(r0[2], r0[3]);
    u[2] = cvtpk(r1[0], r1[1]);
    u[3] = cvtpk(r1[2], r1[3]);
    *(u32x4*)(hb + idx) = u;
}

// ---------------- counting sort of edges by dst -------------------------
__global__ __launch_bounds__(256) void k_hist(const int* __restrict__ ei,
                                              int* __restrict__ hist) {
    int e = blockIdx.x * 256 + threadIdx.x;
    if (e < N_EDGES) atomicAdd(&hist[ei[N_EDGES + e]], 1);
}

__global__ __launch_bounds__(1024) void k_scan1(const int* __restrict__ hist,
                                                int* __restrict__ chunksum) {
    __shared__ int s[1024];
    int t = threadIdx.x;
    int i = blockIdx.x * 1024 + t;
    s[t] = (i < N_NODES) ? hist[i] : 0;
    __syncthreads();
    for (int off = 512; off; off >>= 1) {
        if (t < off) s[t] += s[t + off];
        __syncthreads();
    }
    if (t == 0) chunksum[blockIdx.x] = s[0];
}

__global__ void k_scan2(int* __restrict__ chunksum, int n) {
    if (threadIdx.x == 0) {
        int acc = 0;
        for (int i = 0; i < n; ++i) { int v = chunksum[i]; chunksum[i] = acc; acc += v; }
    }
}

__global__ __launch_bounds__(1024) void k_scan3(const int* __restrict__ hist,
                                                const int* __restrict__ chunksum,
                                                int* __restrict__ cursor,
                                                int* __restrict__ rowptr) {
    __shared__ int s[1024];
    int t = threadIdx.x;
    int i = blockIdx.x * 1024 + t;
    int v = (i < N_NODES) ? hist[i] : 0;
    s[t] = v;
    __syncthreads();
    for (int off = 1; off < 1024; off <<= 1) {
        int u = (t >= off) ? s[t - off] : 0;
        __syncthreads();
        s[t] += u;
        __syncthreads();
    }
    if (i < N_NODES) {
        int ex = chunksum[blockIdx.x] + s[t] - v;  // exclusive
        cursor[i] = ex;
        rowptr[i] = ex;
    }
}

__global__ __launch_bounds__(256) void k_scatter(const int* __restrict__ ei,
                                                 int* __restrict__ cursor,
                                                 int* __restrict__ sD,
                                                 int* __restrict__ sS,
                                                 int* __restrict__ sE) {
    int e = blockIdx.x * 256 + threadIdx.x;
    if (e >= N_EDGES) return;
    int d = ei[N_EDGES + e];
    int pos = atomicAdd(&cursor[d], 1);
    sD[pos] = d;
    sS[pos] = ei[e];
    sE[pos] = e;
}

// mark nodes needing zero-init: run crosses a 128-edge tile boundary, or deg==0
__global__ __launch_bounds__(256) void k_mark(
    const int* __restrict__ rowptr, const int* __restrict__ hist,
    unsigned char* __restrict__ bflag) {
    int i = blockIdx.x * 256 + threadIdx.x;
    if (i >= N_NODES) return;
    int s = rowptr[i], d = hist[i];
    bflag[i] = (d == 0) || ((s >> 7) != ((s + d - 1) >> 7));
}

// zero only flagged aggr rows (layer-invariant flag set)
__global__ __launch_bounds__(256) void k_zero_rows(
    const unsigned char* __restrict__ bflag, float* __restrict__ aggr) {
    int idx = blockIdx.x * 256 + threadIdx.x;   // node*64 + pair
    if (idx >= N_NODES * 64) return;
    int node = idx >> 6;
    if (!bflag[node]) return;
    f32x2 z = (f32x2){0.f, 0.f};
    *(f32x2*)(aggr + (size_t)node * HD + 2 * (idx & 63)) = z;
}

// edge projection into sorted order (layer-invariant, once per call)
__global__ __launch_bounds__(256) void k_eproj_sorted(
    const float* __restrict__ ea, const int* __restrict__ sE,
    const float* __restrict__ Wep, const float* __restrict__ bep,
    unsigned short* __restrict__ e_bf) {
    long idx = (long)blockIdx.x * blockDim.x + threadIdx.x;
    long tot = (long)N_EDGES * 32;
    if (idx >= tot) return;
    int p = (int)(idx >> 5), col = (int)(idx & 31);
    int e = sE[p];
    float v = spf(ea[2 * e] * Wep[col] + ea[2 * e + 1] * Wep[32 + col] + bep[col]);
    e_bf[idx] = f2bf(v);
}

// ---- fused weight pack: all 3 layers x {We1,We2,Wn1,Wn2} in ONE launch --
__global__ __launch_bounds__(256) void k_pack_all(
    const float* __restrict__ We1, const float* __restrict__ We2,
    const float* __restrict__ Wn1, const float* __restrict__ Wn2,
    unsigned short* __restrict__ pA1, unsigned short* __restrict__ pA2,
    unsigned short* __restrict__ pWn1, unsigned short* __restrict__ pWn2) {
    int tid = blockIdx.x * 256 + threadIdx.x;
    const int PER_L = (40 + 32 + 48 + 16) * 64;  // 8704
    if (tid >= 3 * PER_L) return;
    int layer = tid / PER_L;
    int r = tid % PER_L;
    const float* W;
    unsigned short* out;
    int ncols, lt;
    if (r < 40 * 64) {
        lt = r; W = We1 + (size_t)layer * 160 * 128; out = pA1 + (size_t)layer * 40 * 64 * 8;
        ncols = 128;
    } else if (r < 72 * 64) {
        lt = r - 40 * 64; W = We2 + (size_t)layer * 128 * 128; out = pA2 + (size_t)layer * 32 * 64 * 8;
        ncols = 128;
    } else if (r < 120 * 64) {
        lt = r - 72 * 64; W = Wn1 + (size_t)layer * 192 * 128; out = pWn1 + (size_t)layer * 48 * 64 * 8;
        ncols = 128;
    } else {
        lt = r - 120 * 64; W = Wn2 + (size_t)layer * 128 * 64; out = pWn2 + (size_t)layer * 16 * 64 * 8;
        ncols = 64;
    }
    int nfrag = ncols >> 4;
    int l = lt & 63; int fr = lt >> 6; int nf = fr % nfrag; int ks = fr / nfrag;
    int n = 16 * nf + (l & 15);
    int k0 = 32 * ks + 8 * (l >> 4);
#pragma unroll
    for (int rr = 0; rr < 8; ++rr)
        out[lt * 8 + rr] = f2bf(W[(k0 + rr) * ncols + n]);
}

// ---------------- MFMA edge conv on dst-sorted edges --------------------
// Round-23 register-bounded form + hoisted GEMM1 B-fragments (loaded once,
// used by all 4 nf-quarters) + cvt_pk packing in both epilogues.
template <bool EPRE>
__global__ __launch_bounds__(256, 4) void k_edge_mfma_s(
    const unsigned short* __restrict__ h_bf, const unsigned short* __restrict__ e_bf,
    const float* __restrict__ ea, const int* __restrict__ sE,
    const float* __restrict__ Wep, const float* __restrict__ bep,
    const int* __restrict__ sD, const int* __restrict__ sS,
    const int* __restrict__ rowptr, const int* __restrict__ hist,
    const unsigned short* __restrict__ pA1, const float* __restrict__ be1,
    const unsigned short* __restrict__ pA2, const float* __restrict__ be2,
    float* __restrict__ aggr) {
    __shared__ unsigned short P[WPB][32][136];   // per-wave P; reused as 128-row stage
    __shared__ int dstB[128];
    __shared__ unsigned short eL[EPRE ? 64 : 128 * 32];

    int lane = threadIdx.x & 63;
    int w = threadIdx.x >> 6;
    int m = lane & 15, g = lane >> 4;
    int tile0 = blockIdx.x * 128;
    int wbase = tile0 + 32 * w;

    int eD0 = sD[wbase + m];
    int eD1 = sD[wbase + 16 + m];
    int eS0 = sS[wbase + m];
    int eS1 = sS[wbase + 16 + m];

    if constexpr (!EPRE) {
        int col = threadIdx.x & 31;
        int r0 = threadIdx.x >> 5;
        float w0 = Wep[col], w1 = Wep[32 + col], bb = bep[col];
#pragma unroll
        for (int i = 0; i < 16; ++i) {
            int em = r0 + 8 * i;
            int e = sE[tile0 + em];
            eL[em * 32 + col] = f2bf(spf(ea[2 * e] * w0 + ea[2 * e + 1] * w1 + bb));
        }
        __syncthreads();
    }

    // ---- hoist GEMM1 B-fragments once (z-rows: dst 64 | src 64 | e 32) --
    bf16x8 B0[5], B1[5];
    B0[0] = *(const bf16x8*)(h_bf + (size_t)eD0 * 64 + 8 * g);
    B1[0] = *(const bf16x8*)(h_bf + (size_t)eD1 * 64 + 8 * g);
    B0[1] = *(const bf16x8*)(h_bf + (size_t)eD0 * 64 + 32 + 8 * g);
    B1[1] = *(const bf16x8*)(h_bf + (size_t)eD1 * 64 + 32 + 8 * g);
    B0[2] = *(const bf16x8*)(h_bf + (size_t)eS0 * 64 + 8 * g);
    B1[2] = *(const bf16x8*)(h_bf + (size_t)eS1 * 64 + 8 * g);
    B0[3] = *(const bf16x8*)(h_bf + (size_t)eS0 * 64 + 32 + 8 * g);
    B1[3] = *(const bf16x8*)(h_bf + (size_t)eS1 * 64 + 32 + 8 * g);
    if constexpr (EPRE) {
        B0[4] = *(const bf16x8*)(e_bf + (size_t)(wbase + m) * 32 + 8 * g);
        B1[4] = *(const bf16x8*)(e_bf + (size_t)(wbase + 16 + m) * 32 + 8 * g);
    } else {
        B0[4] = *(const bf16x8*)&eL[(32 * w + m) * 32 + 8 * g];
        B1[4] = *(const bf16x8*)&eL[(32 * w + 16 + m) * 32 + 8 * g];
    }

    // ---- GEMM1 (K=160) in four nf-quarters: acc = 16 AGPR per region ----
#pragma unroll
    for (int qt = 0; qt < 4; ++qt) {
        f32x4 acc[2][2];
#pragma unroll
        for (int mf = 0; mf < 2; ++mf)
#pragma unroll
            for (int n2 = 0; n2 < 2; ++n2) acc[mf][n2] = (f32x4){0.f, 0.f, 0.f, 0.f};
#pragma unroll
        for (int ks = 0; ks < 5; ++ks) {
#pragma unroll
            for (int n2 = 0; n2 < 2; ++n2) {
                int nf = qt * 2 + n2;
                bf16x8 a = *(const bf16x8*)(pA1 + ((ks * 8 + nf) * 64 + lane) * 8);
                acc[0][n2] = __builtin_amdgcn_mfma_f32_16x16x32_bf16(a, B0[ks], acc[0][n2], 0, 0, 0);
                acc[1][n2] = __builtin_amdgcn_mfma_f32_16x16x32_bf16(a, B1[ks], acc[1][n2], 0, 0, 0);
            }
        }
        // epilogue 1 (this quarter): bias + fast softplus -> P (bf16) in LDS
#pragma unroll
        for (int n2 = 0; n2 < 2; ++n2) {
            int nf = qt * 2 + n2;
            f32x4 bb = *(const f32x4*)(be1 + 16 * nf + 4 * g);
#pragma unroll
            for (int mf = 0; mf < 2; ++mf) {
                f32x4 c = acc[mf][n2];
                unsigned int u01 = cvtpk(spf(c[0] + bb[0]), spf(c[1] + bb[1]));
                unsigned int u23 = cvtpk(spf(c[2] + bb[2]), spf(c[3] + bb[3]));
                unsigned int* dst = (unsigned int*)&P[w][m + 16 * mf][16 * nf + 4 * g];
                dst[0] = u01; dst[1] = u23;
            }
        }
    }

    // ---- GEMM2 (K=128) per m-fragment, two nf-halves; 8-reg deferral ----
    unsigned short (*Pf)[136] = (unsigned short(*)[136]) & P[0][0][0];
#pragma unroll
    for (int mf = 0; mf < 2; ++mf) {
        unsigned int defer[8];
#pragma unroll
        for (int half = 0; half < 2; ++half) {
            f32x4 acc2[4];
#pragma unroll
            for (int n2 = 0; n2 < 4; ++n2) acc2[n2] = (f32x4){0.f, 0.f, 0.f, 0.f};
#pragma unroll
            for (int ks = 0; ks < 4; ++ks) {
                bf16x8 b = *(const bf16x8*)&P[w][m + 16 * mf][32 * ks + 8 * g];
#pragma unroll
                for (int n2 = 0; n2 < 4; ++n2) {
                    int nf = half * 4 + n2;
                    bf16x8 a = *(const bf16x8*)(pA2 + ((ks * 8 + nf) * 64 + lane) * 8);
                    acc2[n2] = __builtin_amdgcn_mfma_f32_16x16x32_bf16(a, b, acc2[n2], 0, 0, 0);
                }
            }
            if (half == 0) {
#pragma unroll
                for (int n2 = 0; n2 < 4; ++n2) {
                    int nf = n2;
                    f32x4 bb = *(const f32x4*)(be2 + 16 * nf + 4 * g);
                    f32x4 c = acc2[n2];
                    defer[2 * n2] = cvtpk(spf(c[0] + bb[0]), spf(c[1] + bb[1]));
                    defer[2 * n2 + 1] = cvtpk(spf(c[2] + bb[2]), spf(c[3] + bb[3]));
                }
            } else {
#pragma unroll
                for (int n2 = 0; n2 < 4; ++n2) {
                    int nf = 4 + n2;
                    f32x4 bb = *(const f32x4*)(be2 + 16 * nf + 4 * g);
                    f32x4 c = acc2[n2];
                    unsigned int* dst =
                        (unsigned int*)&Pf[32 * w + 16 * mf + m][16 * nf + 4 * g];
                    dst[0] = cvtpk(spf(c[0] + bb[0]), spf(c[1] + bb[1]));
                    dst[1] = cvtpk(spf(c[2] + bb[2]), spf(c[3] + bb[3]));
                }
#pragma unroll
                for (int n2 = 0; n2 < 4; ++n2) {
                    unsigned int* dst =
                        (unsigned int*)&Pf[32 * w + 16 * mf + m][16 * n2 + 4 * g];
                    dst[0] = defer[2 * n2];
                    dst[1] = defer[2 * n2 + 1];
                }
            }
        }
    }
    if (g == 0) {
        dstB[32 * w + m] = eD0;
        dstB[32 * w + 16 + m] = eD1;
    }
    __syncthreads();

    // ---- block-wide run-length segmented reduction ----
    int rbeg = 32 * w, rend = rbeg + 32;
    int r = rbeg;
    if (w) {  // skip rows continuing a run that started in a lower wave
        while (r < rend && dstB[r] == dstB[r - 1]) ++r;
    }
    while (r < rend) {
        int d = dstB[r];
        float a0 = 0.f, a1 = 0.f;
        int rr = r;
        do {
            unsigned int u = *(const unsigned int*)&Pf[rr][2 * lane];
            a0 += lo_bf(u);
            a1 += hi_bf(u);
            ++rr;
        } while (rr < 128 && dstB[rr] == d);
        int s0 = rowptr[d];
        bool interior = (s0 >= tile0) && (s0 + hist[d] <= tile0 + 128);
        float* base = aggr + (size_t)d * HD + 2 * lane;
        if (interior) {
            base[0] = a0;
            base[1] = a1;
        } else {
            atomicAdd(base, a0);
            atomicAdd(base + 1, a1);
        }
        r = rr;
    }
}

// ---------------- MFMA node update: 64 nodes/block (2 groups x 2 waves) --
__global__ __launch_bounds__(256, 2) void k_node_mfma(
    const unsigned short* __restrict__ h_bf, const float* __restrict__ aggr,
    const float* __restrict__ h,
    const unsigned short* __restrict__ pWn1, const float* __restrict__ bn1,
    const unsigned short* __restrict__ pWn2, const float* __restrict__ bn2,
    float* __restrict__ t, float* __restrict__ partU) {
    __shared__ unsigned short P[2][32][136];

    int lane = threadIdx.x & 63;
    int wid = threadIdx.x >> 6;
    int grp = wid >> 1;          // 0 or 1 (32-node group)
    int wv = wid & 1;            // 0 or 1 (nf split within group)
    int m = lane & 15, g = lane >> 4;
    int wbase = blockIdx.x * 64 + grp * 32;
    int n0 = wbase + m, n1 = wbase + 16 + m;
    bool v0 = n0 < N_NODES, v1 = n1 < N_NODES;
    int c0 = v0 ? n0 : N_NODES - 1;
    int c1 = v1 ? n1 : N_NODES - 1;

    f32x4 acc[2][4];
#pragma unroll
    for (int mf = 0; mf < 2; ++mf)
#pragma unroll
        for (int n2 = 0; n2 < 4; ++n2) acc[mf][n2] = (f32x4){0.f, 0.f, 0.f, 0.f};

    // ---- GEMM1: K = 192 (h 64 | aggr 128); this wave: nf = 4*wv..4*wv+3
#pragma unroll
    for (int ks = 0; ks < 6; ++ks) {
        bf16x8 b0, b1;
        if (ks < 2) {
            b0 = *(const bf16x8*)(h_bf + (size_t)c0 * 64 + ks * 32 + 8 * g);
            b1 = *(const bf16x8*)(h_bf + (size_t)c1 * 64 + ks * 32 + 8 * g);
        } else {
            b0 = ld8_f32_bf(aggr + (size_t)c0 * 128 + (ks - 2) * 32 + 8 * g);
            b1 = ld8_f32_bf(aggr + (size_t)c1 * 128 + (ks - 2) * 32 + 8 * g);
        }
#pragma unroll
        for (int n2 = 0; n2 < 4; ++n2) {
            int nf = 4 * wv + n2;
            bf16x8 a = *(const bf16x8*)(pWn1 + ((ks * 8 + nf) * 64 + lane) * 8);
            acc[0][n2] = __builtin_amdgcn_mfma_f32_16x16x32_bf16(a, b0, acc[0][n2], 0, 0, 0);
            acc[1][n2] = __builtin_amdgcn_mfma_f32_16x16x32_bf16(a, b1, acc[1][n2], 0, 0, 0);
        }
    }

    // ---- epilogue 1: bias + fast softplus -> P columns of this wave ----
#pragma unroll
    for (int n2 = 0; n2 < 4; ++n2) {
        int nf = 4 * wv + n2;
        f32x4 bb = *(const f32x4*)(bn1 + 16 * nf + 4 * g);
#pragma unroll
        for (int mf = 0; mf < 2; ++mf) {
            f32x4 c = acc[mf][n2];
            unsigned int u01 = cvtpk(spf(c[0] + bb[0]), spf(c[1] + bb[1]));
            unsigned int u23 = cvtpk(spf(c[2] + bb[2]), spf(c[3] + bb[3]));
            unsigned int* dst = (unsigned int*)&P[grp][m + 16 * mf][16 * nf + 4 * g];
            dst[0] = u01; dst[1] = u23;
        }
    }
    __syncthreads();

    f32x4 acc2[2][2];
#pragma unroll
    for (int mf = 0; mf < 2; ++mf)
#pragma unroll
        for (int n2 = 0; n2 < 2; ++n2) acc2[mf][n2] = (f32x4){0.f, 0.f, 0.f, 0.f};

    // ---- GEMM2: K = 128, N = 64; this wave: nf = 2*wv..2*wv+1 ----
#pragma unroll
    for (int ks = 0; ks < 4; ++ks) {
        bf16x8 b0 = *(const bf16x8*)&P[grp][m][32 * ks + 8 * g];
        bf16x8 b1 = *(const bf16x8*)&P[grp][m + 16][32 * ks + 8 * g];
#pragma unroll
        for (int n2 = 0; n2 < 2; ++n2) {
            int nf = 2 * wv + n2;
            bf16x8 a = *(const bf16x8*)(pWn2 + ((ks * 4 + nf) * 64 + lane) * 8);
            acc2[0][n2] = __builtin_amdgcn_mfma_f32_16x16x32_bf16(a, b0, acc2[0][n2], 0, 0, 0);
            acc2[1][n2] = __builtin_amdgcn_mfma_f32_16x16x32_bf16(a, b1, acc2[1][n2], 0, 0, 0);
        }
    }

    // ---- epilogue 2: +bn2 +h residual -> t; partial BN stats -----------
#pragma unroll
    for (int n2 = 0; n2 < 2; ++n2) {
        int nf = 2 * wv + n2;
        f32x4 bb = *(const f32x4*)(bn2 + 16 * nf + 4 * g);
        f32x4 s0v = (f32x4){0.f, 0.f, 0.f, 0.f};
        f32x4 s1v = (f32x4){0.f, 0.f, 0.f, 0.f};
#pragma unroll
        for (int mf = 0; mf < 2; ++mf) {
            int cn = mf ? c1 : c0;
            bool vn = mf ? v1 : v0;
            f32x4 hv = *(const f32x4*)(h + (size_t)cn * 64 + 16 * nf + 4 * g);
            f32x4 c = acc2[mf][n2];
            f32x4 tn;
#pragma unroll
            for (int j = 0; j < 4; ++j) tn[j] = c[j] + bb[j] + hv[j];
            if (vn) *(f32x4*)(t + (size_t)cn * 64 + 16 * nf + 4 * g) = tn;
#pragma unroll
            for (int j = 0; j < 4; ++j) {
                float tv = vn ? tn[j] : 0.f;
                s0v[j] += tv;
                s1v[j] += tv * tv;
            }
        }
#pragma unroll
        for (int j = 0; j < 4; ++j) {
#pragma unroll
            for (int k = 1; k <= 8; k <<= 1) {
                s0v[j] += __shfl_xor(s0v[j], k);
                s1v[j] += __shfl_xor(s1v[j], k);
            }
        }
        if (m == 0) {
#pragma unroll
            for (int j = 0; j < 4; ++j) {
                int ch = 16 * nf + 4 * g + j;
                size_t row = (size_t)blockIdx.x * 2 + grp;
                partU[row * 128 + ch] = s0v[j];
                partU[row * 128 + 64 + ch] = s1v[j];
            }
        }
    }
}

// ---------------- pooling + readout (unchanged) -------------------------
__global__ __launch_bounds__(256) void k_pool(
    const float* __restrict__ h, const int* __restrict__ batch,
    float* __restrict__ pooled, float* __restrict__ cnt) {
    int lane = threadIdx.x & 63;
    int wave = (blockIdx.x * blockDim.x + threadIdx.x) >> 6;
    int nw = (gridDim.x * blockDim.x) >> 6;
    int chunk = (N_NODES + nw - 1) / nw;
    int s = wave * chunk;
    int epos = min(N_NODES, s + chunk);
    if (s >= N_NODES) return;
    int curg = batch[s];
    float acc = 0.f, c = 0.f;
    for (int i = s; i < epos; ++i) {
        int g = batch[i];
        if (g != curg) {
            atomicAdd(&pooled[curg * ND + lane], acc);
            if (lane == 0) atomicAdd(&cnt[curg], c);
            acc = 0.f; c = 0.f; curg = g;
        }
        acc += h[i * ND + lane];
        c += 1.f;
    }
    atomicAdd(&pooled[curg * ND + lane], acc);
    if (lane == 0) atomicAdd(&cnt[curg], c);
}

__global__ __launch_bounds__(256) void k_readout(
    const float* __restrict__ pooled, const float* __restrict__ cnt,
    const float* __restrict__ Wo1, const float* __restrict__ bo1,
    const float* __restrict__ Wo2, const float* __restrict__ bo2,
    float* __restrict__ out) {
    __shared__ float pbuf[WPB][ND];
    int lane = threadIdx.x & 63;
    int wid = threadIdx.x >> 6;
    int g = blockIdx.x * WPB + wid;
    bool valid = g < N_GRAPH;
    int gc = valid ? g : N_GRAPH - 1;
    float c = fmaxf(cnt[gc], 1.f);
    pbuf[wid][lane] = pooled[gc * ND + lane] / c;
    __syncthreads();
    float h0 = bo1[lane], h1 = bo1[64 + lane];
#pragma unroll 8
    for (int k = 0; k < ND; ++k) {
        float pk = pbuf[wid][k];
        h0 += pk * Wo1[k * HD + lane];
        h1 += pk * Wo1[k * HD + 64 + lane];
    }
    float s = sp(h0) * Wo2[lane] + sp(h1) * Wo2[64 + lane];
#pragma unroll
    for (int off = 32; off; off >>= 1) s += __shfl_down(s, off);
    if (valid && lane == 0) out[g] = s + bo2[0];
}

extern "C" void kernel_launch(void* const* d_in, const int* in_sizes, int n_in,
                              void* d_out, int out_size, void* d_ws, size_t ws_size,
                              hipStream_t stream) {
    const float* x       = (const float*)d_in[0];
    const float* ea      = (const float*)d_in[1];
    const int*   ei      = (const int*)d_in[2];
    const int*   batch   = (const int*)d_in[3];
    const float* Wnp     = (const float*)d_in[4];
    const float* bnp     = (const float*)d_in[5];
    const float* g_np    = (const float*)d_in[6];
    const float* be_np   = (const float*)d_in[7];
    const float* Wep     = (const float*)d_in[8];
    const float* bep     = (const float*)d_in[9];
    const float* We1     = (const float*)d_in[10];
    const float* be1     = (const float*)d_in[11];
    const float* We2     = (const float*)d_in[12];
    const float* be2     = (const float*)d_in[13];
    const float* Wn1     = (const float*)d_in[14];
    const float* bn1     = (const float*)d_in[15];
    const float* Wn2     = (const float*)d_in[16];
    const float* bn2     = (const float*)d_in[17];
    const float* g_bn    = (const float*)d_in[18];
    const float* b_bn    = (const float*)d_in[19];
    const float* Wo1     = (const float*)d_in[20];
    const float* bo1     = (const float*)d_in[21];
    const float* Wo2     = (const float*)d_in[22];
    const float* bo2     = (const float*)d_in[23];

    float* ws = (float*)d_ws;
    size_t off = 0;
    float* h      = ws + off; off += (size_t)N_NODES * ND;
    float* t      = ws + off; off += (size_t)N_NODES * ND;
    float* aggr   = ws + off; off += (size_t)N_NODES * HD;
    float* ss     = ws + off; off += 2 * ND;
    float* pooled = ws + off; off += N_GRAPH * ND;
    float* cnt    = ws + off; off += 512;
    unsigned short* h_bf = (unsigned short*)(ws + off); off += (size_t)N_NODES * ND / 2;
    unsigned short* pA1  = (unsigned short*)(ws + off); off += 3 * 5 * 8 * 64 * 8 / 2;
    unsigned short* pA2  = (unsigned short*)(ws + off); off += 3 * 4 * 8 * 64 * 8 / 2;
    unsigned short* pWn1 = (unsigned short*)(ws + off); off += 3 * 6 * 8 * 64 * 8 / 2;
    unsigned short* pWn2 = (unsigned short*)(ws + off); off += 3 * 4 * 4 * 64 * 8 / 2;
    int* sD       = (int*)(ws + off); off += N_EDGES;
    int* sS       = (int*)(ws + off); off += N_EDGES;
    int* sE       = (int*)(ws + off); off += N_EDGES;
    int* hist     = (int*)(ws + off); off += N_NODES;
    int* cursor   = (int*)(ws + off); off += N_NODES;
    int* rowptr   = (int*)(ws + off); off += N_NODES;
    int* chunksum = (int*)(ws + off); off += 64;
    float* partN  = ws + off; off += 512 * 128;
    float* partU  = ws + off; off += (size_t)NBU2 * 128;
    float* part2  = ws + off; off += 16 * 128;
    unsigned char* bflag = (unsigned char*)(ws + off); off += (N_NODES + 3) / 4 + 16;
    size_t base_bytes = off * sizeof(float);
    unsigned short* e_bf = (unsigned short*)(ws + off);
    bool epre = (ws_size >= base_bytes + (size_t)N_EDGES * 32 * 2);

    float* outp = (float*)d_out;

    const int NCH = (N_NODES + 1023) / 1024;  // 49

    // ---- counting sort of edges by dst -> CSR (once per call) ----
    hipMemsetAsync(hist, 0, N_NODES * sizeof(int), stream);
    k_hist<<<(N_EDGES + 255) / 256, 256, 0, stream>>>(ei, hist);
    k_scan1<<<NCH, 1024, 0, stream>>>(hist, chunksum);
    k_scan2<<<1, 64, 0, stream>>>(chunksum, NCH);
    k_scan3<<<NCH, 1024, 0, stream>>>(hist, chunksum, cursor, rowptr);
    k_scatter<<<(N_EDGES + 255) / 256, 256, 0, stream>>>(ei, cursor, sD, sS, sE);
    k_mark<<<(N_NODES + 255) / 256, 256, 0, stream>>>(rowptr, hist, bflag);
    if (epre)
        k_eproj_sorted<<<(int)(((long)N_EDGES * 32 + 255) / 256), 256, 0, stream>>>(
            ea, sE, Wep, bep, e_bf);

    // ---- pack all weights (3 layers x 4 matrices) in one launch ----
    k_pack_all<<<(3 * 8704 + 255) / 256, 256, 0, stream>>>(
        We1, We2, Wn1, Wn2, pA1, pA2, pWn1, pWn2);

    // ---- node projection + BN (two-stage parallel stats) ----
    k_node_proj<<<512, 256, 0, stream>>>(x, Wnp, bnp, t, partN);
    k_stats_part<<<16, 256, 0, stream>>>(partN, 512, part2);
    k_stats_reduce<<<1, 256, 0, stream>>>(part2, 16, g_np, be_np, ss);
    k_bn_apply<<<(N_NODES * ND / 8 + 255) / 256, 256, 0, stream>>>(t, ss, h, h_bf);

    for (int l = 0; l < 3; ++l) {
        // zero only boundary/deg-0 aggr rows (interior rows are overwritten)
        k_zero_rows<<<(N_NODES * 64 + 255) / 256, 256, 0, stream>>>(bflag, aggr);
        if (epre)
            k_edge_mfma_s<true><<<N_EDGES / 128, 256, 0, stream>>>(
                h_bf, e_bf, ea, sE, Wep, bep, sD, sS, rowptr, hist,
                pA1 + (size_t)l * 40 * 64 * 8, be1 + l * HD,
                pA2 + (size_t)l * 32 * 64 * 8, be2 + l * HD, aggr);
        else
            k_edge_mfma_s<false><<<N_EDGES / 128, 256, 0, stream>>>(
                h_bf, e_bf, ea, sE, Wep, bep, sD, sS, rowptr, hist,
                pA1 + (size_t)l * 40 * 64 * 8, be1 + l * HD,
                pA2 + (size_t)l * 32 * 64 * 8, be2 + l * HD, aggr);

        k_node_mfma<<<NBB, 256, 0, stream>>>(
            h_bf, aggr, h,
            pWn1 + (size_t)l * 48 * 64 * 8, bn1 + l * HD,
            pWn2 + (size_t)l * 16 * 64 * 8, bn2 + l * ND, t, partU);
        k_stats_part<<<16, 256, 0, stream>>>(partU, NBU2, part2);
        k_stats_reduce<<<1, 256, 0, stream>>>(part2, 16, g_bn + l * ND, b_bn + l * ND, ss);
        k_bn_apply<<<(N_NODES * ND / 8 + 255) / 256, 256, 0, stream>>>(t, ss, h, h_bf);
    }

    hipMemsetAsync(pooled, 0, (size_t)(N_GRAPH * ND + 512) * sizeof(float), stream);
    k_pool<<<512, 256, 0, stream>>>(h, batch, pooled, cnt);
    k_readout<<<(N_GRAPH + WPB - 1) / WPB, 256, 0, stream>>>(
        pooled, cnt, Wo1, bo1, Wo2, bo2, outp);
}

// Round 29
// 806.437 us; speedup vs baseline: 1.4657x; 1.0062x over previous
//
#include <hip/hip_runtime.h>
#include <hip/hip_bf16.h>

#define N_NODES 50000
#define N_EDGES 800000
#define N_GRAPH 500
#define ND 64
#define ED 32
#define HD 128
#define WPB 4   // waves per block (256 threads)
#define NBB ((N_NODES + 63) / 64)   // 782 node blocks (64 nodes each)
#define NBU2 (2 * NBB)              // 1564 partial-stat rows

typedef __attribute__((ext_vector_type(8))) short bf16x8;
typedef __attribute__((ext_vector_type(4))) float f32x4;
typedef __attribute__((ext_vector_type(2))) float f32x2;
typedef __attribute__((ext_vector_type(4))) unsigned int u32x4;

__device__ __forceinline__ float sp(float x) {
    return fmaxf(x, 0.f) + log1pf(expf(-fabsf(x)));
}

// fast softplus for the bf16 path (v_exp_f32/v_log_f32 based)
__device__ __forceinline__ float spf(float x) {
    return fmaxf(x, 0.f) + __logf(1.f + __expf(-fabsf(x)));
}

__device__ __forceinline__ unsigned short f2bf(float v) {
    __hip_bfloat16 b = __float2bfloat16(v);
    return *(unsigned short*)&b;
}

// single-instruction pack: lo=bf16(a), hi=bf16(b)  (v_cvt_pk_bf16_f32, RNE)
__device__ __forceinline__ unsigned int cvtpk(float a, float b) {
    unsigned int r;
    asm("v_cvt_pk_bf16_f32 %0, %1, %2" : "=v"(r) : "v"(a), "v"(b));
    return r;
}

__device__ __forceinline__ float lo_bf(unsigned int u) { return __uint_as_float(u << 16); }
__device__ __forceinline__ float hi_bf(unsigned int u) { return __uint_as_float(u & 0xffff0000u); }

// load 8 fp32 and round to bf16x8 via 4 cvt_pk
__device__ __forceinline__ bf16x8 ld8_f32_bf(const float* p) {
    f32x4 v0 = *(const f32x4*)p;
    f32x4 v1 = *(const f32x4*)(p + 4);
    u32x4 u;
    u[0] = cvtpk(v0[0], v0[1]);
    u[1] = cvtpk(v0[2], v0[3]);
    u[2] = cvtpk(v1[0], v1[1]);
    u[3] = cvtpk(v1[2], v1[3]);
    return *(bf16x8*)&u;
}

// ---------------- node projection: partial BN stats per block -----------
__global__ __launch_bounds__(256) void k_node_proj(
    const float* __restrict__ x, const float* __restrict__ Wnp,
    const float* __restrict__ bnp, float* __restrict__ t,
    float* __restrict__ partN) {
    __shared__ float red0[4][64], red1[4][64];
    int lane = threadIdx.x & 63;
    int wid = threadIdx.x >> 6;
    int wave = (blockIdx.x * blockDim.x + threadIdx.x) >> 6;
    int nw = (gridDim.x * blockDim.x) >> 6;
    float w[13];
#pragma unroll
    for (int k = 0; k < 13; ++k) w[k] = Wnp[k * ND + lane];
    float bb = bnp[lane];
    float s0 = 0.f, s1 = 0.f;
    for (int i = wave; i < N_NODES; i += nw) {
        float acc = bb;
#pragma unroll
        for (int k = 0; k < 13; ++k) acc += x[i * 13 + k] * w[k];
        float v = sp(acc);
        t[i * ND + lane] = v;
        s0 += v; s1 += v * v;
    }
    red0[wid][lane] = s0;
    red1[wid][lane] = s1;
    __syncthreads();
    int tid = threadIdx.x;
    if (tid < 64)
        partN[blockIdx.x * 128 + tid] =
            red0[0][tid] + red0[1][tid] + red0[2][tid] + red0[3][tid];
    else if (tid < 128) {
        int c = tid - 64;
        partN[blockIdx.x * 128 + tid] =
            red1[0][c] + red1[1][c] + red1[2][c] + red1[3][c];
    }
}

// ---- fused two-stage BN stats (16 blocks, last-block finalize) ---------
__global__ __launch_bounds__(256) void k_stats_fused(
    const float* __restrict__ part, int R,
    const float* __restrict__ g, const float* __restrict__ b,
    float* __restrict__ ss, float* __restrict__ part2,
    int* __restrict__ counter) {
    __shared__ float r0[4][64], r1[4][64];
    __shared__ int last;
    int q = threadIdx.x >> 6, c = threadIdx.x & 63;
    float S0 = 0.f, S1 = 0.f;
    for (int r = blockIdx.x * 4 + q; r < R; r += 64) {
        S0 += part[(size_t)r * 128 + c];
        S1 += part[(size_t)r * 128 + 64 + c];
    }
    r0[q][c] = S0; r1[q][c] = S1;
    __syncthreads();
    if (threadIdx.x < 64)
        part2[blockIdx.x * 128 + c] = r0[0][c] + r0[1][c] + r0[2][c] + r0[3][c];
    else if (threadIdx.x < 128) {
        int cc = threadIdx.x - 64;
        part2[blockIdx.x * 128 + 64 + cc] =
            r1[0][cc] + r1[1][cc] + r1[2][cc] + r1[3][cc];
    }
    __syncthreads();
    __threadfence();
    if (threadIdx.x == 0) last = (atomicAdd(counter, 1) == 15);
    __syncthreads();
    if (!last) return;
    // finalize: atomic-load part2 (cross-XCD safe), emit scale/shift
    float T0 = 0.f, T1 = 0.f;
    for (int r = q; r < 16; r += 4) {
        T0 += atomicAdd(&part2[r * 128 + c], 0.f);
        T1 += atomicAdd(&part2[r * 128 + 64 + c], 0.f);
    }
    __syncthreads();
    r0[q][c] = T0; r1[q][c] = T1;
    __syncthreads();
    if (threadIdx.x < 64) {
        float s0 = r0[0][c] + r0[1][c] + r0[2][c] + r0[3][c];
        float s1 = r1[0][c] + r1[1][c] + r1[2][c] + r1[3][c];
        float inv_n = 1.f / (float)N_NODES;
        float mu = s0 * inv_n;
        float var = s1 * inv_n - mu * mu;
        float rs = rsqrtf(var + 1e-5f);
        float sc = rs * g[c];
        ss[c] = sc;
        ss[64 + c] = b[c] - mu * sc;
    }
    if (threadIdx.x == 0) *counter = 0;   // self-clean for next invocation
}

// vectorized BN apply: 8 elements/thread (channels contiguous, 8 | 64)
__global__ __launch_bounds__(256) void k_bn_apply(
    const float* __restrict__ t, const float* __restrict__ ss,
    float* __restrict__ h, unsigned short* __restrict__ hb) {
    int idx = (blockIdx.x * 256 + threadIdx.x) * 8;
    if (idx >= N_NODES * ND) return;
    int c = idx & (ND - 1);
    f32x4 sc0 = *(const f32x4*)(ss + c);
    f32x4 sc1 = *(const f32x4*)(ss + c + 4);
    f32x4 sh0 = *(const f32x4*)(ss + ND + c);
    f32x4 sh1 = *(const f32x4*)(ss + ND + c + 4);
    f32x4 v0 = *(const f32x4*)(t + idx);
    f32x4 v1 = *(const f32x4*)(t + idx + 4);
    f32x4 r0, r1;
#pragma unroll
    for (int j = 0; j < 4; ++j) { r0[j] = v0[j] * sc0[j] + sh0[j]; r1[j] = v1[j] * sc1[j] + sh1[j]; }
    *(f32x4*)(h + idx) = r0;
    *(f32x4*)(h + idx + 4) = r1;
    u32x4 u;
    u[0] = cvtpk(r0[0], r0[1]);
    u[1] = cvtpk(r0[2], r0[3]);
    u[2] = cvtpk(r1[0], r1[1]);
    u[3] = cvtpk(r1[2], r1[3]);
    *(u32x4*)(hb + idx) = u;
}

// ---------------- counting sort of edges by dst -------------------------
__global__ __launch_bounds__(256) void k_hist(const int* __restrict__ ei,
                                              int* __restrict__ hist) {
    int e = blockIdx.x * 256 + threadIdx.x;
    if (e < N_EDGES) atomicAdd(&hist[ei[N_EDGES + e]], 1);
}

__global__ __launch_bounds__(1024) void k_scan1(const int* __restrict__ hist,
                                                int* __restrict__ chunksum) {
    __shared__ int s[1024];
    int t = threadIdx.x;
    int i = blockIdx.x * 1024 + t;
    s[t] = (i < N_NODES) ? hist[i] : 0;
    __syncthreads();
    for (int off = 512; off; off >>= 1) {
        if (t < off) s[t] += s[t + off];
        __syncthreads();
    }
    if (t == 0) chunksum[blockIdx.x] = s[0];
}

__global__ void k_scan2(int* __restrict__ chunksum, int n) {
    if (threadIdx.x == 0) {
        int acc = 0;
        for (int i = 0; i < n; ++i) { int v = chunksum[i]; chunksum[i] = acc; acc += v; }
    }
}

// scan + rowptr + boundary-flag (k_mark folded in)
__global__ __launch_bounds__(1024) void k_scan3(const int* __restrict__ hist,
                                                const int* __restrict__ chunksum,
                                                int* __restrict__ cursor,
                                                int* __restrict__ rowptr,
                                                unsigned char* __restrict__ bflag) {
    __shared__ int s[1024];
    int t = threadIdx.x;
    int i = blockIdx.x * 1024 + t;
    int v = (i < N_NODES) ? hist[i] : 0;
    s[t] = v;
    __syncthreads();
    for (int off = 1; off < 1024; off <<= 1) {
        int u = (t >= off) ? s[t - off] : 0;
        __syncthreads();
        s[t] += u;
        __syncthreads();
    }
    if (i < N_NODES) {
        int ex = chunksum[blockIdx.x] + s[t] - v;  // exclusive
        cursor[i] = ex;
        rowptr[i] = ex;
        bflag[i] = (v == 0) || ((ex >> 7) != ((ex + v - 1) >> 7));
    }
}

__global__ __launch_bounds__(256) void k_scatter(const int* __restrict__ ei,
                                                 int* __restrict__ cursor,
                                                 int* __restrict__ sD,
                                                 int* __restrict__ sS,
                                                 int* __restrict__ sE) {
    int e = blockIdx.x * 256 + threadIdx.x;
    if (e >= N_EDGES) return;
    int d = ei[N_EDGES + e];
    int pos = atomicAdd(&cursor[d], 1);
    sD[pos] = d;
    sS[pos] = ei[e];
    sE[pos] = e;
}

// zero only flagged aggr rows (prologue only; per-layer zeroing folded
// into k_node_mfma's tail)
__global__ __launch_bounds__(256) void k_zero_rows(
    const unsigned char* __restrict__ bflag, float* __restrict__ aggr) {
    int idx = blockIdx.x * 256 + threadIdx.x;   // node*64 + pair
    if (idx >= N_NODES * 64) return;
    int node = idx >> 6;
    if (!bflag[node]) return;
    f32x2 z = (f32x2){0.f, 0.f};
    *(f32x2*)(aggr + (size_t)node * HD + 2 * (idx & 63)) = z;
}

// edge projection into sorted order (layer-invariant, once per call)
__global__ __launch_bounds__(256) void k_eproj_sorted(
    const float* __restrict__ ea, const int* __restrict__ sE,
    const float* __restrict__ Wep, const float* __restrict__ bep,
    unsigned short* __restrict__ e_bf) {
    long idx = (long)blockIdx.x * blockDim.x + threadIdx.x;
    long tot = (long)N_EDGES * 32;
    if (idx >= tot) return;
    int p = (int)(idx >> 5), col = (int)(idx & 31);
    int e = sE[p];
    float v = spf(ea[2 * e] * Wep[col] + ea[2 * e + 1] * Wep[32 + col] + bep[col]);
    e_bf[idx] = f2bf(v);
}

// ---- fused weight pack: all 3 layers x {We1,We2,Wn1,Wn2} in ONE launch --
__global__ __launch_bounds__(256) void k_pack_all(
    const float* __restrict__ We1, const float* __restrict__ We2,
    const float* __restrict__ Wn1, const float* __restrict__ Wn2,
    unsigned short* __restrict__ pA1, unsigned short* __restrict__ pA2,
    unsigned short* __restrict__ pWn1, unsigned short* __restrict__ pWn2) {
    int tid = blockIdx.x * 256 + threadIdx.x;
    const int PER_L = (40 + 32 + 48 + 16) * 64;  // 8704
    if (tid >= 3 * PER_L) return;
    int layer = tid / PER_L;
    int r = tid % PER_L;
    const float* W;
    unsigned short* out;
    int ncols, lt;
    if (r < 40 * 64) {
        lt = r; W = We1 + (size_t)layer * 160 * 128; out = pA1 + (size_t)layer * 40 * 64 * 8;
        ncols = 128;
    } else if (r < 72 * 64) {
        lt = r - 40 * 64; W = We2 + (size_t)layer * 128 * 128; out = pA2 + (size_t)layer * 32 * 64 * 8;
        ncols = 128;
    } else if (r < 120 * 64) {
        lt = r - 72 * 64; W = Wn1 + (size_t)layer * 192 * 128; out = pWn1 + (size_t)layer * 48 * 64 * 8;
        ncols = 128;
    } else {
        lt = r - 120 * 64; W = Wn2 + (size_t)layer * 128 * 64; out = pWn2 + (size_t)layer * 16 * 64 * 8;
        ncols = 64;
    }
    int nfrag = ncols >> 4;
    int l = lt & 63; int fr = lt >> 6; int nf = fr % nfrag; int ks = fr / nfrag;
    int n = 16 * nf + (l & 15);
    int k0 = 32 * ks + 8 * (l >> 4);
#pragma unroll
    for (int rr = 0; rr < 8; ++rr)
        out[lt * 8 + rr] = f2bf(W[(k0 + rr) * ncols + n]);
}

// ---------------- MFMA edge conv on dst-sorted edges --------------------
// Register-bounded form + hoisted GEMM1 B-fragments + cvt_pk packing.
template <bool EPRE>
__global__ __launch_bounds__(256, 4) void k_edge_mfma_s(
    const unsigned short* __restrict__ h_bf, const unsigned short* __restrict__ e_bf,
    const float* __restrict__ ea, const int* __restrict__ sE,
    const float* __restrict__ Wep, const float* __restrict__ bep,
    const int* __restrict__ sD, const int* __restrict__ sS,
    const int* __restrict__ rowptr, const int* __restrict__ hist,
    const unsigned short* __restrict__ pA1, const float* __restrict__ be1,
    const unsigned short* __restrict__ pA2, const float* __restrict__ be2,
    float* __restrict__ aggr) {
    __shared__ unsigned short P[WPB][32][136];   // per-wave P; reused as 128-row stage
    __shared__ int dstB[128];
    __shared__ unsigned short eL[EPRE ? 64 : 128 * 32];

    int lane = threadIdx.x & 63;
    int w = threadIdx.x >> 6;
    int m = lane & 15, g = lane >> 4;
    int tile0 = blockIdx.x * 128;
    int wbase = tile0 + 32 * w;

    int eD0 = sD[wbase + m];
    int eD1 = sD[wbase + 16 + m];
    int eS0 = sS[wbase + m];
    int eS1 = sS[wbase + 16 + m];

    if constexpr (!EPRE) {
        int col = threadIdx.x & 31;
        int r0 = threadIdx.x >> 5;
        float w0 = Wep[col], w1 = Wep[32 + col], bb = bep[col];
#pragma unroll
        for (int i = 0; i < 16; ++i) {
            int em = r0 + 8 * i;
            int e = sE[tile0 + em];
            eL[em * 32 + col] = f2bf(spf(ea[2 * e] * w0 + ea[2 * e + 1] * w1 + bb));
        }
        __syncthreads();
    }

    // ---- hoist GEMM1 B-fragments once (z-rows: dst 64 | src 64 | e 32) --
    bf16x8 B0[5], B1[5];
    B0[0] = *(const bf16x8*)(h_bf + (size_t)eD0 * 64 + 8 * g);
    B1[0] = *(const bf16x8*)(h_bf + (size_t)eD1 * 64 + 8 * g);
    B0[1] = *(const bf16x8*)(h_bf + (size_t)eD0 * 64 + 32 + 8 * g);
    B1[1] = *(const bf16x8*)(h_bf + (size_t)eD1 * 64 + 32 + 8 * g);
    B0[2] = *(const bf16x8*)(h_bf + (size_t)eS0 * 64 + 8 * g);
    B1[2] = *(const bf16x8*)(h_bf + (size_t)eS1 * 64 + 8 * g);
    B0[3] = *(const bf16x8*)(h_bf + (size_t)eS0 * 64 + 32 + 8 * g);
    B1[3] = *(const bf16x8*)(h_bf + (size_t)eS1 * 64 + 32 + 8 * g);
    if constexpr (EPRE) {
        B0[4] = *(const bf16x8*)(e_bf + (size_t)(wbase + m) * 32 + 8 * g);
        B1[4] = *(const bf16x8*)(e_bf + (size_t)(wbase + 16 + m) * 32 + 8 * g);
    } else {
        B0[4] = *(const bf16x8*)&eL[(32 * w + m) * 32 + 8 * g];
        B1[4] = *(const bf16x8*)&eL[(32 * w + 16 + m) * 32 + 8 * g];
    }

    // ---- GEMM1 (K=160) in four nf-quarters: acc = 16 AGPR per region ----
#pragma unroll
    for (int qt = 0; qt < 4; ++qt) {
        f32x4 acc[2][2];
#pragma unroll
        for (int mf = 0; mf < 2; ++mf)
#pragma unroll
            for (int n2 = 0; n2 < 2; ++n2) acc[mf][n2] = (f32x4){0.f, 0.f, 0.f, 0.f};
#pragma unroll
        for (int ks = 0; ks < 5; ++ks) {
#pragma unroll
            for (int n2 = 0; n2 < 2; ++n2) {
                int nf = qt * 2 + n2;
                bf16x8 a = *(const bf16x8*)(pA1 + ((ks * 8 + nf) * 64 + lane) * 8);
                acc[0][n2] = __builtin_amdgcn_mfma_f32_16x16x32_bf16(a, B0[ks], acc[0][n2], 0, 0, 0);
                acc[1][n2] = __builtin_amdgcn_mfma_f32_16x16x32_bf16(a, B1[ks], acc[1][n2], 0, 0, 0);
            }
        }
        // epilogue 1 (this quarter): bias + fast softplus -> P (bf16) in LDS
#pragma unroll
        for (int n2 = 0; n2 < 2; ++n2) {
            int nf = qt * 2 + n2;
            f32x4 bb = *(const f32x4*)(be1 + 16 * nf + 4 * g);
#pragma unroll
            for (int mf = 0; mf < 2; ++mf) {
                f32x4 c = acc[mf][n2];
                unsigned int u01 = cvtpk(spf(c[0] + bb[0]), spf(c[1] + bb[1]));
                unsigned int u23 = cvtpk(spf(c[2] + bb[2]), spf(c[3] + bb[3]));
                unsigned int* dst = (unsigned int*)&P[w][m + 16 * mf][16 * nf + 4 * g];
                dst[0] = u01; dst[1] = u23;
            }
        }
    }

    // ---- GEMM2 (K=128) per m-fragment, two nf-halves; 8-reg deferral ----
    unsigned short (*Pf)[136] = (unsigned short(*)[136]) & P[0][0][0];
#pragma unroll
    for (int mf = 0; mf < 2; ++mf) {
        unsigned int defer[8];
#pragma unroll
        for (int half = 0; half < 2; ++half) {
            f32x4 acc2[4];
#pragma unroll
            for (int n2 = 0; n2 < 4; ++n2) acc2[n2] = (f32x4){0.f, 0.f, 0.f, 0.f};
#pragma unroll
            for (int ks = 0; ks < 4; ++ks) {
                bf16x8 b = *(const bf16x8*)&P[w][m + 16 * mf][32 * ks + 8 * g];
#pragma unroll
                for (int n2 = 0; n2 < 4; ++n2) {
                    int nf = half * 4 + n2;
                    bf16x8 a = *(const bf16x8*)(pA2 + ((ks * 8 + nf) * 64 + lane) * 8);
                    acc2[n2] = __builtin_amdgcn_mfma_f32_16x16x32_bf16(a, b, acc2[n2], 0, 0, 0);
                }
            }
            if (half == 0) {
#pragma unroll
                for (int n2 = 0; n2 < 4; ++n2) {
                    int nf = n2;
                    f32x4 bb = *(const f32x4*)(be2 + 16 * nf + 4 * g);
                    f32x4 c = acc2[n2];
                    defer[2 * n2] = cvtpk(spf(c[0] + bb[0]), spf(c[1] + bb[1]));
                    defer[2 * n2 + 1] = cvtpk(spf(c[2] + bb[2]), spf(c[3] + bb[3]));
                }
            } else {
#pragma unroll
                for (int n2 = 0; n2 < 4; ++n2) {
                    int nf = 4 + n2;
                    f32x4 bb = *(const f32x4*)(be2 + 16 * nf + 4 * g);
                    f32x4 c = acc2[n2];
                    unsigned int* dst =
                        (unsigned int*)&Pf[32 * w + 16 * mf + m][16 * nf + 4 * g];
                    dst[0] = cvtpk(spf(c[0] + bb[0]), spf(c[1] + bb[1]));
                    dst[1] = cvtpk(spf(c[2] + bb[2]), spf(c[3] + bb[3]));
                }
#pragma unroll
                for (int n2 = 0; n2 < 4; ++n2) {
                    unsigned int* dst =
                        (unsigned int*)&Pf[32 * w + 16 * mf + m][16 * n2 + 4 * g];
                    dst[0] = defer[2 * n2];
                    dst[1] = defer[2 * n2 + 1];
                }
            }
        }
    }
    if (g == 0) {
        dstB[32 * w + m] = eD0;
        dstB[32 * w + 16 + m] = eD1;
    }
    __syncthreads();

    // ---- block-wide run-length segmented reduction ----
    int rbeg = 32 * w, rend = rbeg + 32;
    int r = rbeg;
    if (w) {  // skip rows continuing a run that started in a lower wave
        while (r < rend && dstB[r] == dstB[r - 1]) ++r;
    }
    while (r < rend) {
        int d = dstB[r];
        float a0 = 0.f, a1 = 0.f;
        int rr = r;
        do {
            unsigned int u = *(const unsigned int*)&Pf[rr][2 * lane];
            a0 += lo_bf(u);
            a1 += hi_bf(u);
            ++rr;
        } while (rr < 128 && dstB[rr] == d);
        int s0 = rowptr[d];
        bool interior = (s0 >= tile0) && (s0 + hist[d] <= tile0 + 128);
        float* base = aggr + (size_t)d * HD + 2 * lane;
        if (interior) {
            base[0] = a0;
            base[1] = a1;
        } else {
            atomicAdd(base, a0);
            atomicAdd(base + 1, a1);
        }
        r = rr;
    }
}

// ---------------- MFMA node update: 64 nodes/block (2 groups x 2 waves) --
// Tail: re-zeroes flagged aggr rows for the next layer (reads done pre-sync).
__global__ __launch_bounds__(256, 2) void k_node_mfma(
    const unsigned short* __restrict__ h_bf, float* __restrict__ aggr,
    const float* __restrict__ h, const unsigned char* __restrict__ bflag,
    const unsigned short* __restrict__ pWn1, const float* __restrict__ bn1,
    const unsigned short* __restrict__ pWn2, const float* __restrict__ bn2,
    float* __restrict__ t, float* __restrict__ partU) {
    __shared__ unsigned short P[2][32][136];

    int lane = threadIdx.x & 63;
    int wid = threadIdx.x >> 6;
    int grp = wid >> 1;          // 0 or 1 (32-node group)
    int wv = wid & 1;            // 0 or 1 (nf split within group)
    int m = lane & 15, g = lane >> 4;
    int wbase = blockIdx.x * 64 + grp * 32;
    int n0 = wbase + m, n1 = wbase + 16 + m;
    bool v0 = n0 < N_NODES, v1 = n1 < N_NODES;
    int c0 = v0 ? n0 : N_NODES - 1;
    int c1 = v1 ? n1 : N_NODES - 1;

    f32x4 acc[2][4];
#pragma unroll
    for (int mf = 0; mf < 2; ++mf)
#pragma unroll
        for (int n2 = 0; n2 < 4; ++n2) acc[mf][n2] = (f32x4){0.f, 0.f, 0.f, 0.f};

    // ---- GEMM1: K = 192 (h 64 | aggr 128); this wave: nf = 4*wv..4*wv+3
#pragma unroll
    for (int ks = 0; ks < 6; ++ks) {
        bf16x8 b0, b1;
        if (ks < 2) {
            b0 = *(const bf16x8*)(h_bf + (size_t)c0 * 64 + ks * 32 + 8 * g);
            b1 = *(const bf16x8*)(h_bf + (size_t)c1 * 64 + ks * 32 + 8 * g);
        } else {
            b0 = ld8_f32_bf(aggr + (size_t)c0 * 128 + (ks - 2) * 32 + 8 * g);
            b1 = ld8_f32_bf(aggr + (size_t)c1 * 128 + (ks - 2) * 32 + 8 * g);
        }
#pragma unroll
        for (int n2 = 0; n2 < 4; ++n2) {
            int nf = 4 * wv + n2;
            bf16x8 a = *(const bf16x8*)(pWn1 + ((ks * 8 + nf) * 64 + lane) * 8);
            acc[0][n2] = __builtin_amdgcn_mfma_f32_16x16x32_bf16(a, b0, acc[0][n2], 0, 0, 0);
            acc[1][n2] = __builtin_amdgcn_mfma_f32_16x16x32_bf16(a, b1, acc[1][n2], 0, 0, 0);
        }
    }

    // ---- epilogue 1: bias + fast softplus -> P columns of this wave ----
#pragma unroll
    for (int n2 = 0; n2 < 4; ++n2) {
        int nf = 4 * wv + n2;
        f32x4 bb = *(const f32x4*)(bn1 + 16 * nf + 4 * g);
#pragma unroll
        for (int mf = 0; mf < 2; ++mf) {
            f32x4 c = acc[mf][n2];
            unsigned int u01 = cvtpk(spf(c[0] + bb[0]), spf(c[1] + bb[1]));
            unsigned int u23 = cvtpk(spf(c[2] + bb[2]), spf(c[3] + bb[3]));
            unsigned int* dst = (unsigned int*)&P[grp][m + 16 * mf][16 * nf + 4 * g];
            dst[0] = u01; dst[1] = u23;
        }
    }
    __syncthreads();

    f32x4 acc2[2][2];
#pragma unroll
    for (int mf = 0; mf < 2; ++mf)
#pragma unroll
        for (int n2 = 0; n2 < 2; ++n2) acc2[mf][n2] = (f32x4){0.f, 0.f, 0.f, 0.f};

    // ---- GEMM2: K = 128, N = 64; this wave: nf = 2*wv..2*wv+1 ----
#pragma unroll
    for (int ks = 0; ks < 4; ++ks) {
        bf16x8 b0 = *(const bf16x8*)&P[grp][m][32 * ks + 8 * g];
        bf16x8 b1 = *(const bf16x8*)&P[grp][m + 16][32 * ks + 8 * g];
#pragma unroll
        for (int n2 = 0; n2 < 2; ++n2) {
            int nf = 2 * wv + n2;
            bf16x8 a = *(const bf16x8*)(pWn2 + ((ks * 4 + nf) * 64 + lane) * 8);
            acc2[0][n2] = __builtin_amdgcn_mfma_f32_16x16x32_bf16(a, b0, acc2[0][n2], 0, 0, 0);
            acc2[1][n2] = __builtin_amdgcn_mfma_f32_16x16x32_bf16(a, b1, acc2[1][n2], 0, 0, 0);
        }
    }

    // ---- epilogue 2: +bn2 +h residual -> t; partial BN stats -----------
#pragma unroll
    for (int n2 = 0; n2 < 2; ++n2) {
        int nf = 2 * wv + n2;
        f32x4 bb = *(const f32x4*)(bn2 + 16 * nf + 4 * g);
        f32x4 s0v = (f32x4){0.f, 0.f, 0.f, 0.f};
        f32x4 s1v = (f32x4){0.f, 0.f, 0.f, 0.f};
#pragma unroll
        for (int mf = 0; mf < 2; ++mf) {
            int cn = mf ? c1 : c0;
            bool vn = mf ? v1 : v0;
            f32x4 hv = *(const f32x4*)(h + (size_t)cn * 64 + 16 * nf + 4 * g);
            f32x4 c = acc2[mf][n2];
            f32x4 tn;
#pragma unroll
            for (int j = 0; j < 4; ++j) tn[j] = c[j] + bb[j] + hv[j];
            if (vn) *(f32x4*)(t + (size_t)cn * 64 + 16 * nf + 4 * g) = tn;
#pragma unroll
            for (int j = 0; j < 4; ++j) {
                float tv = vn ? tn[j] : 0.f;
                s0v[j] += tv;
                s1v[j] += tv * tv;
            }
        }
#pragma unroll
        for (int j = 0; j < 4; ++j) {
#pragma unroll
            for (int k = 1; k <= 8; k <<= 1) {
                s0v[j] += __shfl_xor(s0v[j], k);
                s1v[j] += __shfl_xor(s1v[j], k);
            }
        }
        if (m == 0) {
#pragma unroll
            for (int j = 0; j < 4; ++j) {
                int ch = 16 * nf + 4 * g + j;
                size_t row = (size_t)blockIdx.x * 2 + grp;
                partU[row * 128 + ch] = s0v[j];
                partU[row * 128 + 64 + ch] = s1v[j];
            }
        }
    }

    // ---- tail: re-zero flagged aggr rows for the next layer ------------
    // (both waves' GEMM1 aggr reads completed before the earlier sync)
    int zn = wbase + 16 * wv + m;
    if (zn < N_NODES && bflag[zn]) {
        float* base = aggr + (size_t)zn * HD + 4 * g;
        f32x4 z = (f32x4){0.f, 0.f, 0.f, 0.f};
#pragma unroll
        for (int j = 0; j < 8; ++j) *(f32x4*)(base + 16 * j) = z;
    }
}

// ---------------- pooling + readout (unchanged) -------------------------
__global__ __launch_bounds__(256) void k_pool(
    const float* __restrict__ h, const int* __restrict__ batch,
    float* __restrict__ pooled, float* __restrict__ cnt) {
    int lane = threadIdx.x & 63;
    int wave = (blockIdx.x * blockDim.x + threadIdx.x) >> 6;
    int nw = (gridDim.x * blockDim.x) >> 6;
    int chunk = (N_NODES + nw - 1) / nw;
    int s = wave * chunk;
    int epos = min(N_NODES, s + chunk);
    if (s >= N_NODES) return;
    int curg = batch[s];
    float acc = 0.f, c = 0.f;
    for (int i = s; i < epos; ++i) {
        int g = batch[i];
        if (g != curg) {
            atomicAdd(&pooled[curg * ND + lane], acc);
            if (lane == 0) atomicAdd(&cnt[curg], c);
            acc = 0.f; c = 0.f; curg = g;
        }
        acc += h[i * ND + lane];
        c += 1.f;
    }
    atomicAdd(&pooled[curg * ND + lane], acc);
    if (lane == 0) atomicAdd(&cnt[curg], c);
}

__global__ __launch_bounds__(256) void k_readout(
    const float* __restrict__ pooled, const float* __restrict__ cnt,
    const float* __restrict__ Wo1, const float* __restrict__ bo1,
    const float* __restrict__ Wo2, const float* __restrict__ bo2,
    float* __restrict__ out) {
    __shared__ float pbuf[WPB][ND];
    int lane = threadIdx.x & 63;
    int wid = threadIdx.x >> 6;
    int g = blockIdx.x * WPB + wid;
    bool valid = g < N_GRAPH;
    int gc = valid ? g : N_GRAPH - 1;
    float c = fmaxf(cnt[gc], 1.f);
    pbuf[wid][lane] = pooled[gc * ND + lane] / c;
    __syncthreads();
    float h0 = bo1[lane], h1 = bo1[64 + lane];
#pragma unroll 8
    for (int k = 0; k < ND; ++k) {
        float pk = pbuf[wid][k];
        h0 += pk * Wo1[k * HD + lane];
        h1 += pk * Wo1[k * HD + 64 + lane];
    }
    float s = sp(h0) * Wo2[lane] + sp(h1) * Wo2[64 + lane];
#pragma unroll
    for (int off = 32; off; off >>= 1) s += __shfl_down(s, off);
    if (valid && lane == 0) out[g] = s + bo2[0];
}

extern "C" void kernel_launch(void* const* d_in, const int* in_sizes, int n_in,
                              void* d_out, int out_size, void* d_ws, size_t ws_size,
                              hipStream_t stream) {
    const float* x       = (const float*)d_in[0];
    const float* ea      = (const float*)d_in[1];
    const int*   ei      = (const int*)d_in[2];
    const int*   batch   = (const int*)d_in[3];
    const float* Wnp     = (const float*)d_in[4];
    const float* bnp     = (const float*)d_in[5];
    const float* g_np    = (const float*)d_in[6];
    const float* be_np   = (const float*)d_in[7];
    const float* Wep     = (const float*)d_in[8];
    const float* bep     = (const float*)d_in[9];
    const float* We1     = (const float*)d_in[10];
    const float* be1     = (const float*)d_in[11];
    const float* We2     = (const float*)d_in[12];
    const float* be2     = (const float*)d_in[13];
    const float* Wn1     = (const float*)d_in[14];
    const float* bn1     = (const float*)d_in[15];
    const float* Wn2     = (const float*)d_in[16];
    const float* bn2     = (const float*)d_in[17];
    const float* g_bn    = (const float*)d_in[18];
    const float* b_bn    = (const float*)d_in[19];
    const float* Wo1     = (const float*)d_in[20];
    const float* bo1     = (const float*)d_in[21];
    const float* Wo2     = (const float*)d_in[22];
    const float* bo2     = (const float*)d_in[23];

    float* ws = (float*)d_ws;
    size_t off = 0;
    float* h      = ws + off; off += (size_t)N_NODES * ND;
    float* t      = ws + off; off += (size_t)N_NODES * ND;
    float* aggr   = ws + off; off += (size_t)N_NODES * HD;
    float* ss     = ws + off; off += 2 * ND;
    float* pooled = ws + off; off += N_GRAPH * ND;
    float* cnt    = ws + off; off += 512;
    unsigned short* h_bf = (unsigned short*)(ws + off); off += (size_t)N_NODES * ND / 2;
    unsigned short* pA1  = (unsigned short*)(ws + off); off += 3 * 5 * 8 * 64 * 8 / 2;
    unsigned short* pA2  = (unsigned short*)(ws + off); off += 3 * 4 * 8 * 64 * 8 / 2;
    unsigned short* pWn1 = (unsigned short*)(ws + off); off += 3 * 6 * 8 * 64 * 8 / 2;
    unsigned short* pWn2 = (unsigned short*)(ws + off); off += 3 * 4 * 4 * 64 * 8 / 2;
    int* sD       = (int*)(ws + off); off += N_EDGES;
    int* sS       = (int*)(ws + off); off += N_EDGES;
    int* sE       = (int*)(ws + off); off += N_EDGES;
    int* hist     = (int*)(ws + off); off += N_NODES;
    int* cursor   = (int*)(ws + off); off += N_NODES;
    int* rowptr   = (int*)(ws + off); off += N_NODES;
    int* chunksum = (int*)(ws + off); off += 64;
    int* counter  = (int*)(ws + off); off += 4;
    float* partN  = ws + off; off += 512 * 128;
    float* partU  = ws + off; off += (size_t)NBU2 * 128;
    float* part2  = ws + off; off += 16 * 128;
    unsigned char* bflag = (unsigned char*)(ws + off); off += (N_NODES + 3) / 4 + 16;
    size_t base_bytes = off * sizeof(float);
    unsigned short* e_bf = (unsigned short*)(ws + off);
    bool epre = (ws_size >= base_bytes + (size_t)N_EDGES * 32 * 2);

    float* outp = (float*)d_out;

    const int NCH = (N_NODES + 1023) / 1024;  // 49

    // ---- counting sort of edges by dst -> CSR (once per call) ----
    hipMemsetAsync(hist, 0, N_NODES * sizeof(int), stream);
    hipMemsetAsync(counter, 0, sizeof(int), stream);
    k_hist<<<(N_EDGES + 255) / 256, 256, 0, stream>>>(ei, hist);
    k_scan1<<<NCH, 1024, 0, stream>>>(hist, chunksum);
    k_scan2<<<1, 64, 0, stream>>>(chunksum, NCH);
    k_scan3<<<NCH, 1024, 0, stream>>>(hist, chunksum, cursor, rowptr, bflag);
    k_scatter<<<(N_EDGES + 255) / 256, 256, 0, stream>>>(ei, cursor, sD, sS, sE);
    if (epre)
        k_eproj_sorted<<<(int)(((long)N_EDGES * 32 + 255) / 256), 256, 0, stream>>>(
            ea, sE, Wep, bep, e_bf);

    // ---- pack all weights (3 layers x 4 matrices) in one launch ----
    k_pack_all<<<(3 * 8704 + 255) / 256, 256, 0, stream>>>(
        We1, We2, Wn1, Wn2, pA1, pA2, pWn1, pWn2);

    // ---- node projection + BN (fused two-stage stats) ----
    k_node_proj<<<512, 256, 0, stream>>>(x, Wnp, bnp, t, partN);
    k_stats_fused<<<16, 256, 0, stream>>>(partN, 512, g_np, be_np, ss, part2, counter);
    k_bn_apply<<<(N_NODES * ND / 8 + 255) / 256, 256, 0, stream>>>(t, ss, h, h_bf);

    // zero flagged aggr rows once (later layers re-zeroed by k_node_mfma tail)
    k_zero_rows<<<(N_NODES * 64 + 255) / 256, 256, 0, stream>>>(bflag, aggr);

    for (int l = 0; l < 3; ++l) {
        if (epre)
            k_edge_mfma_s<true><<<N_EDGES / 128, 256, 0, stream>>>(
                h_bf, e_bf, ea, sE, Wep, bep, sD, sS, rowptr, hist,
                pA1 + (size_t)l * 40 * 64 * 8, be1 + l * HD,
                pA2 + (size_t)l * 32 * 64 * 8, be2 + l * HD, aggr);
        else
            k_edge_mfma_s<false><<<N_EDGES / 128, 256, 0, stream>>>(
                h_bf, e_bf, ea, sE, Wep, bep, sD, sS, rowptr, hist,
                pA1 + (size_t)l * 40 * 64 * 8, be1 + l * HD,
                pA2 + (size_t)l * 32 * 64 * 8, be2 + l * HD, aggr);

        k_node_mfma<<<NBB, 256, 0, stream>>>(
            h_bf, aggr, h, bflag,
            pWn1 + (size_t)l * 48 * 64 * 8, bn1 + l * HD,
            pWn2 + (size_t)l * 16 * 64 * 8, bn2 + l * ND, t, partU);
        k_stats_fused<<<16, 256, 0, stream>>>(partU, NBU2, g_bn + l * ND, b_bn + l * ND, ss, part2, counter);
        k_bn_apply<<<(N_NODES * ND / 8 + 255) / 256, 256, 0, stream>>>(t, ss, h, h_bf);
    }

    hipMemsetAsync(pooled, 0, (size_t)(N_GRAPH * ND + 512) * sizeof(float), stream);
    k_pool<<<512, 256, 0, stream>>>(h, batch, pooled, cnt);
    k_readout<<<(N_GRAPH + WPB - 1) / WPB, 256, 0, stream>>>(
        pooled, cnt, Wo1, bo1, Wo2, bo2, outp);
}